// Round 8
// baseline (1270.949 us; speedup 1.0000x reference)
//
#include <hip/hip_runtime.h>
#include <stdint.h>

// ---------------- problem constants ----------------
#define N0 32768      // 32^3
#define N1 262144     // 64^3
#define N2 2097152    // 128^3

// d_out element offsets (cls0, cls1, cls2, out)
#define OFF_CLS0 0L
#define OFF_CLS1 32768L
#define OFF_CLS2 294912L
#define OFF_OUT  2392064L

// ---------------- ws layout (byte offsets, within proven ~320MB footprint) --
#define O_FLAGS 0UL            // int[64]: [0]=bf16 [1]=boolmode [8..]=counters [32]=list cnt
#define O_STATE 256UL
#define O_TIE   512UL          // 16000 ints (tie voxel-index list)
#define O_HIST1 66048UL        // 65536 u32
#define O_HIST2 328192UL       // 65536 u32
#define O_OCC0  590336UL       // N0 u8
#define O_OCC1  623104UL       // N1 u8
#define O_OCC2  885248UL       // N2 u8
#define O_MASK0 2982400UL
#define O_MASK1 3015168UL
#define O_BCNT  3277312UL      // 8192 ints (block counts / exclusive prefix)
#define O_SEL   5374464UL      // N2 u8 (dense by voxel, only active entries used)
#define O_KEYS  7471616UL      // N2 u32 keyl[] by LIST POSITION
#define O_FEAT0 15860224UL     // N0*16 f32
#define O_HR1   17957376UL     // N1*16 f32 ; ALIASED: list0 (lvl0), list2 (lvl2, hr1 dead)
#define O_FEAT1 34734592UL     // N1*16 f32
#define O_HR2   51511808UL     // N2*16 f32 ; ALIASED: list1 @+0 (lvl1), xf @+4MB (lvl0)
#define O_FEAT2 185729536UL    // N2*16 f32  (ends ~320 MB)

#define TIE_CAP 16000
#define GMAX 2048              // grid cap for grid-stride sparse kernels

// ---------------- dtype-flexible helpers ----------------
// flags[0] = floats-are-bf16; flags[1] = bool mode (0 i32,1 u8,2 bf16,3 f32,4 i64)
__device__ __forceinline__ float ldf(const void* p, long i, int bf) {
    if (bf) {
        uint16_t h = ((const uint16_t*)p)[i];
        return __uint_as_float(((uint32_t)h) << 16);
    }
    return ((const float*)p)[i];
}
__device__ __forceinline__ int ldb(const void* p, long i, int m) {
    switch (m) {
        case 0: return ((const int*)p)[i] != 0;
        case 1: return ((const uint8_t*)p)[i] != 0;
        case 2: { uint16_t h = ((const uint16_t*)p)[i]; return (h & 0x7FFF) != 0; }
        case 4: return ((const long long*)p)[i] != 0;
        default: { float f = ((const float*)p)[i]; return f != 0.0f; }
    }
}
__device__ __forceinline__ float rndb(float f, int en) {
    if (!en) return f;
    uint32_t u = __float_as_uint(f);
    u += 0x7FFFu + ((u >> 16) & 1u);
    u &= 0xFFFF0000u;
    return __uint_as_float(u);
}
__device__ __forceinline__ void stf(void* p, long i, float v, int bf) {
    if (bf) {
        uint32_t u = __float_as_uint(v);
        u += 0x7FFFu + ((u >> 16) & 1u);
        ((uint16_t*)p)[i] = (uint16_t)(u >> 16);
    } else {
        ((float*)p)[i] = v;
    }
}
// order-preserving float->u32 key; all finite keys are > 0
__device__ __forceinline__ uint32_t fkey(float f) {
    f = f + 0.0f;
    uint32_t u = __float_as_uint(f);
    return (u & 0x80000000u) ? ~u : (u | 0x80000000u);
}

// ---------------- runtime dtype detection (parallel) ----------------------
__global__ void k_fzero(int* flags) {
    int t = threadIdx.x;
    if (t < 16) flags[8 + t] = 0;
}
__global__ void k_fscan(const void* x, const void* gt2, int* flags) {
    int* cnt = flags + 8;
    __shared__ int lc[8];
    int t = threadIdx.x;
    if (t < 8) lc[t] = 0;
    __syncthreads();
    long gid = (long)blockIdx.x * blockDim.x + threadIdx.x;
    long gstride = (long)gridDim.x * blockDim.x;
    int ltiny = 0;
    const uint32_t* xu = (const uint32_t*)x;
    for (long i = gid; i < 524288; i += gstride) {
        uint32_t u = xu[i];
        uint32_t e = (u >> 23) & 0xFFu;
        if (e == 0u && (u & 0x7FFFFFu) != 0u) ltiny++;
    }
    int l1off = 0, l1any = 0, l3f = 0, l84 = 0;
    const uint8_t* g = (const uint8_t*)gt2;
    for (long i = gid; i < 2097152; i += gstride) {
        uint8_t b = g[i];
        if (b == 1u) {
            l1any++;
            if ((i & 3) != 0) l1off++;
            if ((i & 7) == 4) l84++;
        }
        if (b == 0x3Fu && (i & 3) == 1) l3f++;
    }
    if (ltiny) atomicAdd(&lc[0], ltiny);
    if (l1off) atomicAdd(&lc[1], l1off);
    if (l1any) atomicAdd(&lc[2], l1any);
    if (l3f)   atomicAdd(&lc[3], l3f);
    if (l84)   atomicAdd(&lc[4], l84);
    __syncthreads();
    if (t < 5 && lc[t]) atomicAdd(&cnt[t], lc[t]);
}
__global__ void k_ffinal(int* flags) {
    if (threadIdx.x != 0 || blockIdx.x != 0) return;
    const int* cnt = flags + 8;
    flags[0] = (cnt[0] > 8) ? 1 : 0;
    int bm;
    if (cnt[1] > 8)       bm = 1;
    else if (cnt[2] > 8)  bm = (cnt[4] > 8) ? 0 : 4;
    else if (cnt[3] > 8)  bm = 2;
    else                  bm = 3;
    flags[1] = bm;
}

// zero entire d_out (harness re-poisons to 0xAA each launch)
__global__ void k_zout(void* dout, long out_elems, const int* flags) {
    long bytes = out_elems * (flags[0] ? 2 : 4);
    long n16 = bytes >> 4;
    uint4 z = make_uint4(0, 0, 0, 0);
    uint4* p = (uint4*)dout;
    long stride = (long)gridDim.x * blockDim.x;
    for (long i = (long)blockIdx.x * blockDim.x + threadIdx.x; i < n16; i += stride)
        p[i] = z;
}

__global__ void k_occ0(const void* occraw, uint8_t* occ, const int* flags) {
    long v = (long)blockIdx.x * blockDim.x + threadIdx.x;
    if (v >= N0) return;
    occ[v] = (uint8_t)ldb(occraw, v, flags[1]);
}

__global__ void k_xcast(const void* x, float* xf, const int* flags) {
    long i = (long)blockIdx.x * blockDim.x + threadIdx.x;
    if (i >= (long)N0 * 32) return;
    xf[i] = ldf(x, i, flags[0]);
}

// ---------------- 3-phase scan compaction (zero contended atomics) ---------
__global__ void k_cnt(const uint8_t* __restrict__ occ, long N,
                      int* __restrict__ bcnt, uint8_t* maskz) {
    long v = (long)blockIdx.x * 256 + threadIdx.x;
    int a = (v < N) && occ[v];
    if (maskz && v < N) maskz[v] = 0;
    unsigned long long m = __ballot(a != 0);
    __shared__ int wsum[4];
    int lane = threadIdx.x & 63, wid = threadIdx.x >> 6;
    if (lane == 0) wsum[wid] = (int)__popcll(m);
    __syncthreads();
    if (threadIdx.x == 0)
        bcnt[blockIdx.x] = wsum[0] + wsum[1] + wsum[2] + wsum[3];
}
__global__ void k_scanb(int* __restrict__ bcnt, int nb, int* cnt) {
    __shared__ int tsum[256];
    __shared__ int tpre[257];
    int t = threadIdx.x;
    int ch = (nb + 255) / 256;
    int lo = t * ch, hi = min(lo + ch, nb);
    int s = 0;
    for (int i = lo; i < hi; i++) s += bcnt[i];
    tsum[t] = s;
    __syncthreads();
    if (t == 0) {
        int run = 0;
        for (int j = 0; j < 256; j++) { tpre[j] = run; run += tsum[j]; }
        tpre[256] = run;
        cnt[0] = run;  // total actives
    }
    __syncthreads();
    int run = tpre[t];
    for (int i = lo; i < hi; i++) { int x = bcnt[i]; bcnt[i] = run; run += x; }
}
__global__ void k_fill(const uint8_t* __restrict__ occ, long N,
                       const int* __restrict__ bcnt, int* __restrict__ list) {
    long v = (long)blockIdx.x * 256 + threadIdx.x;
    int a = (v < N) && occ[v];
    unsigned long long m = __ballot(a != 0);
    __shared__ int wsum[4];
    int lane = threadIdx.x & 63, wid = threadIdx.x >> 6;
    if (lane == 0) wsum[wid] = (int)__popcll(m);
    __syncthreads();
    int base = bcnt[blockIdx.x];
    for (int w = 0; w < wid; w++) base += wsum[w];
    if (a) list[base + (int)__popcll(m & ((1ull << lane) - 1ull))] = (int)v;
}

// ---------------- sparse 3^3 conv, CIN->16, relu -------------------------
// R7 post-mortem: per-tap `if(!occ) continue` made a serial chain of 27
// scattered byte loads (~200cyc each) — latency-bound at VALUBusy 39%.
// R8: hoist all 27 occ loads (unconditional, clamped addr, one waitcnt) into
// a 27-bit mask, then __ffs-walk only active taps. Grid-stride (cap GMAX).
template <int CIN, int D>
__global__ void k_sconv16(const float* __restrict__ xin, const void* w, const void* bias,
                          const uint8_t* __restrict__ occ, const int* __restrict__ list,
                          const int* __restrict__ cnt, float* __restrict__ out,
                          const int* __restrict__ flags) {
    __shared__ float wl[27 * CIN * 16 + 16];
    const int n = cnt[0];
    if (blockIdx.x * 256 >= n) return;
    const int bf = flags[0];
    for (int i = threadIdx.x; i < 27 * CIN * 16; i += 256) wl[i] = ldf(w, i, bf);
    if (threadIdx.x < 16) wl[27 * CIN * 16 + threadIdx.x] = ldf(bias, threadIdx.x, bf);
    __syncthreads();
    for (int i = blockIdx.x * 256 + threadIdx.x; i < n; i += gridDim.x * 256) {
        int v = list[i];
        int wd = v % D, hh = (v / D) % D, dd = v / (D * D);
        // hoisted neighbor-occupancy gather: 27 independent loads, 1 wait
        uint32_t nbm = 0u;
        {
            int t = 0;
#pragma unroll
            for (int kd = 0; kd < 3; kd++)
#pragma unroll
                for (int kh = 0; kh < 3; kh++)
#pragma unroll
                    for (int kw = 0; kw < 3; kw++, t++) {
                        int d2 = dd + kd - 1, h2 = hh + kh - 1, w2 = wd + kw - 1;
                        int ok = (int)((unsigned)d2 < (unsigned)D) &
                                 (int)((unsigned)h2 < (unsigned)D) &
                                 (int)((unsigned)w2 < (unsigned)D);
                        int nv = v + (kd - 1) * D * D + (kh - 1) * D + (kw - 1);
                        int nvc = ok ? nv : v;  // clamped: load always valid
                        if ((int)occ[nvc] & ok) nbm |= (1u << t);
                    }
        }
        float acc[16];
#pragma unroll
        for (int co = 0; co < 16; co++) acc[co] = 0.0f;
        while (nbm) {
            int t = __ffs(nbm) - 1;
            nbm &= nbm - 1u;
            int kd = t / 9, r9 = t - kd * 9;
            int kh = r9 / 3, kw = r9 - kh * 3;
            long nv = (long)v + (kd - 1) * (D * D) + (kh - 1) * D + (kw - 1);
            const float4* xp = (const float4*)(xin + nv * CIN);
            const float* wp = &wl[t * CIN * 16];
#pragma unroll
            for (int c4 = 0; c4 < CIN / 4; c4++) {
                float4 x4 = xp[c4];
                const float* wq = wp + c4 * 64;
#pragma unroll
                for (int co = 0; co < 16; co++) acc[co] += x4.x * wq[co];
#pragma unroll
                for (int co = 0; co < 16; co++) acc[co] += x4.y * wq[16 + co];
#pragma unroll
                for (int co = 0; co < 16; co++) acc[co] += x4.z * wq[32 + co];
#pragma unroll
                for (int co = 0; co < 16; co++) acc[co] += x4.w * wq[48 + co];
            }
        }
        float* op = out + (long)v * 16;
#pragma unroll
        for (int co = 0; co < 16; co++) {
            float val = rndb(acc[co], bf);
            val = rndb(val + wl[27 * CIN * 16 + co], bf);
            op[co] = fmaxf(val, 0.0f);
        }
    }
}

// ---------------- sparse cls conv (16->1): d_out slice + position keys -----
template <int D>
__global__ void k_scls(const float* __restrict__ feat, const void* w, const void* bias,
                       const uint8_t* __restrict__ occ, const int* __restrict__ list,
                       const int* __restrict__ cnt, void* dout, long ooff,
                       uint32_t* __restrict__ keyl, const int* __restrict__ flags) {
    __shared__ float wl[27 * 16 + 1];
    const int n = cnt[0];
    if (blockIdx.x * 256 >= n) return;
    const int bf = flags[0];
    for (int i = threadIdx.x; i < 27 * 16; i += 256) wl[i] = ldf(w, i, bf);
    if (threadIdx.x == 0) wl[432] = ldf(bias, 0, bf);
    __syncthreads();
    for (int i = blockIdx.x * 256 + threadIdx.x; i < n; i += gridDim.x * 256) {
        int v = list[i];
        int wd = v % D, hh = (v / D) % D, dd = v / (D * D);
        uint32_t nbm = 0u;
        {
            int t = 0;
#pragma unroll
            for (int kd = 0; kd < 3; kd++)
#pragma unroll
                for (int kh = 0; kh < 3; kh++)
#pragma unroll
                    for (int kw = 0; kw < 3; kw++, t++) {
                        int d2 = dd + kd - 1, h2 = hh + kh - 1, w2 = wd + kw - 1;
                        int ok = (int)((unsigned)d2 < (unsigned)D) &
                                 (int)((unsigned)h2 < (unsigned)D) &
                                 (int)((unsigned)w2 < (unsigned)D);
                        int nv = v + (kd - 1) * D * D + (kh - 1) * D + (kw - 1);
                        int nvc = ok ? nv : v;
                        if ((int)occ[nvc] & ok) nbm |= (1u << t);
                    }
        }
        float acc = 0.0f;
        while (nbm) {
            int t = __ffs(nbm) - 1;
            nbm &= nbm - 1u;
            int kd = t / 9, r9 = t - kd * 9;
            int kh = r9 / 3, kw = r9 - kh * 3;
            long nv = (long)v + (kd - 1) * (D * D) + (kh - 1) * D + (kw - 1);
            const float4* xp = (const float4*)(feat + nv * 16);
            const float* wp = &wl[t * 16];
            float4 a0 = xp[0], a1 = xp[1], a2 = xp[2], a3 = xp[3];
            acc += a0.x * wp[0] + a0.y * wp[1] + a0.z * wp[2] + a0.w * wp[3];
            acc += a1.x * wp[4] + a1.y * wp[5] + a1.z * wp[6] + a1.w * wp[7];
            acc += a2.x * wp[8] + a2.y * wp[9] + a2.z * wp[10] + a2.w * wp[11];
            acc += a3.x * wp[12] + a3.y * wp[13] + a3.z * wp[14] + a3.w * wp[15];
        }
        float val = rndb(acc, bf);
        val = rndb(val + wl[432], bf);
        stf(dout, ooff + v, val, bf);
        keyl[i] = fkey(val);
    }
}

// ---------------- sparse 2x up-sample (transpose conv, kernel-flipped) -----
template <int Dp>
__global__ void k_sup(const float* __restrict__ featp, const void* w, const void* bias,
                      const int* __restrict__ list, const int* __restrict__ cnt,
                      float* __restrict__ hrelu, const int* __restrict__ flags) {
    __shared__ float wl[2048 + 16];
    const int n = cnt[0];
    if (blockIdx.x * 256 >= n) return;
    const int bf = flags[0];
    for (int i = threadIdx.x; i < 2048; i += 256) wl[i] = ldf(w, i, bf);
    if (threadIdx.x < 16) wl[2048 + threadIdx.x] = ldf(bias, threadIdx.x, bf);
    __syncthreads();
    const int D = Dp * 2;
    for (int i = blockIdx.x * 256 + threadIdx.x; i < n; i += gridDim.x * 256) {
        int v = list[i];
        int wd = v % D, hh = (v / D) % D, dd = v / (D * D);
        const float4* xp = (const float4*)(featp +
            ((long)((dd >> 1) * Dp + (hh >> 1)) * Dp + (wd >> 1)) * 16);
        // y[o] = x[o>>1] * w[1-(o&1)] per axis (jax conv_transpose, k=2,s=2,'VALID')
        int a = 1 - (dd & 1), b2 = 1 - (hh & 1), c = 1 - (wd & 1);
        const float* wp = &wl[((a * 2 + b2) * 2 + c) * 256];
        float acc[16];
#pragma unroll
        for (int co = 0; co < 16; co++) acc[co] = 0.0f;
#pragma unroll
        for (int c4 = 0; c4 < 4; c4++) {
            float4 x4 = xp[c4];
            const float* wq = wp + c4 * 64;
#pragma unroll
            for (int co = 0; co < 16; co++) acc[co] += x4.x * wq[co];
#pragma unroll
            for (int co = 0; co < 16; co++) acc[co] += x4.y * wq[16 + co];
#pragma unroll
            for (int co = 0; co < 16; co++) acc[co] += x4.z * wq[32 + co];
#pragma unroll
            for (int co = 0; co < 16; co++) acc[co] += x4.w * wq[48 + co];
        }
        float* op = hrelu + (long)v * 16;
#pragma unroll
        for (int co = 0; co < 16; co++) {
            float val = rndb(acc[co], bf);
            val = rndb(val + wl[2048 + co], bf);
            op[co] = fmaxf(val, 0.0f);  // relu(h) feeding next conv
        }
    }
}

template <int Dp>
__global__ void k_expand(const uint8_t* __restrict__ maskp, uint8_t* __restrict__ occc) {
    const int D = Dp * 2;
    long v = (long)blockIdx.x * blockDim.x + threadIdx.x;
    if (v >= (long)D * D * D) return;
    int wd = (int)(v % D), hh = (int)((v / D) % D), dd = (int)(v / ((long)D * D));
    occc[v] = maskp[((long)(dd >> 1) * Dp + (hh >> 1)) * Dp + (wd >> 1)];
}

// ---------------- exact top-k over position keys (radix-16/16) -------------
// Per-block LDS histogram (R7 win): 65536 bins as packed u16 pairs in 128KB
// LDS; per-block entries <= 8192 so u16 never overflows.
// state: [0]=B(-1 => select-all) [1]=count_above [2]=krem [3]=K [4]=ties_needed [5]=tie_count
__global__ void k_hzero(uint32_t* hist1, int* state) {
    int i = blockIdx.x * blockDim.x + threadIdx.x;
    if (i < 65536) hist1[i] = 0u;
    if (i < 16) state[i] = 0;
}
__global__ void k_hist1(const uint32_t* __restrict__ keyl, const int* cnt,
                        uint32_t* __restrict__ hist) {
    __shared__ uint32_t lh[32768];
    const int n = cnt[0];
    for (int j = threadIdx.x; j < 32768; j += 256) lh[j] = 0u;
    __syncthreads();
    const int stride = gridDim.x * 256;
    for (int i = blockIdx.x * 256 + threadIdx.x; i < n; i += stride) {
        uint32_t bin = keyl[i] >> 16;
        atomicAdd(&lh[bin >> 1], 1u << ((bin & 1u) << 4));
    }
    __syncthreads();
    for (int j = threadIdx.x; j < 32768; j += 256) {
        uint32_t p = lh[j];
        if (p) {
            uint32_t lo = p & 0xFFFFu, hi = p >> 16;
            if (lo) atomicAdd(&hist[2 * j], lo);
            if (hi) atomicAdd(&hist[2 * j + 1], hi);
        }
    }
}
__global__ void k_scan1(const uint32_t* hist, const void* kptr, const int* cnt,
                        int* state, uint32_t* hist2) {
    __shared__ uint32_t part[256];
    int t = threadIdx.x;
    uint32_t s = 0;
    for (int j = 0; j < 256; j++) s += hist[t * 256 + j];
    part[t] = s;
    for (int i = t; i < 65536; i += 256) hist2[i] = 0u;
    __syncthreads();
    if (t == 0) {
        uint32_t k = (uint32_t)((const int*)kptr)[0];
        uint32_t total = (uint32_t)cnt[0];
        if (k >= total) {
            state[0] = -1;
            state[3] = 0;   // K=0 -> sel = (key > 0), true for all finite keys
            state[4] = 0;
            state[5] = 0;
            return;
        }
        uint32_t cum = 0, cab = 0;
        int B = 0;
        for (int c = 255; c >= 0; c--) {
            if (cum + part[c] >= k) {
                uint32_t cc = cum;
                for (int b = c * 256 + 255; b >= c * 256; b--) {
                    uint32_t h = hist[b];
                    if (cc + h >= k) { B = b; cab = cc; break; }
                    cc += h;
                }
                break;
            }
            cum += part[c];
        }
        state[0] = B;
        state[1] = (int)cab;
        state[2] = (int)(k - cab);
    }
}
__global__ void k_hist2(const uint32_t* __restrict__ keyl, const int* cnt,
                        const int* state, uint32_t* __restrict__ hist2) {
    if (state[0] < 0) return;
    __shared__ uint32_t lh[32768];
    const int n = cnt[0];
    const int B = state[0];
    for (int j = threadIdx.x; j < 32768; j += 256) lh[j] = 0u;
    __syncthreads();
    const int stride = gridDim.x * 256;
    for (int i = blockIdx.x * 256 + threadIdx.x; i < n; i += stride) {
        uint32_t key = keyl[i];
        if ((int)(key >> 16) == B) {
            uint32_t bin = key & 0xFFFFu;
            atomicAdd(&lh[bin >> 1], 1u << ((bin & 1u) << 4));
        }
    }
    __syncthreads();
    for (int j = threadIdx.x; j < 32768; j += 256) {
        uint32_t p = lh[j];
        if (p) {
            uint32_t lo = p & 0xFFFFu, hi = p >> 16;
            if (lo) atomicAdd(&hist2[2 * j], lo);
            if (hi) atomicAdd(&hist2[2 * j + 1], hi);
        }
    }
}
__global__ void k_scan2(const uint32_t* hist2, int* state) {
    __shared__ uint32_t part[256];
    int t = threadIdx.x;
    if (state[0] < 0) return;
    uint32_t s = 0;
    for (int j = 0; j < 256; j++) s += hist2[t * 256 + j];
    part[t] = s;
    __syncthreads();
    if (t == 0) {
        uint32_t krem = (uint32_t)state[2];
        uint32_t cum = 0, cl = 0;
        int L = 0;
        for (int c = 255; c >= 0; c--) {
            if (cum + part[c] >= krem) {
                uint32_t cc = cum;
                for (int b = c * 256 + 255; b >= c * 256; b--) {
                    uint32_t h = hist2[b];
                    if (cc + h >= krem) { L = b; cl = cc; break; }
                    cc += h;
                }
                break;
            }
            cum += part[c];
        }
        uint32_t K = ((uint32_t)state[0] << 16) | (uint32_t)L;
        state[3] = (int)K;
        state[4] = (int)(krem - cl);
        state[5] = 0;
    }
}
// tie collection wave-aggregated: one atomicAdd-with-return per wave
__global__ void k_mark(const uint32_t* __restrict__ keyl, const int* __restrict__ list,
                       const int* cnt, int* state, uint8_t* __restrict__ sel, int* tiel) {
    int n = cnt[0];
    int i = blockIdx.x * 256 + threadIdx.x;
    uint32_t K = (uint32_t)state[3];
    int v = 0, isTie = 0;
    if (i < n) {
        uint32_t key = keyl[i];
        v = list[i];
        sel[v] = (key > K) ? (uint8_t)1 : (uint8_t)0;
        isTie = (key == K && K != 0u);
    }
    unsigned long long m = __ballot(isTie != 0);
    if (m) {
        int lane = threadIdx.x & 63;
        int leader = __ffsll((unsigned long long)m) - 1;
        int base = 0;
        if (lane == leader) base = atomicAdd(&state[5], (int)__popcll(m));
        base = __shfl(base, leader, 64);
        if (isTie) {
            int pos = base + (int)__popcll(m & ((1ull << lane) - 1ull));
            if (pos < TIE_CAP) tiel[pos] = v;
        }
    }
}
// ties at the threshold key: jax.lax.top_k keeps LOWEST voxel indices first
__global__ void k_ties(const int* state, const int* tiel, uint8_t* sel) {
    __shared__ int lst[TIE_CAP];
    int T = state[5];
    if (T > TIE_CAP) T = TIE_CAP;
    int need = state[4];
    if (need <= 0 || T == 0) return;
    for (int i = threadIdx.x; i < T; i += blockDim.x) lst[i] = tiel[i];
    __syncthreads();
    for (int e = threadIdx.x; e < T; e += blockDim.x) {
        int idx = lst[e], r = 0;
        for (int j = 0; j < T; j++) r += (lst[j] < idx) ? 1 : 0;
        if (r < need) sel[idx] = 1;
    }
}
// prune for levels 0/1: write dense mask (pre-zeroed by k_cnt) at actives.
__global__ void k_sapply(const uint8_t* __restrict__ sel, const int* __restrict__ list,
                         const int* cnt, const void* gt, uint8_t* __restrict__ mask,
                         const int* flags) {
    int n = cnt[0];
    int i = blockIdx.x * 256 + threadIdx.x;
    if (i >= n) return;
    int v = list[i];
    mask[v] = (uint8_t)(sel[v] || ldb(gt, v, flags[1]));
}
// final level: scatter masked features straight into pre-zeroed d_out
__global__ void k_sapply_out(const uint8_t* __restrict__ sel, const int* __restrict__ list,
                             const int* cnt, const void* gt, const float* __restrict__ feat,
                             void* dout, const int* flags) {
    int n = cnt[0];
    int i = blockIdx.x * 256 + threadIdx.x;
    if (i >= n) return;
    int v = list[i];
    if (!(sel[v] || ldb(gt, v, flags[1]))) return;
    const int bf = flags[0];
    long base = OFF_OUT + (long)v * 16;
    const float* fp = feat + (long)v * 16;
#pragma unroll
    for (int co = 0; co < 16; co++) stf(dout, base + co, fp[co], bf);
}

// ---------------- launcher ----------------
extern "C" void kernel_launch(void* const* d_in, const int* in_sizes, int n_in,
                              void* d_out, int out_size, void* d_ws, size_t ws_size,
                              hipStream_t stream) {
    char* ws = (char*)d_ws;
    int* flags = (int*)(ws + O_FLAGS);
    int* cnt = flags + 32;
    int* state = (int*)(ws + O_STATE);
    int* tiel = (int*)(ws + O_TIE);
    uint32_t* h1 = (uint32_t*)(ws + O_HIST1);
    uint32_t* h2 = (uint32_t*)(ws + O_HIST2);
    uint8_t* occ0 = (uint8_t*)(ws + O_OCC0);
    uint8_t* occ1 = (uint8_t*)(ws + O_OCC1);
    uint8_t* occ2 = (uint8_t*)(ws + O_OCC2);
    uint8_t* mask0 = (uint8_t*)(ws + O_MASK0);
    uint8_t* mask1 = (uint8_t*)(ws + O_MASK1);
    int* bcnt = (int*)(ws + O_BCNT);
    uint8_t* sel = (uint8_t*)(ws + O_SEL);
    uint32_t* keyl = (uint32_t*)(ws + O_KEYS);
    float* feat0 = (float*)(ws + O_FEAT0);
    float* hr1 = (float*)(ws + O_HR1);
    float* feat1 = (float*)(ws + O_FEAT1);
    float* hr2 = (float*)(ws + O_HR2);
    float* feat2 = (float*)(ws + O_FEAT2);
    // aliased scratch (lifetimes verified disjoint):
    int* list0 = (int*)(ws + O_HR1);                      // lvl0; hr1 written at lvl1
    int* list1 = (int*)(ws + O_HR2);                      // lvl1; hr2 written at lvl2
    int* list2 = (int*)(ws + O_HR1);                      // lvl2; hr1 dead after lvl1 conv
    float* xf = (float*)(ws + O_HR2 + (4UL << 20));       // lvl0 only; 4 MB

    const int G1 = N1 / 256;                // 1024
    const int G2 = GMAX;                    // 2048 (grid-stride covers up to N2)

    // inputs: 0:x 1:occ0 2:gt0 3:gt1 4:gt2 5:w_conv0 6:b_conv0 7:w_cls0 8:b_cls0
    // 9:w_up1 10:b_up1 11:w_conv1 12:b_conv1 13:w_cls1 14:b_cls1
    // 15:w_up2 16:b_up2 17:w_conv2 18:b_conv2 19:w_cls2 20:b_cls2 21-23:nums
    k_fzero<<<1, 64, 0, stream>>>(flags);
    k_fscan<<<512, 256, 0, stream>>>(d_in[0], d_in[4], flags);
    k_ffinal<<<1, 64, 0, stream>>>(flags);
    k_zout<<<2048, 256, 0, stream>>>(d_out, (long)out_size, flags);
    k_occ0<<<N0 / 256, 256, 0, stream>>>(d_in[1], occ0, flags);
    k_xcast<<<(N0 * 32) / 256, 256, 0, stream>>>(d_in[0], xf, flags);

    // ---- level 0
    k_cnt<<<N0 / 256, 256, 0, stream>>>(occ0, N0, bcnt, mask0);
    k_scanb<<<1, 256, 0, stream>>>(bcnt, N0 / 256, cnt);
    k_fill<<<N0 / 256, 256, 0, stream>>>(occ0, N0, bcnt, list0);
    k_sconv16<32, 32><<<N0 / 256, 256, 0, stream>>>(xf, d_in[5], d_in[6], occ0,
                                                    list0, cnt, feat0, flags);
    k_scls<32><<<N0 / 256, 256, 0, stream>>>(feat0, d_in[7], d_in[8], occ0, list0,
                                             cnt, d_out, OFF_CLS0, keyl, flags);
    k_hzero<<<256, 256, 0, stream>>>(h1, state);
    k_hist1<<<256, 256, 0, stream>>>(keyl, cnt, h1);
    k_scan1<<<1, 256, 0, stream>>>(h1, d_in[21], cnt, state, h2);
    k_hist2<<<256, 256, 0, stream>>>(keyl, cnt, state, h2);
    k_scan2<<<1, 256, 0, stream>>>(h2, state);
    k_mark<<<N0 / 256, 256, 0, stream>>>(keyl, list0, cnt, state, sel, tiel);
    k_ties<<<1, 1024, 0, stream>>>(state, tiel, sel);
    k_sapply<<<N0 / 256, 256, 0, stream>>>(sel, list0, cnt, d_in[2], mask0, flags);

    // ---- level 1
    k_expand<32><<<N1 / 256, 256, 0, stream>>>(mask0, occ1);
    k_cnt<<<N1 / 256, 256, 0, stream>>>(occ1, N1, bcnt, mask1);
    k_scanb<<<1, 256, 0, stream>>>(bcnt, N1 / 256, cnt);
    k_fill<<<N1 / 256, 256, 0, stream>>>(occ1, N1, bcnt, list1);
    k_sup<32><<<G1, 256, 0, stream>>>(feat0, d_in[9], d_in[10], list1, cnt,
                                      hr1, flags);
    k_sconv16<16, 64><<<G1, 256, 0, stream>>>(hr1, d_in[11], d_in[12], occ1,
                                              list1, cnt, feat1, flags);
    k_scls<64><<<G1, 256, 0, stream>>>(feat1, d_in[13], d_in[14], occ1, list1,
                                       cnt, d_out, OFF_CLS1, keyl, flags);
    k_hzero<<<256, 256, 0, stream>>>(h1, state);
    k_hist1<<<256, 256, 0, stream>>>(keyl, cnt, h1);
    k_scan1<<<1, 256, 0, stream>>>(h1, d_in[22], cnt, state, h2);
    k_hist2<<<256, 256, 0, stream>>>(keyl, cnt, state, h2);
    k_scan2<<<1, 256, 0, stream>>>(h2, state);
    k_mark<<<N1 / 256, 256, 0, stream>>>(keyl, list1, cnt, state, sel, tiel);
    k_ties<<<1, 1024, 0, stream>>>(state, tiel, sel);
    k_sapply<<<N1 / 256, 256, 0, stream>>>(sel, list1, cnt, d_in[3], mask1, flags);

    // ---- level 2
    k_expand<64><<<N2 / 256, 256, 0, stream>>>(mask1, occ2);
    k_cnt<<<N2 / 256, 256, 0, stream>>>(occ2, N2, bcnt, (uint8_t*)0);
    k_scanb<<<1, 256, 0, stream>>>(bcnt, N2 / 256, cnt);
    k_fill<<<N2 / 256, 256, 0, stream>>>(occ2, N2, bcnt, list2);
    k_sup<64><<<G2, 256, 0, stream>>>(feat1, d_in[15], d_in[16], list2, cnt,
                                      hr2, flags);
    k_sconv16<16, 128><<<G2, 256, 0, stream>>>(hr2, d_in[17], d_in[18], occ2,
                                               list2, cnt, feat2, flags);
    k_scls<128><<<G2, 256, 0, stream>>>(feat2, d_in[19], d_in[20], occ2, list2,
                                        cnt, d_out, OFF_CLS2, keyl, flags);
    k_hzero<<<256, 256, 0, stream>>>(h1, state);
    k_hist1<<<256, 256, 0, stream>>>(keyl, cnt, h1);
    k_scan1<<<1, 256, 0, stream>>>(h1, d_in[23], cnt, state, h2);
    k_hist2<<<256, 256, 0, stream>>>(keyl, cnt, state, h2);
    k_scan2<<<1, 256, 0, stream>>>(h2, state);
    k_mark<<<N2 / 256, 256, 0, stream>>>(keyl, list2, cnt, state, sel, tiel);
    k_ties<<<1, 1024, 0, stream>>>(state, tiel, sel);
    k_sapply_out<<<N2 / 256, 256, 0, stream>>>(sel, list2, cnt, d_in[4], feat2,
                                               d_out, flags);
}

// Round 9
// 1211.862 us; speedup vs baseline: 1.0488x; 1.0488x over previous
//
#include <hip/hip_runtime.h>
#include <stdint.h>

// ---------------- problem constants ----------------
#define N0 32768      // 32^3
#define N1 262144     // 64^3
#define N2 2097152    // 128^3

// d_out element offsets (cls0, cls1, cls2, out)
#define OFF_CLS0 0L
#define OFF_CLS1 32768L
#define OFF_CLS2 294912L
#define OFF_OUT  2392064L

// ---------------- ws layout (byte offsets, within proven ~320MB footprint) --
#define O_FLAGS 0UL            // int[64]: [0]=bf16 [1]=boolmode [8..]=counters [32]=list cnt
#define O_STATE 256UL
#define O_TIE   512UL          // 16000 ints (tie voxel-index list)
#define O_HIST1 66048UL        // 65536 u32
#define O_HIST2 328192UL       // 65536 u32
#define O_OCC0  590336UL       // N0 u8
#define O_OCC1  623104UL       // N1 u8
#define O_OCC2  885248UL       // N2 u8
#define O_MASK0 2982400UL
#define O_MASK1 3015168UL
#define O_BCNT  3277312UL      // 8192 ints (block counts / exclusive prefix)
#define O_SEL   5374464UL      // N2 u8 (dense by voxel, only active entries used)
#define O_KEYS  7471616UL      // N2 u32 keyl[] by LIST POSITION
#define O_FEAT0 15860224UL     // N0*16 f32
#define O_HR1   17957376UL     // N1*16 f32 ; ALIASED: list0 (lvl0), list2 (lvl2, hr1 dead)
#define O_FEAT1 34734592UL     // N1*16 f32
#define O_HR2   51511808UL     // N2*16 f32 ; ALIASED: list1 @+0 (lvl1), xf @+4MB (lvl0)
#define O_FEAT2 185729536UL    // N2*16 f32  (ends ~320 MB)

#define TIE_CAP 16000
#define GMAX 2048              // grid cap for grid-stride sparse kernels

// ---------------- dtype-flexible helpers ----------------
// flags[0] = floats-are-bf16; flags[1] = bool mode (0 i32,1 u8,2 bf16,3 f32,4 i64)
__device__ __forceinline__ float ldf(const void* p, long i, int bf) {
    if (bf) {
        uint16_t h = ((const uint16_t*)p)[i];
        return __uint_as_float(((uint32_t)h) << 16);
    }
    return ((const float*)p)[i];
}
__device__ __forceinline__ int ldb(const void* p, long i, int m) {
    switch (m) {
        case 0: return ((const int*)p)[i] != 0;
        case 1: return ((const uint8_t*)p)[i] != 0;
        case 2: { uint16_t h = ((const uint16_t*)p)[i]; return (h & 0x7FFF) != 0; }
        case 4: return ((const long long*)p)[i] != 0;
        default: { float f = ((const float*)p)[i]; return f != 0.0f; }
    }
}
__device__ __forceinline__ float rndb(float f, int en) {
    if (!en) return f;
    uint32_t u = __float_as_uint(f);
    u += 0x7FFFu + ((u >> 16) & 1u);
    u &= 0xFFFF0000u;
    return __uint_as_float(u);
}
__device__ __forceinline__ void stf(void* p, long i, float v, int bf) {
    if (bf) {
        uint32_t u = __float_as_uint(v);
        u += 0x7FFFu + ((u >> 16) & 1u);
        ((uint16_t*)p)[i] = (uint16_t)(u >> 16);
    } else {
        ((float*)p)[i] = v;
    }
}
// order-preserving float->u32 key; all finite keys are > 0
__device__ __forceinline__ uint32_t fkey(float f) {
    f = f + 0.0f;
    uint32_t u = __float_as_uint(f);
    return (u & 0x80000000u) ? ~u : (u | 0x80000000u);
}

// ---------------- runtime dtype detection (parallel) ----------------------
__global__ void k_fzero(int* flags) {
    int t = threadIdx.x;
    if (t < 16) flags[8 + t] = 0;
}
__global__ void k_fscan(const void* x, const void* gt2, int* flags) {
    int* cnt = flags + 8;
    __shared__ int lc[8];
    int t = threadIdx.x;
    if (t < 8) lc[t] = 0;
    __syncthreads();
    long gid = (long)blockIdx.x * blockDim.x + threadIdx.x;
    long gstride = (long)gridDim.x * blockDim.x;
    int ltiny = 0;
    const uint32_t* xu = (const uint32_t*)x;
    for (long i = gid; i < 524288; i += gstride) {
        uint32_t u = xu[i];
        uint32_t e = (u >> 23) & 0xFFu;
        if (e == 0u && (u & 0x7FFFFFu) != 0u) ltiny++;
    }
    int l1off = 0, l1any = 0, l3f = 0, l84 = 0;
    const uint8_t* g = (const uint8_t*)gt2;
    for (long i = gid; i < 2097152; i += gstride) {
        uint8_t b = g[i];
        if (b == 1u) {
            l1any++;
            if ((i & 3) != 0) l1off++;
            if ((i & 7) == 4) l84++;
        }
        if (b == 0x3Fu && (i & 3) == 1) l3f++;
    }
    if (ltiny) atomicAdd(&lc[0], ltiny);
    if (l1off) atomicAdd(&lc[1], l1off);
    if (l1any) atomicAdd(&lc[2], l1any);
    if (l3f)   atomicAdd(&lc[3], l3f);
    if (l84)   atomicAdd(&lc[4], l84);
    __syncthreads();
    if (t < 5 && lc[t]) atomicAdd(&cnt[t], lc[t]);
}
__global__ void k_ffinal(int* flags) {
    if (threadIdx.x != 0 || blockIdx.x != 0) return;
    const int* cnt = flags + 8;
    flags[0] = (cnt[0] > 8) ? 1 : 0;
    int bm;
    if (cnt[1] > 8)       bm = 1;
    else if (cnt[2] > 8)  bm = (cnt[4] > 8) ? 0 : 4;
    else if (cnt[3] > 8)  bm = 2;
    else                  bm = 3;
    flags[1] = bm;
}

// zero entire d_out (harness re-poisons to 0xAA each launch)
__global__ void k_zout(void* dout, long out_elems, const int* flags) {
    long bytes = out_elems * (flags[0] ? 2 : 4);
    long n16 = bytes >> 4;
    uint4 z = make_uint4(0, 0, 0, 0);
    uint4* p = (uint4*)dout;
    long stride = (long)gridDim.x * blockDim.x;
    for (long i = (long)blockIdx.x * blockDim.x + threadIdx.x; i < n16; i += stride)
        p[i] = z;
}

__global__ void k_occ0(const void* occraw, uint8_t* occ, const int* flags) {
    long v = (long)blockIdx.x * blockDim.x + threadIdx.x;
    if (v >= N0) return;
    occ[v] = (uint8_t)ldb(occraw, v, flags[1]);
}

__global__ void k_xcast(const void* x, float* xf, const int* flags) {
    long i = (long)blockIdx.x * blockDim.x + threadIdx.x;
    if (i >= (long)N0 * 32) return;
    xf[i] = ldf(x, i, flags[0]);
}

// ---------------- 3-phase scan compaction (zero contended atomics) ---------
__global__ void k_cnt(const uint8_t* __restrict__ occ, long N,
                      int* __restrict__ bcnt, uint8_t* maskz) {
    long v = (long)blockIdx.x * 256 + threadIdx.x;
    int a = (v < N) && occ[v];
    if (maskz && v < N) maskz[v] = 0;
    unsigned long long m = __ballot(a != 0);
    __shared__ int wsum[4];
    int lane = threadIdx.x & 63, wid = threadIdx.x >> 6;
    if (lane == 0) wsum[wid] = (int)__popcll(m);
    __syncthreads();
    if (threadIdx.x == 0)
        bcnt[blockIdx.x] = wsum[0] + wsum[1] + wsum[2] + wsum[3];
}
__global__ void k_scanb(int* __restrict__ bcnt, int nb, int* cnt) {
    __shared__ int tsum[256];
    __shared__ int tpre[257];
    int t = threadIdx.x;
    int ch = (nb + 255) / 256;
    int lo = t * ch, hi = min(lo + ch, nb);
    int s = 0;
    for (int i = lo; i < hi; i++) s += bcnt[i];
    tsum[t] = s;
    __syncthreads();
    if (t == 0) {
        int run = 0;
        for (int j = 0; j < 256; j++) { tpre[j] = run; run += tsum[j]; }
        tpre[256] = run;
        cnt[0] = run;  // total actives
    }
    __syncthreads();
    int run = tpre[t];
    for (int i = lo; i < hi; i++) { int x = bcnt[i]; bcnt[i] = run; run += x; }
}
__global__ void k_fill(const uint8_t* __restrict__ occ, long N,
                       const int* __restrict__ bcnt, int* __restrict__ list) {
    long v = (long)blockIdx.x * 256 + threadIdx.x;
    int a = (v < N) && occ[v];
    unsigned long long m = __ballot(a != 0);
    __shared__ int wsum[4];
    int lane = threadIdx.x & 63, wid = threadIdx.x >> 6;
    if (lane == 0) wsum[wid] = (int)__popcll(m);
    __syncthreads();
    int base = bcnt[blockIdx.x];
    for (int w = 0; w < wid; w++) base += wsum[w];
    if (a) list[base + (int)__popcll(m & ((1ull << lane) - 1ull))] = (int)v;
}

// ---------------- sparse 3^3 conv, CIN->16, relu -------------------------
// R8 post-mortem: per-lane __ffs tap-walk made weight-LDS reads divergent ->
// 1.3e8 bank-conflict cycles (0 before). R9: keep the hoisted 27-load occ
// mask (removes R7's serial load->branch chain) but iterate taps with a
// WAVE-UNIFORM t, predicating per lane — weight reads are broadcasts again.
template <int CIN, int D>
__global__ void k_sconv16(const float* __restrict__ xin, const void* w, const void* bias,
                          const uint8_t* __restrict__ occ, const int* __restrict__ list,
                          const int* __restrict__ cnt, float* __restrict__ out,
                          const int* __restrict__ flags) {
    __shared__ float wl[27 * CIN * 16 + 16];
    const int n = cnt[0];
    if (blockIdx.x * 256 >= n) return;
    const int bf = flags[0];
    for (int i = threadIdx.x; i < 27 * CIN * 16; i += 256) wl[i] = ldf(w, i, bf);
    if (threadIdx.x < 16) wl[27 * CIN * 16 + threadIdx.x] = ldf(bias, threadIdx.x, bf);
    __syncthreads();
    for (int i = blockIdx.x * 256 + threadIdx.x; i < n; i += gridDim.x * 256) {
        int v = list[i];
        int wd = v % D, hh = (v / D) % D, dd = v / (D * D);
        // hoisted neighbor-occupancy gather: 27 independent loads, 1 wait
        uint32_t nbm = 0u;
        {
            int t = 0;
#pragma unroll
            for (int kd = 0; kd < 3; kd++)
#pragma unroll
                for (int kh = 0; kh < 3; kh++)
#pragma unroll
                    for (int kw = 0; kw < 3; kw++, t++) {
                        int d2 = dd + kd - 1, h2 = hh + kh - 1, w2 = wd + kw - 1;
                        int ok = (int)((unsigned)d2 < (unsigned)D) &
                                 (int)((unsigned)h2 < (unsigned)D) &
                                 (int)((unsigned)w2 < (unsigned)D);
                        int nv = v + (kd - 1) * D * D + (kh - 1) * D + (kw - 1);
                        int nvc = ok ? nv : v;  // clamped: load always valid
                        if ((int)occ[nvc] & ok) nbm |= (1u << t);
                    }
        }
        float acc[16];
#pragma unroll
        for (int co = 0; co < 16; co++) acc[co] = 0.0f;
        // wave-uniform tap loop; per-lane predication only (exec mask)
        for (int t = 0; t < 27; t++) {
            if (nbm & (1u << t)) {
                int kd = t / 9, r9 = t - kd * 9;
                int kh = r9 / 3, kw = r9 - kh * 3;
                long nv = (long)v + (kd - 1) * (D * D) + (kh - 1) * D + (kw - 1);
                const float4* xp = (const float4*)(xin + nv * CIN);
                const float* wp = &wl[t * CIN * 16];  // uniform addr -> broadcast
#pragma unroll
                for (int c4 = 0; c4 < CIN / 4; c4++) {
                    float4 x4 = xp[c4];
                    const float* wq = wp + c4 * 64;
#pragma unroll
                    for (int co = 0; co < 16; co++) acc[co] += x4.x * wq[co];
#pragma unroll
                    for (int co = 0; co < 16; co++) acc[co] += x4.y * wq[16 + co];
#pragma unroll
                    for (int co = 0; co < 16; co++) acc[co] += x4.z * wq[32 + co];
#pragma unroll
                    for (int co = 0; co < 16; co++) acc[co] += x4.w * wq[48 + co];
                }
            }
        }
        float* op = out + (long)v * 16;
#pragma unroll
        for (int co = 0; co < 16; co++) {
            float val = rndb(acc[co], bf);
            val = rndb(val + wl[27 * CIN * 16 + co], bf);
            op[co] = fmaxf(val, 0.0f);
        }
    }
}

// ---------------- sparse cls conv (16->1): d_out slice + position keys -----
template <int D>
__global__ void k_scls(const float* __restrict__ feat, const void* w, const void* bias,
                       const uint8_t* __restrict__ occ, const int* __restrict__ list,
                       const int* __restrict__ cnt, void* dout, long ooff,
                       uint32_t* __restrict__ keyl, const int* __restrict__ flags) {
    __shared__ float wl[27 * 16 + 1];
    const int n = cnt[0];
    if (blockIdx.x * 256 >= n) return;
    const int bf = flags[0];
    for (int i = threadIdx.x; i < 27 * 16; i += 256) wl[i] = ldf(w, i, bf);
    if (threadIdx.x == 0) wl[432] = ldf(bias, 0, bf);
    __syncthreads();
    for (int i = blockIdx.x * 256 + threadIdx.x; i < n; i += gridDim.x * 256) {
        int v = list[i];
        int wd = v % D, hh = (v / D) % D, dd = v / (D * D);
        uint32_t nbm = 0u;
        {
            int t = 0;
#pragma unroll
            for (int kd = 0; kd < 3; kd++)
#pragma unroll
                for (int kh = 0; kh < 3; kh++)
#pragma unroll
                    for (int kw = 0; kw < 3; kw++, t++) {
                        int d2 = dd + kd - 1, h2 = hh + kh - 1, w2 = wd + kw - 1;
                        int ok = (int)((unsigned)d2 < (unsigned)D) &
                                 (int)((unsigned)h2 < (unsigned)D) &
                                 (int)((unsigned)w2 < (unsigned)D);
                        int nv = v + (kd - 1) * D * D + (kh - 1) * D + (kw - 1);
                        int nvc = ok ? nv : v;
                        if ((int)occ[nvc] & ok) nbm |= (1u << t);
                    }
        }
        float acc = 0.0f;
        for (int t = 0; t < 27; t++) {
            if (nbm & (1u << t)) {
                int kd = t / 9, r9 = t - kd * 9;
                int kh = r9 / 3, kw = r9 - kh * 3;
                long nv = (long)v + (kd - 1) * (D * D) + (kh - 1) * D + (kw - 1);
                const float4* xp = (const float4*)(feat + nv * 16);
                const float* wp = &wl[t * 16];  // uniform addr -> broadcast
                float4 a0 = xp[0], a1 = xp[1], a2 = xp[2], a3 = xp[3];
                acc += a0.x * wp[0] + a0.y * wp[1] + a0.z * wp[2] + a0.w * wp[3];
                acc += a1.x * wp[4] + a1.y * wp[5] + a1.z * wp[6] + a1.w * wp[7];
                acc += a2.x * wp[8] + a2.y * wp[9] + a2.z * wp[10] + a2.w * wp[11];
                acc += a3.x * wp[12] + a3.y * wp[13] + a3.z * wp[14] + a3.w * wp[15];
            }
        }
        float val = rndb(acc, bf);
        val = rndb(val + wl[432], bf);
        stf(dout, ooff + v, val, bf);
        keyl[i] = fkey(val);
    }
}

// ---------------- sparse 2x up-sample (transpose conv, kernel-flipped) -----
template <int Dp>
__global__ void k_sup(const float* __restrict__ featp, const void* w, const void* bias,
                      const int* __restrict__ list, const int* __restrict__ cnt,
                      float* __restrict__ hrelu, const int* __restrict__ flags) {
    __shared__ float wl[2048 + 16];
    const int n = cnt[0];
    if (blockIdx.x * 256 >= n) return;
    const int bf = flags[0];
    for (int i = threadIdx.x; i < 2048; i += 256) wl[i] = ldf(w, i, bf);
    if (threadIdx.x < 16) wl[2048 + threadIdx.x] = ldf(bias, threadIdx.x, bf);
    __syncthreads();
    const int D = Dp * 2;
    for (int i = blockIdx.x * 256 + threadIdx.x; i < n; i += gridDim.x * 256) {
        int v = list[i];
        int wd = v % D, hh = (v / D) % D, dd = v / (D * D);
        const float4* xp = (const float4*)(featp +
            ((long)((dd >> 1) * Dp + (hh >> 1)) * Dp + (wd >> 1)) * 16);
        // y[o] = x[o>>1] * w[1-(o&1)] per axis (jax conv_transpose, k=2,s=2,'VALID')
        int a = 1 - (dd & 1), b2 = 1 - (hh & 1), c = 1 - (wd & 1);
        const float* wp = &wl[((a * 2 + b2) * 2 + c) * 256];
        float acc[16];
#pragma unroll
        for (int co = 0; co < 16; co++) acc[co] = 0.0f;
#pragma unroll
        for (int c4 = 0; c4 < 4; c4++) {
            float4 x4 = xp[c4];
            const float* wq = wp + c4 * 64;
#pragma unroll
            for (int co = 0; co < 16; co++) acc[co] += x4.x * wq[co];
#pragma unroll
            for (int co = 0; co < 16; co++) acc[co] += x4.y * wq[16 + co];
#pragma unroll
            for (int co = 0; co < 16; co++) acc[co] += x4.z * wq[32 + co];
#pragma unroll
            for (int co = 0; co < 16; co++) acc[co] += x4.w * wq[48 + co];
        }
        float* op = hrelu + (long)v * 16;
#pragma unroll
        for (int co = 0; co < 16; co++) {
            float val = rndb(acc[co], bf);
            val = rndb(val + wl[2048 + co], bf);
            op[co] = fmaxf(val, 0.0f);  // relu(h) feeding next conv
        }
    }
}

template <int Dp>
__global__ void k_expand(const uint8_t* __restrict__ maskp, uint8_t* __restrict__ occc) {
    const int D = Dp * 2;
    long v = (long)blockIdx.x * blockDim.x + threadIdx.x;
    if (v >= (long)D * D * D) return;
    int wd = (int)(v % D), hh = (int)((v / D) % D), dd = (int)(v / ((long)D * D));
    occc[v] = maskp[((long)(dd >> 1) * Dp + (hh >> 1)) * Dp + (wd >> 1)];
}

// ---------------- exact top-k over position keys (radix-16/16) -------------
// Per-block LDS histogram (R7 win): 65536 bins as packed u16 pairs in 128KB
// LDS; per-block entries <= 8192 so u16 never overflows.
// state: [0]=B(-1 => select-all) [1]=count_above [2]=krem [3]=K [4]=ties_needed [5]=tie_count
__global__ void k_hzero(uint32_t* hist1, int* state) {
    int i = blockIdx.x * blockDim.x + threadIdx.x;
    if (i < 65536) hist1[i] = 0u;
    if (i < 16) state[i] = 0;
}
__global__ void k_hist1(const uint32_t* __restrict__ keyl, const int* cnt,
                        uint32_t* __restrict__ hist) {
    __shared__ uint32_t lh[32768];
    const int n = cnt[0];
    for (int j = threadIdx.x; j < 32768; j += 256) lh[j] = 0u;
    __syncthreads();
    const int stride = gridDim.x * 256;
    for (int i = blockIdx.x * 256 + threadIdx.x; i < n; i += stride) {
        uint32_t bin = keyl[i] >> 16;
        atomicAdd(&lh[bin >> 1], 1u << ((bin & 1u) << 4));
    }
    __syncthreads();
    for (int j = threadIdx.x; j < 32768; j += 256) {
        uint32_t p = lh[j];
        if (p) {
            uint32_t lo = p & 0xFFFFu, hi = p >> 16;
            if (lo) atomicAdd(&hist[2 * j], lo);
            if (hi) atomicAdd(&hist[2 * j + 1], hi);
        }
    }
}
__global__ void k_scan1(const uint32_t* hist, const void* kptr, const int* cnt,
                        int* state, uint32_t* hist2) {
    __shared__ uint32_t part[256];
    int t = threadIdx.x;
    uint32_t s = 0;
    for (int j = 0; j < 256; j++) s += hist[t * 256 + j];
    part[t] = s;
    for (int i = t; i < 65536; i += 256) hist2[i] = 0u;
    __syncthreads();
    if (t == 0) {
        uint32_t k = (uint32_t)((const int*)kptr)[0];
        uint32_t total = (uint32_t)cnt[0];
        if (k >= total) {
            state[0] = -1;
            state[3] = 0;   // K=0 -> sel = (key > 0), true for all finite keys
            state[4] = 0;
            state[5] = 0;
            return;
        }
        uint32_t cum = 0, cab = 0;
        int B = 0;
        for (int c = 255; c >= 0; c--) {
            if (cum + part[c] >= k) {
                uint32_t cc = cum;
                for (int b = c * 256 + 255; b >= c * 256; b--) {
                    uint32_t h = hist[b];
                    if (cc + h >= k) { B = b; cab = cc; break; }
                    cc += h;
                }
                break;
            }
            cum += part[c];
        }
        state[0] = B;
        state[1] = (int)cab;
        state[2] = (int)(k - cab);
    }
}
__global__ void k_hist2(const uint32_t* __restrict__ keyl, const int* cnt,
                        const int* state, uint32_t* __restrict__ hist2) {
    if (state[0] < 0) return;
    __shared__ uint32_t lh[32768];
    const int n = cnt[0];
    const int B = state[0];
    for (int j = threadIdx.x; j < 32768; j += 256) lh[j] = 0u;
    __syncthreads();
    const int stride = gridDim.x * 256;
    for (int i = blockIdx.x * 256 + threadIdx.x; i < n; i += stride) {
        uint32_t key = keyl[i];
        if ((int)(key >> 16) == B) {
            uint32_t bin = key & 0xFFFFu;
            atomicAdd(&lh[bin >> 1], 1u << ((bin & 1u) << 4));
        }
    }
    __syncthreads();
    for (int j = threadIdx.x; j < 32768; j += 256) {
        uint32_t p = lh[j];
        if (p) {
            uint32_t lo = p & 0xFFFFu, hi = p >> 16;
            if (lo) atomicAdd(&hist2[2 * j], lo);
            if (hi) atomicAdd(&hist2[2 * j + 1], hi);
        }
    }
}
__global__ void k_scan2(const uint32_t* hist2, int* state) {
    __shared__ uint32_t part[256];
    int t = threadIdx.x;
    if (state[0] < 0) return;
    uint32_t s = 0;
    for (int j = 0; j < 256; j++) s += hist2[t * 256 + j];
    part[t] = s;
    __syncthreads();
    if (t == 0) {
        uint32_t krem = (uint32_t)state[2];
        uint32_t cum = 0, cl = 0;
        int L = 0;
        for (int c = 255; c >= 0; c--) {
            if (cum + part[c] >= krem) {
                uint32_t cc = cum;
                for (int b = c * 256 + 255; b >= c * 256; b--) {
                    uint32_t h = hist2[b];
                    if (cc + h >= krem) { L = b; cl = cc; break; }
                    cc += h;
                }
                break;
            }
            cum += part[c];
        }
        uint32_t K = ((uint32_t)state[0] << 16) | (uint32_t)L;
        state[3] = (int)K;
        state[4] = (int)(krem - cl);
        state[5] = 0;
    }
}
// tie collection wave-aggregated: one atomicAdd-with-return per wave
__global__ void k_mark(const uint32_t* __restrict__ keyl, const int* __restrict__ list,
                       const int* cnt, int* state, uint8_t* __restrict__ sel, int* tiel) {
    int n = cnt[0];
    int i = blockIdx.x * 256 + threadIdx.x;
    uint32_t K = (uint32_t)state[3];
    int v = 0, isTie = 0;
    if (i < n) {
        uint32_t key = keyl[i];
        v = list[i];
        sel[v] = (key > K) ? (uint8_t)1 : (uint8_t)0;
        isTie = (key == K && K != 0u);
    }
    unsigned long long m = __ballot(isTie != 0);
    if (m) {
        int lane = threadIdx.x & 63;
        int leader = __ffsll((unsigned long long)m) - 1;
        int base = 0;
        if (lane == leader) base = atomicAdd(&state[5], (int)__popcll(m));
        base = __shfl(base, leader, 64);
        if (isTie) {
            int pos = base + (int)__popcll(m & ((1ull << lane) - 1ull));
            if (pos < TIE_CAP) tiel[pos] = v;
        }
    }
}
// ties at the threshold key: jax.lax.top_k keeps LOWEST voxel indices first
__global__ void k_ties(const int* state, const int* tiel, uint8_t* sel) {
    __shared__ int lst[TIE_CAP];
    int T = state[5];
    if (T > TIE_CAP) T = TIE_CAP;
    int need = state[4];
    if (need <= 0 || T == 0) return;
    for (int i = threadIdx.x; i < T; i += blockDim.x) lst[i] = tiel[i];
    __syncthreads();
    for (int e = threadIdx.x; e < T; e += blockDim.x) {
        int idx = lst[e], r = 0;
        for (int j = 0; j < T; j++) r += (lst[j] < idx) ? 1 : 0;
        if (r < need) sel[idx] = 1;
    }
}
// prune for levels 0/1: write dense mask (pre-zeroed by k_cnt) at actives.
__global__ void k_sapply(const uint8_t* __restrict__ sel, const int* __restrict__ list,
                         const int* cnt, const void* gt, uint8_t* __restrict__ mask,
                         const int* flags) {
    int n = cnt[0];
    int i = blockIdx.x * 256 + threadIdx.x;
    if (i >= n) return;
    int v = list[i];
    mask[v] = (uint8_t)(sel[v] || ldb(gt, v, flags[1]));
}
// final level: scatter masked features straight into pre-zeroed d_out
__global__ void k_sapply_out(const uint8_t* __restrict__ sel, const int* __restrict__ list,
                             const int* cnt, const void* gt, const float* __restrict__ feat,
                             void* dout, const int* flags) {
    int n = cnt[0];
    int i = blockIdx.x * 256 + threadIdx.x;
    if (i >= n) return;
    int v = list[i];
    if (!(sel[v] || ldb(gt, v, flags[1]))) return;
    const int bf = flags[0];
    long base = OFF_OUT + (long)v * 16;
    const float* fp = feat + (long)v * 16;
#pragma unroll
    for (int co = 0; co < 16; co++) stf(dout, base + co, fp[co], bf);
}

// ---------------- launcher ----------------
extern "C" void kernel_launch(void* const* d_in, const int* in_sizes, int n_in,
                              void* d_out, int out_size, void* d_ws, size_t ws_size,
                              hipStream_t stream) {
    char* ws = (char*)d_ws;
    int* flags = (int*)(ws + O_FLAGS);
    int* cnt = flags + 32;
    int* state = (int*)(ws + O_STATE);
    int* tiel = (int*)(ws + O_TIE);
    uint32_t* h1 = (uint32_t*)(ws + O_HIST1);
    uint32_t* h2 = (uint32_t*)(ws + O_HIST2);
    uint8_t* occ0 = (uint8_t*)(ws + O_OCC0);
    uint8_t* occ1 = (uint8_t*)(ws + O_OCC1);
    uint8_t* occ2 = (uint8_t*)(ws + O_OCC2);
    uint8_t* mask0 = (uint8_t*)(ws + O_MASK0);
    uint8_t* mask1 = (uint8_t*)(ws + O_MASK1);
    int* bcnt = (int*)(ws + O_BCNT);
    uint8_t* sel = (uint8_t*)(ws + O_SEL);
    uint32_t* keyl = (uint32_t*)(ws + O_KEYS);
    float* feat0 = (float*)(ws + O_FEAT0);
    float* hr1 = (float*)(ws + O_HR1);
    float* feat1 = (float*)(ws + O_FEAT1);
    float* hr2 = (float*)(ws + O_HR2);
    float* feat2 = (float*)(ws + O_FEAT2);
    // aliased scratch (lifetimes verified disjoint):
    int* list0 = (int*)(ws + O_HR1);                      // lvl0; hr1 written at lvl1
    int* list1 = (int*)(ws + O_HR2);                      // lvl1; hr2 written at lvl2
    int* list2 = (int*)(ws + O_HR1);                      // lvl2; hr1 dead after lvl1 conv
    float* xf = (float*)(ws + O_HR2 + (4UL << 20));       // lvl0 only; 4 MB

    const int G1 = N1 / 256;                // 1024
    const int G2 = GMAX;                    // 2048 (grid-stride covers up to N2)

    // inputs: 0:x 1:occ0 2:gt0 3:gt1 4:gt2 5:w_conv0 6:b_conv0 7:w_cls0 8:b_cls0
    // 9:w_up1 10:b_up1 11:w_conv1 12:b_conv1 13:w_cls1 14:b_cls1
    // 15:w_up2 16:b_up2 17:w_conv2 18:b_conv2 19:w_cls2 20:b_cls2 21-23:nums
    k_fzero<<<1, 64, 0, stream>>>(flags);
    k_fscan<<<512, 256, 0, stream>>>(d_in[0], d_in[4], flags);
    k_ffinal<<<1, 64, 0, stream>>>(flags);
    k_zout<<<2048, 256, 0, stream>>>(d_out, (long)out_size, flags);
    k_occ0<<<N0 / 256, 256, 0, stream>>>(d_in[1], occ0, flags);
    k_xcast<<<(N0 * 32) / 256, 256, 0, stream>>>(d_in[0], xf, flags);

    // ---- level 0
    k_cnt<<<N0 / 256, 256, 0, stream>>>(occ0, N0, bcnt, mask0);
    k_scanb<<<1, 256, 0, stream>>>(bcnt, N0 / 256, cnt);
    k_fill<<<N0 / 256, 256, 0, stream>>>(occ0, N0, bcnt, list0);
    k_sconv16<32, 32><<<N0 / 256, 256, 0, stream>>>(xf, d_in[5], d_in[6], occ0,
                                                    list0, cnt, feat0, flags);
    k_scls<32><<<N0 / 256, 256, 0, stream>>>(feat0, d_in[7], d_in[8], occ0, list0,
                                             cnt, d_out, OFF_CLS0, keyl, flags);
    k_hzero<<<256, 256, 0, stream>>>(h1, state);
    k_hist1<<<256, 256, 0, stream>>>(keyl, cnt, h1);
    k_scan1<<<1, 256, 0, stream>>>(h1, d_in[21], cnt, state, h2);
    k_hist2<<<256, 256, 0, stream>>>(keyl, cnt, state, h2);
    k_scan2<<<1, 256, 0, stream>>>(h2, state);
    k_mark<<<N0 / 256, 256, 0, stream>>>(keyl, list0, cnt, state, sel, tiel);
    k_ties<<<1, 1024, 0, stream>>>(state, tiel, sel);
    k_sapply<<<N0 / 256, 256, 0, stream>>>(sel, list0, cnt, d_in[2], mask0, flags);

    // ---- level 1
    k_expand<32><<<N1 / 256, 256, 0, stream>>>(mask0, occ1);
    k_cnt<<<N1 / 256, 256, 0, stream>>>(occ1, N1, bcnt, mask1);
    k_scanb<<<1, 256, 0, stream>>>(bcnt, N1 / 256, cnt);
    k_fill<<<N1 / 256, 256, 0, stream>>>(occ1, N1, bcnt, list1);
    k_sup<32><<<G1, 256, 0, stream>>>(feat0, d_in[9], d_in[10], list1, cnt,
                                      hr1, flags);
    k_sconv16<16, 64><<<G1, 256, 0, stream>>>(hr1, d_in[11], d_in[12], occ1,
                                              list1, cnt, feat1, flags);
    k_scls<64><<<G1, 256, 0, stream>>>(feat1, d_in[13], d_in[14], occ1, list1,
                                       cnt, d_out, OFF_CLS1, keyl, flags);
    k_hzero<<<256, 256, 0, stream>>>(h1, state);
    k_hist1<<<256, 256, 0, stream>>>(keyl, cnt, h1);
    k_scan1<<<1, 256, 0, stream>>>(h1, d_in[22], cnt, state, h2);
    k_hist2<<<256, 256, 0, stream>>>(keyl, cnt, state, h2);
    k_scan2<<<1, 256, 0, stream>>>(h2, state);
    k_mark<<<N1 / 256, 256, 0, stream>>>(keyl, list1, cnt, state, sel, tiel);
    k_ties<<<1, 1024, 0, stream>>>(state, tiel, sel);
    k_sapply<<<N1 / 256, 256, 0, stream>>>(sel, list1, cnt, d_in[3], mask1, flags);

    // ---- level 2
    k_expand<64><<<N2 / 256, 256, 0, stream>>>(mask1, occ2);
    k_cnt<<<N2 / 256, 256, 0, stream>>>(occ2, N2, bcnt, (uint8_t*)0);
    k_scanb<<<1, 256, 0, stream>>>(bcnt, N2 / 256, cnt);
    k_fill<<<N2 / 256, 256, 0, stream>>>(occ2, N2, bcnt, list2);
    k_sup<64><<<G2, 256, 0, stream>>>(feat1, d_in[15], d_in[16], list2, cnt,
                                      hr2, flags);
    k_sconv16<16, 128><<<G2, 256, 0, stream>>>(hr2, d_in[17], d_in[18], occ2,
                                               list2, cnt, feat2, flags);
    k_scls<128><<<G2, 256, 0, stream>>>(feat2, d_in[19], d_in[20], occ2, list2,
                                        cnt, d_out, OFF_CLS2, keyl, flags);
    k_hzero<<<256, 256, 0, stream>>>(h1, state);
    k_hist1<<<256, 256, 0, stream>>>(keyl, cnt, h1);
    k_scan1<<<1, 256, 0, stream>>>(h1, d_in[23], cnt, state, h2);
    k_hist2<<<256, 256, 0, stream>>>(keyl, cnt, state, h2);
    k_scan2<<<1, 256, 0, stream>>>(h2, state);
    k_mark<<<N2 / 256, 256, 0, stream>>>(keyl, list2, cnt, state, sel, tiel);
    k_ties<<<1, 1024, 0, stream>>>(state, tiel, sel);
    k_sapply_out<<<N2 / 256, 256, 0, stream>>>(sel, list2, cnt, d_in[4], feat2,
                                               d_out, flags);
}

// Round 11
// 942.009 us; speedup vs baseline: 1.3492x; 1.2865x over previous
//
#include <hip/hip_runtime.h>
#include <stdint.h>

// R11 = byte-level revert to R7 (952us, passing). R10's compact-layout
// rewrite failed POST-TIMING only (first launch correct, replays diverged,
// 2x slower) — root cause not identified from available evidence; all ws
// lifetimes/bounds audited clean. Re-establish known-good baseline.

// ---------------- problem constants ----------------
#define N0 32768      // 32^3
#define N1 262144     // 64^3
#define N2 2097152    // 128^3

// d_out element offsets (cls0, cls1, cls2, out)
#define OFF_CLS0 0L
#define OFF_CLS1 32768L
#define OFF_CLS2 294912L
#define OFF_OUT  2392064L

// ---------------- ws layout (byte offsets, within proven ~320MB footprint) --
#define O_FLAGS 0UL            // int[64]: [0]=bf16 [1]=boolmode [8..]=counters [32]=list cnt
#define O_STATE 256UL
#define O_TIE   512UL          // 16000 ints (tie voxel-index list)
#define O_HIST1 66048UL        // 65536 u32
#define O_HIST2 328192UL       // 65536 u32
#define O_OCC0  590336UL       // N0 u8
#define O_OCC1  623104UL       // N1 u8
#define O_OCC2  885248UL       // N2 u8
#define O_MASK0 2982400UL
#define O_MASK1 3015168UL
#define O_BCNT  3277312UL      // 8192 ints (block counts / exclusive prefix)
#define O_SEL   5374464UL      // N2 u8 (dense by voxel, only active entries used)
#define O_KEYS  7471616UL      // N2 u32 keyl[] by LIST POSITION
#define O_FEAT0 15860224UL     // N0*16 f32
#define O_HR1   17957376UL     // N1*16 f32 ; ALIASED: list0 (lvl0), list2 (lvl2, hr1 dead)
#define O_FEAT1 34734592UL     // N1*16 f32
#define O_HR2   51511808UL     // N2*16 f32 ; ALIASED: list1 @+0 (lvl1), xf @+4MB (lvl0)
#define O_FEAT2 185729536UL    // N2*16 f32  (ends ~320 MB)

#define TIE_CAP 16000

// ---------------- dtype-flexible helpers ----------------
// flags[0] = floats-are-bf16; flags[1] = bool mode (0 i32,1 u8,2 bf16,3 f32,4 i64)
__device__ __forceinline__ float ldf(const void* p, long i, int bf) {
    if (bf) {
        uint16_t h = ((const uint16_t*)p)[i];
        return __uint_as_float(((uint32_t)h) << 16);
    }
    return ((const float*)p)[i];
}
__device__ __forceinline__ int ldb(const void* p, long i, int m) {
    switch (m) {
        case 0: return ((const int*)p)[i] != 0;
        case 1: return ((const uint8_t*)p)[i] != 0;
        case 2: { uint16_t h = ((const uint16_t*)p)[i]; return (h & 0x7FFF) != 0; }
        case 4: return ((const long long*)p)[i] != 0;
        default: { float f = ((const float*)p)[i]; return f != 0.0f; }
    }
}
__device__ __forceinline__ float rndb(float f, int en) {
    if (!en) return f;
    uint32_t u = __float_as_uint(f);
    u += 0x7FFFu + ((u >> 16) & 1u);
    u &= 0xFFFF0000u;
    return __uint_as_float(u);
}
__device__ __forceinline__ void stf(void* p, long i, float v, int bf) {
    if (bf) {
        uint32_t u = __float_as_uint(v);
        u += 0x7FFFu + ((u >> 16) & 1u);
        ((uint16_t*)p)[i] = (uint16_t)(u >> 16);
    } else {
        ((float*)p)[i] = v;
    }
}
// order-preserving float->u32 key; all finite keys are > 0
__device__ __forceinline__ uint32_t fkey(float f) {
    f = f + 0.0f;
    uint32_t u = __float_as_uint(f);
    return (u & 0x80000000u) ? ~u : (u | 0x80000000u);
}

// ---------------- runtime dtype detection (parallel) ----------------------
__global__ void k_fzero(int* flags) {
    int t = threadIdx.x;
    if (t < 16) flags[8 + t] = 0;
}
__global__ void k_fscan(const void* x, const void* gt2, int* flags) {
    int* cnt = flags + 8;
    __shared__ int lc[8];
    int t = threadIdx.x;
    if (t < 8) lc[t] = 0;
    __syncthreads();
    long gid = (long)blockIdx.x * blockDim.x + threadIdx.x;
    long gstride = (long)gridDim.x * blockDim.x;
    int ltiny = 0;
    const uint32_t* xu = (const uint32_t*)x;
    for (long i = gid; i < 524288; i += gstride) {
        uint32_t u = xu[i];
        uint32_t e = (u >> 23) & 0xFFu;
        if (e == 0u && (u & 0x7FFFFFu) != 0u) ltiny++;
    }
    int l1off = 0, l1any = 0, l3f = 0, l84 = 0;
    const uint8_t* g = (const uint8_t*)gt2;
    for (long i = gid; i < 2097152; i += gstride) {
        uint8_t b = g[i];
        if (b == 1u) {
            l1any++;
            if ((i & 3) != 0) l1off++;
            if ((i & 7) == 4) l84++;
        }
        if (b == 0x3Fu && (i & 3) == 1) l3f++;
    }
    if (ltiny) atomicAdd(&lc[0], ltiny);
    if (l1off) atomicAdd(&lc[1], l1off);
    if (l1any) atomicAdd(&lc[2], l1any);
    if (l3f)   atomicAdd(&lc[3], l3f);
    if (l84)   atomicAdd(&lc[4], l84);
    __syncthreads();
    if (t < 5 && lc[t]) atomicAdd(&cnt[t], lc[t]);
}
__global__ void k_ffinal(int* flags) {
    if (threadIdx.x != 0 || blockIdx.x != 0) return;
    const int* cnt = flags + 8;
    flags[0] = (cnt[0] > 8) ? 1 : 0;
    int bm;
    if (cnt[1] > 8)       bm = 1;
    else if (cnt[2] > 8)  bm = (cnt[4] > 8) ? 0 : 4;
    else if (cnt[3] > 8)  bm = 2;
    else                  bm = 3;
    flags[1] = bm;
}

// zero entire d_out (harness re-poisons to 0xAA each launch)
__global__ void k_zout(void* dout, long out_elems, const int* flags) {
    long bytes = out_elems * (flags[0] ? 2 : 4);
    long n16 = bytes >> 4;
    uint4 z = make_uint4(0, 0, 0, 0);
    uint4* p = (uint4*)dout;
    long stride = (long)gridDim.x * blockDim.x;
    for (long i = (long)blockIdx.x * blockDim.x + threadIdx.x; i < n16; i += stride)
        p[i] = z;
}

__global__ void k_occ0(const void* occraw, uint8_t* occ, const int* flags) {
    long v = (long)blockIdx.x * blockDim.x + threadIdx.x;
    if (v >= N0) return;
    occ[v] = (uint8_t)ldb(occraw, v, flags[1]);
}

__global__ void k_xcast(const void* x, float* xf, const int* flags) {
    long i = (long)blockIdx.x * blockDim.x + threadIdx.x;
    if (i >= (long)N0 * 32) return;
    xf[i] = ldf(x, i, flags[0]);
}

// ---------------- 3-phase scan compaction (zero contended atomics) ---------
__global__ void k_cnt(const uint8_t* __restrict__ occ, long N,
                      int* __restrict__ bcnt, uint8_t* maskz) {
    long v = (long)blockIdx.x * 256 + threadIdx.x;
    int a = (v < N) && occ[v];
    if (maskz && v < N) maskz[v] = 0;
    unsigned long long m = __ballot(a != 0);
    __shared__ int wsum[4];
    int lane = threadIdx.x & 63, wid = threadIdx.x >> 6;
    if (lane == 0) wsum[wid] = (int)__popcll(m);
    __syncthreads();
    if (threadIdx.x == 0)
        bcnt[blockIdx.x] = wsum[0] + wsum[1] + wsum[2] + wsum[3];
}
__global__ void k_scanb(int* __restrict__ bcnt, int nb, int* cnt) {
    __shared__ int tsum[256];
    __shared__ int tpre[257];
    int t = threadIdx.x;
    int ch = (nb + 255) / 256;
    int lo = t * ch, hi = min(lo + ch, nb);
    int s = 0;
    for (int i = lo; i < hi; i++) s += bcnt[i];
    tsum[t] = s;
    __syncthreads();
    if (t == 0) {
        int run = 0;
        for (int j = 0; j < 256; j++) { tpre[j] = run; run += tsum[j]; }
        tpre[256] = run;
        cnt[0] = run;  // total actives
    }
    __syncthreads();
    int run = tpre[t];
    for (int i = lo; i < hi; i++) { int x = bcnt[i]; bcnt[i] = run; run += x; }
}
__global__ void k_fill(const uint8_t* __restrict__ occ, long N,
                       const int* __restrict__ bcnt, int* __restrict__ list) {
    long v = (long)blockIdx.x * 256 + threadIdx.x;
    int a = (v < N) && occ[v];
    unsigned long long m = __ballot(a != 0);
    __shared__ int wsum[4];
    int lane = threadIdx.x & 63, wid = threadIdx.x >> 6;
    if (lane == 0) wsum[wid] = (int)__popcll(m);
    __syncthreads();
    int base = bcnt[blockIdx.x];
    for (int w = 0; w < wid; w++) base += wsum[w];
    if (a) list[base + (int)__popcll(m & ((1ull << lane) - 1ull))] = (int)v;
}

// ---------------- sparse 3^3 conv, CIN->16, relu, tap-skipping -------------
template <int CIN, int D>
__global__ void k_sconv16(const float* __restrict__ xin, const void* w, const void* bias,
                          const uint8_t* __restrict__ occ, const int* __restrict__ list,
                          const int* __restrict__ cnt, float* __restrict__ out,
                          const int* __restrict__ flags) {
    __shared__ float wl[27 * CIN * 16 + 16];
    const int n = cnt[0];
    if (blockIdx.x * 256 >= n) return;
    const int bf = flags[0];
    for (int i = threadIdx.x; i < 27 * CIN * 16; i += 256) wl[i] = ldf(w, i, bf);
    if (threadIdx.x < 16) wl[27 * CIN * 16 + threadIdx.x] = ldf(bias, threadIdx.x, bf);
    __syncthreads();
    int i = blockIdx.x * 256 + threadIdx.x;
    if (i >= n) return;
    int v = list[i];
    int wd = v % D, hh = (v / D) % D, dd = v / (D * D);
    float acc[16];
#pragma unroll
    for (int co = 0; co < 16; co++) acc[co] = 0.0f;
    for (int kd = 0; kd < 3; kd++) {
        int d2 = dd + kd - 1;
        if ((unsigned)d2 >= (unsigned)D) continue;
        for (int kh = 0; kh < 3; kh++) {
            int h2 = hh + kh - 1;
            if ((unsigned)h2 >= (unsigned)D) continue;
            for (int kw = 0; kw < 3; kw++) {
                int w2 = wd + kw - 1;
                if ((unsigned)w2 >= (unsigned)D) continue;
                long nv = ((long)d2 * D + h2) * D + w2;
                if (!occ[nv]) continue;  // inactive neighbors contribute 0 (and hold poison)
                const float4* xp = (const float4*)(xin + nv * CIN);
                const float* wp = &wl[((kd * 3 + kh) * 3 + kw) * CIN * 16];
#pragma unroll
                for (int c4 = 0; c4 < CIN / 4; c4++) {
                    float4 x4 = xp[c4];
                    const float* wq = wp + c4 * 64;
#pragma unroll
                    for (int co = 0; co < 16; co++) acc[co] += x4.x * wq[co];
#pragma unroll
                    for (int co = 0; co < 16; co++) acc[co] += x4.y * wq[16 + co];
#pragma unroll
                    for (int co = 0; co < 16; co++) acc[co] += x4.z * wq[32 + co];
#pragma unroll
                    for (int co = 0; co < 16; co++) acc[co] += x4.w * wq[48 + co];
                }
            }
        }
    }
    float* op = out + (long)v * 16;
#pragma unroll
    for (int co = 0; co < 16; co++) {
        float val = rndb(acc[co], bf);
        val = rndb(val + wl[27 * CIN * 16 + co], bf);
        op[co] = fmaxf(val, 0.0f);
    }
}

// ---------------- sparse cls conv (16->1): d_out slice + position keys -----
template <int D>
__global__ void k_scls(const float* __restrict__ feat, const void* w, const void* bias,
                       const uint8_t* __restrict__ occ, const int* __restrict__ list,
                       const int* __restrict__ cnt, void* dout, long ooff,
                       uint32_t* __restrict__ keyl, const int* __restrict__ flags) {
    __shared__ float wl[27 * 16 + 1];
    const int n = cnt[0];
    if (blockIdx.x * 256 >= n) return;
    const int bf = flags[0];
    for (int i = threadIdx.x; i < 27 * 16; i += 256) wl[i] = ldf(w, i, bf);
    if (threadIdx.x == 0) wl[432] = ldf(bias, 0, bf);
    __syncthreads();
    int i = blockIdx.x * 256 + threadIdx.x;
    if (i >= n) return;
    int v = list[i];
    int wd = v % D, hh = (v / D) % D, dd = v / (D * D);
    float acc = 0.0f;
    for (int kd = 0; kd < 3; kd++) {
        int d2 = dd + kd - 1;
        if ((unsigned)d2 >= (unsigned)D) continue;
        for (int kh = 0; kh < 3; kh++) {
            int h2 = hh + kh - 1;
            if ((unsigned)h2 >= (unsigned)D) continue;
            for (int kw = 0; kw < 3; kw++) {
                int w2 = wd + kw - 1;
                if ((unsigned)w2 >= (unsigned)D) continue;
                long nv = ((long)d2 * D + h2) * D + w2;
                if (!occ[nv]) continue;
                const float4* xp = (const float4*)(feat + nv * 16);
                const float* wp = &wl[((kd * 3 + kh) * 3 + kw) * 16];
                float4 a0 = xp[0], a1 = xp[1], a2 = xp[2], a3 = xp[3];
                acc += a0.x * wp[0] + a0.y * wp[1] + a0.z * wp[2] + a0.w * wp[3];
                acc += a1.x * wp[4] + a1.y * wp[5] + a1.z * wp[6] + a1.w * wp[7];
                acc += a2.x * wp[8] + a2.y * wp[9] + a2.z * wp[10] + a2.w * wp[11];
                acc += a3.x * wp[12] + a3.y * wp[13] + a3.z * wp[14] + a3.w * wp[15];
            }
        }
    }
    float val = rndb(acc, bf);
    val = rndb(val + wl[432], bf);
    stf(dout, ooff + v, val, bf);
    keyl[i] = fkey(val);
}

// ---------------- sparse 2x up-sample (transpose conv, kernel-flipped) -----
template <int Dp>
__global__ void k_sup(const float* __restrict__ featp, const void* w, const void* bias,
                      const int* __restrict__ list, const int* __restrict__ cnt,
                      float* __restrict__ hrelu, const int* __restrict__ flags) {
    __shared__ float wl[2048 + 16];
    const int n = cnt[0];
    if (blockIdx.x * 256 >= n) return;
    const int bf = flags[0];
    for (int i = threadIdx.x; i < 2048; i += 256) wl[i] = ldf(w, i, bf);
    if (threadIdx.x < 16) wl[2048 + threadIdx.x] = ldf(bias, threadIdx.x, bf);
    __syncthreads();
    int i = blockIdx.x * 256 + threadIdx.x;
    if (i >= n) return;
    int v = list[i];
    const int D = Dp * 2;
    int wd = v % D, hh = (v / D) % D, dd = v / (D * D);
    const float4* xp = (const float4*)(featp +
        ((long)((dd >> 1) * Dp + (hh >> 1)) * Dp + (wd >> 1)) * 16);
    // y[o] = x[o>>1] * w[1-(o&1)] per axis (jax conv_transpose, k=2,s=2,'VALID')
    int a = 1 - (dd & 1), b2 = 1 - (hh & 1), c = 1 - (wd & 1);
    const float* wp = &wl[((a * 2 + b2) * 2 + c) * 256];
    float acc[16];
#pragma unroll
    for (int co = 0; co < 16; co++) acc[co] = 0.0f;
#pragma unroll
    for (int c4 = 0; c4 < 4; c4++) {
        float4 x4 = xp[c4];
        const float* wq = wp + c4 * 64;
#pragma unroll
        for (int co = 0; co < 16; co++) acc[co] += x4.x * wq[co];
#pragma unroll
        for (int co = 0; co < 16; co++) acc[co] += x4.y * wq[16 + co];
#pragma unroll
        for (int co = 0; co < 16; co++) acc[co] += x4.z * wq[32 + co];
#pragma unroll
        for (int co = 0; co < 16; co++) acc[co] += x4.w * wq[48 + co];
    }
    float* op = hrelu + (long)v * 16;
#pragma unroll
    for (int co = 0; co < 16; co++) {
        float val = rndb(acc[co], bf);
        val = rndb(val + wl[2048 + co], bf);
        op[co] = fmaxf(val, 0.0f);  // relu(h) feeding next conv
    }
}

template <int Dp>
__global__ void k_expand(const uint8_t* __restrict__ maskp, uint8_t* __restrict__ occc) {
    const int D = Dp * 2;
    long v = (long)blockIdx.x * blockDim.x + threadIdx.x;
    if (v >= (long)D * D * D) return;
    int wd = (int)(v % D), hh = (int)((v / D) % D), dd = (int)(v / ((long)D * D));
    occc[v] = maskp[((long)(dd >> 1) * Dp + (hh >> 1)) * Dp + (wd >> 1)];
}

// ---------------- exact top-k over position keys (radix-16/16) -------------
// Per-block LDS histogram (R7 win): 65536 bins as packed u16 pairs in 128KB
// LDS; per-block entries <= 8192 so u16 never overflows.
// state: [0]=B(-1 => select-all) [1]=count_above [2]=krem [3]=K [4]=ties_needed [5]=tie_count
__global__ void k_hzero(uint32_t* hist1, int* state) {
    int i = blockIdx.x * blockDim.x + threadIdx.x;
    if (i < 65536) hist1[i] = 0u;
    if (i < 16) state[i] = 0;
}
__global__ void k_hist1(const uint32_t* __restrict__ keyl, const int* cnt,
                        uint32_t* __restrict__ hist) {
    __shared__ uint32_t lh[32768];
    const int n = cnt[0];
    for (int j = threadIdx.x; j < 32768; j += 256) lh[j] = 0u;
    __syncthreads();
    const int stride = gridDim.x * 256;
    for (int i = blockIdx.x * 256 + threadIdx.x; i < n; i += stride) {
        uint32_t bin = keyl[i] >> 16;
        atomicAdd(&lh[bin >> 1], 1u << ((bin & 1u) << 4));
    }
    __syncthreads();
    for (int j = threadIdx.x; j < 32768; j += 256) {
        uint32_t p = lh[j];
        if (p) {
            uint32_t lo = p & 0xFFFFu, hi = p >> 16;
            if (lo) atomicAdd(&hist[2 * j], lo);
            if (hi) atomicAdd(&hist[2 * j + 1], hi);
        }
    }
}
__global__ void k_scan1(const uint32_t* hist, const void* kptr, const int* cnt,
                        int* state, uint32_t* hist2) {
    __shared__ uint32_t part[256];
    int t = threadIdx.x;
    uint32_t s = 0;
    for (int j = 0; j < 256; j++) s += hist[t * 256 + j];
    part[t] = s;
    for (int i = t; i < 65536; i += 256) hist2[i] = 0u;
    __syncthreads();
    if (t == 0) {
        uint32_t k = (uint32_t)((const int*)kptr)[0];
        uint32_t total = (uint32_t)cnt[0];
        if (k >= total) {
            state[0] = -1;
            state[3] = 0;   // K=0 -> sel = (key > 0), true for all finite keys
            state[4] = 0;
            state[5] = 0;
            return;
        }
        uint32_t cum = 0, cab = 0;
        int B = 0;
        for (int c = 255; c >= 0; c--) {
            if (cum + part[c] >= k) {
                uint32_t cc = cum;
                for (int b = c * 256 + 255; b >= c * 256; b--) {
                    uint32_t h = hist[b];
                    if (cc + h >= k) { B = b; cab = cc; break; }
                    cc += h;
                }
                break;
            }
            cum += part[c];
        }
        state[0] = B;
        state[1] = (int)cab;
        state[2] = (int)(k - cab);
    }
}
__global__ void k_hist2(const uint32_t* __restrict__ keyl, const int* cnt,
                        const int* state, uint32_t* __restrict__ hist2) {
    if (state[0] < 0) return;
    __shared__ uint32_t lh[32768];
    const int n = cnt[0];
    const int B = state[0];
    for (int j = threadIdx.x; j < 32768; j += 256) lh[j] = 0u;
    __syncthreads();
    const int stride = gridDim.x * 256;
    for (int i = blockIdx.x * 256 + threadIdx.x; i < n; i += stride) {
        uint32_t key = keyl[i];
        if ((int)(key >> 16) == B) {
            uint32_t bin = key & 0xFFFFu;
            atomicAdd(&lh[bin >> 1], 1u << ((bin & 1u) << 4));
        }
    }
    __syncthreads();
    for (int j = threadIdx.x; j < 32768; j += 256) {
        uint32_t p = lh[j];
        if (p) {
            uint32_t lo = p & 0xFFFFu, hi = p >> 16;
            if (lo) atomicAdd(&hist2[2 * j], lo);
            if (hi) atomicAdd(&hist2[2 * j + 1], hi);
        }
    }
}
__global__ void k_scan2(const uint32_t* hist2, int* state) {
    __shared__ uint32_t part[256];
    int t = threadIdx.x;
    if (state[0] < 0) return;
    uint32_t s = 0;
    for (int j = 0; j < 256; j++) s += hist2[t * 256 + j];
    part[t] = s;
    __syncthreads();
    if (t == 0) {
        uint32_t krem = (uint32_t)state[2];
        uint32_t cum = 0, cl = 0;
        int L = 0;
        for (int c = 255; c >= 0; c--) {
            if (cum + part[c] >= krem) {
                uint32_t cc = cum;
                for (int b = c * 256 + 255; b >= c * 256; b--) {
                    uint32_t h = hist2[b];
                    if (cc + h >= krem) { L = b; cl = cc; break; }
                    cc += h;
                }
                break;
            }
            cum += part[c];
        }
        uint32_t K = ((uint32_t)state[0] << 16) | (uint32_t)L;
        state[3] = (int)K;
        state[4] = (int)(krem - cl);
        state[5] = 0;
    }
}
// tie collection wave-aggregated: one atomicAdd-with-return per wave
__global__ void k_mark(const uint32_t* __restrict__ keyl, const int* __restrict__ list,
                       const int* cnt, int* state, uint8_t* __restrict__ sel, int* tiel) {
    int n = cnt[0];
    int i = blockIdx.x * 256 + threadIdx.x;
    uint32_t K = (uint32_t)state[3];
    int v = 0, isTie = 0;
    if (i < n) {
        uint32_t key = keyl[i];
        v = list[i];
        sel[v] = (key > K) ? (uint8_t)1 : (uint8_t)0;
        isTie = (key == K && K != 0u);
    }
    unsigned long long m = __ballot(isTie != 0);
    if (m) {
        int lane = threadIdx.x & 63;
        int leader = __ffsll((unsigned long long)m) - 1;
        int base = 0;
        if (lane == leader) base = atomicAdd(&state[5], (int)__popcll(m));
        base = __shfl(base, leader, 64);
        if (isTie) {
            int pos = base + (int)__popcll(m & ((1ull << lane) - 1ull));
            if (pos < TIE_CAP) tiel[pos] = v;
        }
    }
}
// ties at the threshold key: jax.lax.top_k keeps LOWEST voxel indices first
__global__ void k_ties(const int* state, const int* tiel, uint8_t* sel) {
    __shared__ int lst[TIE_CAP];
    int T = state[5];
    if (T > TIE_CAP) T = TIE_CAP;
    int need = state[4];
    if (need <= 0 || T == 0) return;
    for (int i = threadIdx.x; i < T; i += blockDim.x) lst[i] = tiel[i];
    __syncthreads();
    for (int e = threadIdx.x; e < T; e += blockDim.x) {
        int idx = lst[e], r = 0;
        for (int j = 0; j < T; j++) r += (lst[j] < idx) ? 1 : 0;
        if (r < need) sel[idx] = 1;
    }
}
// prune for levels 0/1: write dense mask (pre-zeroed by k_cnt) at actives.
__global__ void k_sapply(const uint8_t* __restrict__ sel, const int* __restrict__ list,
                         const int* cnt, const void* gt, uint8_t* __restrict__ mask,
                         const int* flags) {
    int n = cnt[0];
    int i = blockIdx.x * 256 + threadIdx.x;
    if (i >= n) return;
    int v = list[i];
    mask[v] = (uint8_t)(sel[v] || ldb(gt, v, flags[1]));
}
// final level: scatter masked features straight into pre-zeroed d_out
__global__ void k_sapply_out(const uint8_t* __restrict__ sel, const int* __restrict__ list,
                             const int* cnt, const void* gt, const float* __restrict__ feat,
                             void* dout, const int* flags) {
    int n = cnt[0];
    int i = blockIdx.x * 256 + threadIdx.x;
    if (i >= n) return;
    int v = list[i];
    if (!(sel[v] || ldb(gt, v, flags[1]))) return;
    const int bf = flags[0];
    long base = OFF_OUT + (long)v * 16;
    const float* fp = feat + (long)v * 16;
#pragma unroll
    for (int co = 0; co < 16; co++) stf(dout, base + co, fp[co], bf);
}

// ---------------- launcher ----------------
extern "C" void kernel_launch(void* const* d_in, const int* in_sizes, int n_in,
                              void* d_out, int out_size, void* d_ws, size_t ws_size,
                              hipStream_t stream) {
    char* ws = (char*)d_ws;
    int* flags = (int*)(ws + O_FLAGS);
    int* cnt = flags + 32;
    int* state = (int*)(ws + O_STATE);
    int* tiel = (int*)(ws + O_TIE);
    uint32_t* h1 = (uint32_t*)(ws + O_HIST1);
    uint32_t* h2 = (uint32_t*)(ws + O_HIST2);
    uint8_t* occ0 = (uint8_t*)(ws + O_OCC0);
    uint8_t* occ1 = (uint8_t*)(ws + O_OCC1);
    uint8_t* occ2 = (uint8_t*)(ws + O_OCC2);
    uint8_t* mask0 = (uint8_t*)(ws + O_MASK0);
    uint8_t* mask1 = (uint8_t*)(ws + O_MASK1);
    int* bcnt = (int*)(ws + O_BCNT);
    uint8_t* sel = (uint8_t*)(ws + O_SEL);
    uint32_t* keyl = (uint32_t*)(ws + O_KEYS);
    float* feat0 = (float*)(ws + O_FEAT0);
    float* hr1 = (float*)(ws + O_HR1);
    float* feat1 = (float*)(ws + O_FEAT1);
    float* hr2 = (float*)(ws + O_HR2);
    float* feat2 = (float*)(ws + O_FEAT2);
    // aliased scratch (lifetimes verified disjoint):
    int* list0 = (int*)(ws + O_HR1);                      // lvl0; hr1 written at lvl1
    int* list1 = (int*)(ws + O_HR2);                      // lvl1; hr2 written at lvl2
    int* list2 = (int*)(ws + O_HR1);                      // lvl2; hr1 dead after lvl1 conv
    float* xf = (float*)(ws + O_HR2 + (4UL << 20));       // lvl0 only; 4 MB

    // inputs: 0:x 1:occ0 2:gt0 3:gt1 4:gt2 5:w_conv0 6:b_conv0 7:w_cls0 8:b_cls0
    // 9:w_up1 10:b_up1 11:w_conv1 12:b_conv1 13:w_cls1 14:b_cls1
    // 15:w_up2 16:b_up2 17:w_conv2 18:b_conv2 19:w_cls2 20:b_cls2 21-23:nums
    k_fzero<<<1, 64, 0, stream>>>(flags);
    k_fscan<<<512, 256, 0, stream>>>(d_in[0], d_in[4], flags);
    k_ffinal<<<1, 64, 0, stream>>>(flags);
    k_zout<<<2048, 256, 0, stream>>>(d_out, (long)out_size, flags);
    k_occ0<<<N0 / 256, 256, 0, stream>>>(d_in[1], occ0, flags);
    k_xcast<<<(N0 * 32) / 256, 256, 0, stream>>>(d_in[0], xf, flags);

    // ---- level 0
    k_cnt<<<N0 / 256, 256, 0, stream>>>(occ0, N0, bcnt, mask0);
    k_scanb<<<1, 256, 0, stream>>>(bcnt, N0 / 256, cnt);
    k_fill<<<N0 / 256, 256, 0, stream>>>(occ0, N0, bcnt, list0);
    k_sconv16<32, 32><<<N0 / 256, 256, 0, stream>>>(xf, d_in[5], d_in[6], occ0,
                                                    list0, cnt, feat0, flags);
    k_scls<32><<<N0 / 256, 256, 0, stream>>>(feat0, d_in[7], d_in[8], occ0, list0,
                                             cnt, d_out, OFF_CLS0, keyl, flags);
    k_hzero<<<256, 256, 0, stream>>>(h1, state);
    k_hist1<<<256, 256, 0, stream>>>(keyl, cnt, h1);
    k_scan1<<<1, 256, 0, stream>>>(h1, d_in[21], cnt, state, h2);
    k_hist2<<<256, 256, 0, stream>>>(keyl, cnt, state, h2);
    k_scan2<<<1, 256, 0, stream>>>(h2, state);
    k_mark<<<N0 / 256, 256, 0, stream>>>(keyl, list0, cnt, state, sel, tiel);
    k_ties<<<1, 1024, 0, stream>>>(state, tiel, sel);
    k_sapply<<<N0 / 256, 256, 0, stream>>>(sel, list0, cnt, d_in[2], mask0, flags);

    // ---- level 1
    k_expand<32><<<N1 / 256, 256, 0, stream>>>(mask0, occ1);
    k_cnt<<<N1 / 256, 256, 0, stream>>>(occ1, N1, bcnt, mask1);
    k_scanb<<<1, 256, 0, stream>>>(bcnt, N1 / 256, cnt);
    k_fill<<<N1 / 256, 256, 0, stream>>>(occ1, N1, bcnt, list1);
    k_sup<32><<<N1 / 256, 256, 0, stream>>>(feat0, d_in[9], d_in[10], list1, cnt,
                                            hr1, flags);
    k_sconv16<16, 64><<<N1 / 256, 256, 0, stream>>>(hr1, d_in[11], d_in[12], occ1,
                                                    list1, cnt, feat1, flags);
    k_scls<64><<<N1 / 256, 256, 0, stream>>>(feat1, d_in[13], d_in[14], occ1, list1,
                                             cnt, d_out, OFF_CLS1, keyl, flags);
    k_hzero<<<256, 256, 0, stream>>>(h1, state);
    k_hist1<<<256, 256, 0, stream>>>(keyl, cnt, h1);
    k_scan1<<<1, 256, 0, stream>>>(h1, d_in[22], cnt, state, h2);
    k_hist2<<<256, 256, 0, stream>>>(keyl, cnt, state, h2);
    k_scan2<<<1, 256, 0, stream>>>(h2, state);
    k_mark<<<N1 / 256, 256, 0, stream>>>(keyl, list1, cnt, state, sel, tiel);
    k_ties<<<1, 1024, 0, stream>>>(state, tiel, sel);
    k_sapply<<<N1 / 256, 256, 0, stream>>>(sel, list1, cnt, d_in[3], mask1, flags);

    // ---- level 2
    k_expand<64><<<N2 / 256, 256, 0, stream>>>(mask1, occ2);
    k_cnt<<<N2 / 256, 256, 0, stream>>>(occ2, N2, bcnt, (uint8_t*)0);
    k_scanb<<<1, 256, 0, stream>>>(bcnt, N2 / 256, cnt);
    k_fill<<<N2 / 256, 256, 0, stream>>>(occ2, N2, bcnt, list2);
    k_sup<64><<<N2 / 256, 256, 0, stream>>>(feat1, d_in[15], d_in[16], list2, cnt,
                                            hr2, flags);
    k_sconv16<16, 128><<<N2 / 256, 256, 0, stream>>>(hr2, d_in[17], d_in[18], occ2,
                                                     list2, cnt, feat2, flags);
    k_scls<128><<<N2 / 256, 256, 0, stream>>>(feat2, d_in[19], d_in[20], occ2, list2,
                                              cnt, d_out, OFF_CLS2, keyl, flags);
    k_hzero<<<256, 256, 0, stream>>>(h1, state);
    k_hist1<<<256, 256, 0, stream>>>(keyl, cnt, h1);
    k_scan1<<<1, 256, 0, stream>>>(h1, d_in[23], cnt, state, h2);
    k_hist2<<<256, 256, 0, stream>>>(keyl, cnt, state, h2);
    k_scan2<<<1, 256, 0, stream>>>(h2, state);
    k_mark<<<N2 / 256, 256, 0, stream>>>(keyl, list2, cnt, state, sel, tiel);
    k_ties<<<1, 1024, 0, stream>>>(state, tiel, sel);
    k_sapply_out<<<N2 / 256, 256, 0, stream>>>(sel, list2, cnt, d_in[4], feat2,
                                               d_out, flags);
}

// Round 12
// 924.277 us; speedup vs baseline: 1.3751x; 1.0192x over previous
//
#include <hip/hip_runtime.h>
#include <stdint.h>

// R12 = R11 (942us baseline) with ONE change: k_sconv16 prefetches the 27
// neighbor-occupancy bytes into a bitmask (independent loads, single drain)
// before the tap loop; body is otherwise R7's serial tap-skipping code with
// the branch testing a register bit. No pos[] array (R9's VGPR bloat), no
// per-lane tap walk (R8's LDS-conflict bug).

// ---------------- problem constants ----------------
#define N0 32768      // 32^3
#define N1 262144     // 64^3
#define N2 2097152    // 128^3

// d_out element offsets (cls0, cls1, cls2, out)
#define OFF_CLS0 0L
#define OFF_CLS1 32768L
#define OFF_CLS2 294912L
#define OFF_OUT  2392064L

// ---------------- ws layout (byte offsets, within proven ~320MB footprint) --
#define O_FLAGS 0UL            // int[64]: [0]=bf16 [1]=boolmode [8..]=counters [32]=list cnt
#define O_STATE 256UL
#define O_TIE   512UL          // 16000 ints (tie voxel-index list)
#define O_HIST1 66048UL        // 65536 u32
#define O_HIST2 328192UL       // 65536 u32
#define O_OCC0  590336UL       // N0 u8
#define O_OCC1  623104UL       // N1 u8
#define O_OCC2  885248UL       // N2 u8
#define O_MASK0 2982400UL
#define O_MASK1 3015168UL
#define O_BCNT  3277312UL      // 8192 ints (block counts / exclusive prefix)
#define O_SEL   5374464UL      // N2 u8 (dense by voxel, only active entries used)
#define O_KEYS  7471616UL      // N2 u32 keyl[] by LIST POSITION
#define O_FEAT0 15860224UL     // N0*16 f32
#define O_HR1   17957376UL     // N1*16 f32 ; ALIASED: list0 (lvl0), list2 (lvl2, hr1 dead)
#define O_FEAT1 34734592UL     // N1*16 f32
#define O_HR2   51511808UL     // N2*16 f32 ; ALIASED: list1 @+0 (lvl1), xf @+4MB (lvl0)
#define O_FEAT2 185729536UL    // N2*16 f32  (ends ~320 MB)

#define TIE_CAP 16000

// ---------------- dtype-flexible helpers ----------------
// flags[0] = floats-are-bf16; flags[1] = bool mode (0 i32,1 u8,2 bf16,3 f32,4 i64)
__device__ __forceinline__ float ldf(const void* p, long i, int bf) {
    if (bf) {
        uint16_t h = ((const uint16_t*)p)[i];
        return __uint_as_float(((uint32_t)h) << 16);
    }
    return ((const float*)p)[i];
}
__device__ __forceinline__ int ldb(const void* p, long i, int m) {
    switch (m) {
        case 0: return ((const int*)p)[i] != 0;
        case 1: return ((const uint8_t*)p)[i] != 0;
        case 2: { uint16_t h = ((const uint16_t*)p)[i]; return (h & 0x7FFF) != 0; }
        case 4: return ((const long long*)p)[i] != 0;
        default: { float f = ((const float*)p)[i]; return f != 0.0f; }
    }
}
__device__ __forceinline__ float rndb(float f, int en) {
    if (!en) return f;
    uint32_t u = __float_as_uint(f);
    u += 0x7FFFu + ((u >> 16) & 1u);
    u &= 0xFFFF0000u;
    return __uint_as_float(u);
}
__device__ __forceinline__ void stf(void* p, long i, float v, int bf) {
    if (bf) {
        uint32_t u = __float_as_uint(v);
        u += 0x7FFFu + ((u >> 16) & 1u);
        ((uint16_t*)p)[i] = (uint16_t)(u >> 16);
    } else {
        ((float*)p)[i] = v;
    }
}
// order-preserving float->u32 key; all finite keys are > 0
__device__ __forceinline__ uint32_t fkey(float f) {
    f = f + 0.0f;
    uint32_t u = __float_as_uint(f);
    return (u & 0x80000000u) ? ~u : (u | 0x80000000u);
}

// ---------------- runtime dtype detection (parallel) ----------------------
__global__ void k_fzero(int* flags) {
    int t = threadIdx.x;
    if (t < 16) flags[8 + t] = 0;
}
__global__ void k_fscan(const void* x, const void* gt2, int* flags) {
    int* cnt = flags + 8;
    __shared__ int lc[8];
    int t = threadIdx.x;
    if (t < 8) lc[t] = 0;
    __syncthreads();
    long gid = (long)blockIdx.x * blockDim.x + threadIdx.x;
    long gstride = (long)gridDim.x * blockDim.x;
    int ltiny = 0;
    const uint32_t* xu = (const uint32_t*)x;
    for (long i = gid; i < 524288; i += gstride) {
        uint32_t u = xu[i];
        uint32_t e = (u >> 23) & 0xFFu;
        if (e == 0u && (u & 0x7FFFFFu) != 0u) ltiny++;
    }
    int l1off = 0, l1any = 0, l3f = 0, l84 = 0;
    const uint8_t* g = (const uint8_t*)gt2;
    for (long i = gid; i < 2097152; i += gstride) {
        uint8_t b = g[i];
        if (b == 1u) {
            l1any++;
            if ((i & 3) != 0) l1off++;
            if ((i & 7) == 4) l84++;
        }
        if (b == 0x3Fu && (i & 3) == 1) l3f++;
    }
    if (ltiny) atomicAdd(&lc[0], ltiny);
    if (l1off) atomicAdd(&lc[1], l1off);
    if (l1any) atomicAdd(&lc[2], l1any);
    if (l3f)   atomicAdd(&lc[3], l3f);
    if (l84)   atomicAdd(&lc[4], l84);
    __syncthreads();
    if (t < 5 && lc[t]) atomicAdd(&cnt[t], lc[t]);
}
__global__ void k_ffinal(int* flags) {
    if (threadIdx.x != 0 || blockIdx.x != 0) return;
    const int* cnt = flags + 8;
    flags[0] = (cnt[0] > 8) ? 1 : 0;
    int bm;
    if (cnt[1] > 8)       bm = 1;
    else if (cnt[2] > 8)  bm = (cnt[4] > 8) ? 0 : 4;
    else if (cnt[3] > 8)  bm = 2;
    else                  bm = 3;
    flags[1] = bm;
}

// zero entire d_out (harness re-poisons to 0xAA each launch)
__global__ void k_zout(void* dout, long out_elems, const int* flags) {
    long bytes = out_elems * (flags[0] ? 2 : 4);
    long n16 = bytes >> 4;
    uint4 z = make_uint4(0, 0, 0, 0);
    uint4* p = (uint4*)dout;
    long stride = (long)gridDim.x * blockDim.x;
    for (long i = (long)blockIdx.x * blockDim.x + threadIdx.x; i < n16; i += stride)
        p[i] = z;
}

__global__ void k_occ0(const void* occraw, uint8_t* occ, const int* flags) {
    long v = (long)blockIdx.x * blockDim.x + threadIdx.x;
    if (v >= N0) return;
    occ[v] = (uint8_t)ldb(occraw, v, flags[1]);
}

__global__ void k_xcast(const void* x, float* xf, const int* flags) {
    long i = (long)blockIdx.x * blockDim.x + threadIdx.x;
    if (i >= (long)N0 * 32) return;
    xf[i] = ldf(x, i, flags[0]);
}

// ---------------- 3-phase scan compaction (zero contended atomics) ---------
__global__ void k_cnt(const uint8_t* __restrict__ occ, long N,
                      int* __restrict__ bcnt, uint8_t* maskz) {
    long v = (long)blockIdx.x * 256 + threadIdx.x;
    int a = (v < N) && occ[v];
    if (maskz && v < N) maskz[v] = 0;
    unsigned long long m = __ballot(a != 0);
    __shared__ int wsum[4];
    int lane = threadIdx.x & 63, wid = threadIdx.x >> 6;
    if (lane == 0) wsum[wid] = (int)__popcll(m);
    __syncthreads();
    if (threadIdx.x == 0)
        bcnt[blockIdx.x] = wsum[0] + wsum[1] + wsum[2] + wsum[3];
}
__global__ void k_scanb(int* __restrict__ bcnt, int nb, int* cnt) {
    __shared__ int tsum[256];
    __shared__ int tpre[257];
    int t = threadIdx.x;
    int ch = (nb + 255) / 256;
    int lo = t * ch, hi = min(lo + ch, nb);
    int s = 0;
    for (int i = lo; i < hi; i++) s += bcnt[i];
    tsum[t] = s;
    __syncthreads();
    if (t == 0) {
        int run = 0;
        for (int j = 0; j < 256; j++) { tpre[j] = run; run += tsum[j]; }
        tpre[256] = run;
        cnt[0] = run;  // total actives
    }
    __syncthreads();
    int run = tpre[t];
    for (int i = lo; i < hi; i++) { int x = bcnt[i]; bcnt[i] = run; run += x; }
}
__global__ void k_fill(const uint8_t* __restrict__ occ, long N,
                       const int* __restrict__ bcnt, int* __restrict__ list) {
    long v = (long)blockIdx.x * 256 + threadIdx.x;
    int a = (v < N) && occ[v];
    unsigned long long m = __ballot(a != 0);
    __shared__ int wsum[4];
    int lane = threadIdx.x & 63, wid = threadIdx.x >> 6;
    if (lane == 0) wsum[wid] = (int)__popcll(m);
    __syncthreads();
    int base = bcnt[blockIdx.x];
    for (int w = 0; w < wid; w++) base += wsum[w];
    if (a) list[base + (int)__popcll(m & ((1ull << lane) - 1ull))] = (int)v;
}

// ---------------- sparse 3^3 conv, CIN->16, relu ---------------------------
// R12: occ-byte prefetch into 27-bit mask (independent loads, one drain),
// then R7's serial tap body branching on register bits. wl reads stay
// wave-uniform (broadcast, no conflicts).
template <int CIN, int D>
__global__ void k_sconv16(const float* __restrict__ xin, const void* w, const void* bias,
                          const uint8_t* __restrict__ occ, const int* __restrict__ list,
                          const int* __restrict__ cnt, float* __restrict__ out,
                          const int* __restrict__ flags) {
    __shared__ float wl[27 * CIN * 16 + 16];
    const int n = cnt[0];
    if (blockIdx.x * 256 >= n) return;
    const int bf = flags[0];
    for (int i = threadIdx.x; i < 27 * CIN * 16; i += 256) wl[i] = ldf(w, i, bf);
    if (threadIdx.x < 16) wl[27 * CIN * 16 + threadIdx.x] = ldf(bias, threadIdx.x, bf);
    __syncthreads();
    int i = blockIdx.x * 256 + threadIdx.x;
    if (i >= n) return;
    int v = list[i];
    int wd = v % D, hh = (v / D) % D, dd = v / (D * D);
    // prefetch 27 neighbor-occupancy bytes (independent loads, single wait)
    uint32_t nbm = 0u;
    {
        int t = 0;
#pragma unroll
        for (int kd = 0; kd < 3; kd++)
#pragma unroll
            for (int kh = 0; kh < 3; kh++)
#pragma unroll
                for (int kw = 0; kw < 3; kw++, t++) {
                    int d2 = dd + kd - 1, h2 = hh + kh - 1, w2 = wd + kw - 1;
                    int ok = (int)((unsigned)d2 < (unsigned)D) &
                             (int)((unsigned)h2 < (unsigned)D) &
                             (int)((unsigned)w2 < (unsigned)D);
                    int nv = v + (kd - 1) * D * D + (kh - 1) * D + (kw - 1);
                    int nvc = ok ? nv : v;  // clamped: load always in-bounds
                    nbm |= ((uint32_t)((int)occ[nvc] & ok)) << t;
                }
    }
    float acc[16];
#pragma unroll
    for (int co = 0; co < 16; co++) acc[co] = 0.0f;
    int t = 0;
    for (int kd = 0; kd < 3; kd++) {
        for (int kh = 0; kh < 3; kh++) {
            for (int kw = 0; kw < 3; kw++, t++) {
                if (!((nbm >> t) & 1u)) continue;  // register test, no mem chain
                long nv = (long)v + (kd - 1) * (D * D) + (kh - 1) * D + (kw - 1);
                const float4* xp = (const float4*)(xin + nv * CIN);
                const float* wp = &wl[((kd * 3 + kh) * 3 + kw) * CIN * 16];
#pragma unroll
                for (int c4 = 0; c4 < CIN / 4; c4++) {
                    float4 x4 = xp[c4];
                    const float* wq = wp + c4 * 64;
#pragma unroll
                    for (int co = 0; co < 16; co++) acc[co] += x4.x * wq[co];
#pragma unroll
                    for (int co = 0; co < 16; co++) acc[co] += x4.y * wq[16 + co];
#pragma unroll
                    for (int co = 0; co < 16; co++) acc[co] += x4.z * wq[32 + co];
#pragma unroll
                    for (int co = 0; co < 16; co++) acc[co] += x4.w * wq[48 + co];
                }
            }
        }
    }
    float* op = out + (long)v * 16;
#pragma unroll
    for (int co = 0; co < 16; co++) {
        float val = rndb(acc[co], bf);
        val = rndb(val + wl[27 * CIN * 16 + co], bf);
        op[co] = fmaxf(val, 0.0f);
    }
}

// ---------------- sparse cls conv (16->1): d_out slice + position keys -----
template <int D>
__global__ void k_scls(const float* __restrict__ feat, const void* w, const void* bias,
                       const uint8_t* __restrict__ occ, const int* __restrict__ list,
                       const int* __restrict__ cnt, void* dout, long ooff,
                       uint32_t* __restrict__ keyl, const int* __restrict__ flags) {
    __shared__ float wl[27 * 16 + 1];
    const int n = cnt[0];
    if (blockIdx.x * 256 >= n) return;
    const int bf = flags[0];
    for (int i = threadIdx.x; i < 27 * 16; i += 256) wl[i] = ldf(w, i, bf);
    if (threadIdx.x == 0) wl[432] = ldf(bias, 0, bf);
    __syncthreads();
    int i = blockIdx.x * 256 + threadIdx.x;
    if (i >= n) return;
    int v = list[i];
    int wd = v % D, hh = (v / D) % D, dd = v / (D * D);
    float acc = 0.0f;
    for (int kd = 0; kd < 3; kd++) {
        int d2 = dd + kd - 1;
        if ((unsigned)d2 >= (unsigned)D) continue;
        for (int kh = 0; kh < 3; kh++) {
            int h2 = hh + kh - 1;
            if ((unsigned)h2 >= (unsigned)D) continue;
            for (int kw = 0; kw < 3; kw++) {
                int w2 = wd + kw - 1;
                if ((unsigned)w2 >= (unsigned)D) continue;
                long nv = ((long)d2 * D + h2) * D + w2;
                if (!occ[nv]) continue;
                const float4* xp = (const float4*)(feat + nv * 16);
                const float* wp = &wl[((kd * 3 + kh) * 3 + kw) * 16];
                float4 a0 = xp[0], a1 = xp[1], a2 = xp[2], a3 = xp[3];
                acc += a0.x * wp[0] + a0.y * wp[1] + a0.z * wp[2] + a0.w * wp[3];
                acc += a1.x * wp[4] + a1.y * wp[5] + a1.z * wp[6] + a1.w * wp[7];
                acc += a2.x * wp[8] + a2.y * wp[9] + a2.z * wp[10] + a2.w * wp[11];
                acc += a3.x * wp[12] + a3.y * wp[13] + a3.z * wp[14] + a3.w * wp[15];
            }
        }
    }
    float val = rndb(acc, bf);
    val = rndb(val + wl[432], bf);
    stf(dout, ooff + v, val, bf);
    keyl[i] = fkey(val);
}

// ---------------- sparse 2x up-sample (transpose conv, kernel-flipped) -----
template <int Dp>
__global__ void k_sup(const float* __restrict__ featp, const void* w, const void* bias,
                      const int* __restrict__ list, const int* __restrict__ cnt,
                      float* __restrict__ hrelu, const int* __restrict__ flags) {
    __shared__ float wl[2048 + 16];
    const int n = cnt[0];
    if (blockIdx.x * 256 >= n) return;
    const int bf = flags[0];
    for (int i = threadIdx.x; i < 2048; i += 256) wl[i] = ldf(w, i, bf);
    if (threadIdx.x < 16) wl[2048 + threadIdx.x] = ldf(bias, threadIdx.x, bf);
    __syncthreads();
    int i = blockIdx.x * 256 + threadIdx.x;
    if (i >= n) return;
    int v = list[i];
    const int D = Dp * 2;
    int wd = v % D, hh = (v / D) % D, dd = v / (D * D);
    const float4* xp = (const float4*)(featp +
        ((long)((dd >> 1) * Dp + (hh >> 1)) * Dp + (wd >> 1)) * 16);
    // y[o] = x[o>>1] * w[1-(o&1)] per axis (jax conv_transpose, k=2,s=2,'VALID')
    int a = 1 - (dd & 1), b2 = 1 - (hh & 1), c = 1 - (wd & 1);
    const float* wp = &wl[((a * 2 + b2) * 2 + c) * 256];
    float acc[16];
#pragma unroll
    for (int co = 0; co < 16; co++) acc[co] = 0.0f;
#pragma unroll
    for (int c4 = 0; c4 < 4; c4++) {
        float4 x4 = xp[c4];
        const float* wq = wp + c4 * 64;
#pragma unroll
        for (int co = 0; co < 16; co++) acc[co] += x4.x * wq[co];
#pragma unroll
        for (int co = 0; co < 16; co++) acc[co] += x4.y * wq[16 + co];
#pragma unroll
        for (int co = 0; co < 16; co++) acc[co] += x4.z * wq[32 + co];
#pragma unroll
        for (int co = 0; co < 16; co++) acc[co] += x4.w * wq[48 + co];
    }
    float* op = hrelu + (long)v * 16;
#pragma unroll
    for (int co = 0; co < 16; co++) {
        float val = rndb(acc[co], bf);
        val = rndb(val + wl[2048 + co], bf);
        op[co] = fmaxf(val, 0.0f);  // relu(h) feeding next conv
    }
}

template <int Dp>
__global__ void k_expand(const uint8_t* __restrict__ maskp, uint8_t* __restrict__ occc) {
    const int D = Dp * 2;
    long v = (long)blockIdx.x * blockDim.x + threadIdx.x;
    if (v >= (long)D * D * D) return;
    int wd = (int)(v % D), hh = (int)((v / D) % D), dd = (int)(v / ((long)D * D));
    occc[v] = maskp[((long)(dd >> 1) * Dp + (hh >> 1)) * Dp + (wd >> 1)];
}

// ---------------- exact top-k over position keys (radix-16/16) -------------
// Per-block LDS histogram (R7 win): 65536 bins as packed u16 pairs in 128KB
// LDS; per-block entries <= 8192 so u16 never overflows.
// state: [0]=B(-1 => select-all) [1]=count_above [2]=krem [3]=K [4]=ties_needed [5]=tie_count
__global__ void k_hzero(uint32_t* hist1, int* state) {
    int i = blockIdx.x * blockDim.x + threadIdx.x;
    if (i < 65536) hist1[i] = 0u;
    if (i < 16) state[i] = 0;
}
__global__ void k_hist1(const uint32_t* __restrict__ keyl, const int* cnt,
                        uint32_t* __restrict__ hist) {
    __shared__ uint32_t lh[32768];
    const int n = cnt[0];
    for (int j = threadIdx.x; j < 32768; j += 256) lh[j] = 0u;
    __syncthreads();
    const int stride = gridDim.x * 256;
    for (int i = blockIdx.x * 256 + threadIdx.x; i < n; i += stride) {
        uint32_t bin = keyl[i] >> 16;
        atomicAdd(&lh[bin >> 1], 1u << ((bin & 1u) << 4));
    }
    __syncthreads();
    for (int j = threadIdx.x; j < 32768; j += 256) {
        uint32_t p = lh[j];
        if (p) {
            uint32_t lo = p & 0xFFFFu, hi = p >> 16;
            if (lo) atomicAdd(&hist[2 * j], lo);
            if (hi) atomicAdd(&hist[2 * j + 1], hi);
        }
    }
}
__global__ void k_scan1(const uint32_t* hist, const void* kptr, const int* cnt,
                        int* state, uint32_t* hist2) {
    __shared__ uint32_t part[256];
    int t = threadIdx.x;
    uint32_t s = 0;
    for (int j = 0; j < 256; j++) s += hist[t * 256 + j];
    part[t] = s;
    for (int i = t; i < 65536; i += 256) hist2[i] = 0u;
    __syncthreads();
    if (t == 0) {
        uint32_t k = (uint32_t)((const int*)kptr)[0];
        uint32_t total = (uint32_t)cnt[0];
        if (k >= total) {
            state[0] = -1;
            state[3] = 0;   // K=0 -> sel = (key > 0), true for all finite keys
            state[4] = 0;
            state[5] = 0;
            return;
        }
        uint32_t cum = 0, cab = 0;
        int B = 0;
        for (int c = 255; c >= 0; c--) {
            if (cum + part[c] >= k) {
                uint32_t cc = cum;
                for (int b = c * 256 + 255; b >= c * 256; b--) {
                    uint32_t h = hist[b];
                    if (cc + h >= k) { B = b; cab = cc; break; }
                    cc += h;
                }
                break;
            }
            cum += part[c];
        }
        state[0] = B;
        state[1] = (int)cab;
        state[2] = (int)(k - cab);
    }
}
__global__ void k_hist2(const uint32_t* __restrict__ keyl, const int* cnt,
                        const int* state, uint32_t* __restrict__ hist2) {
    if (state[0] < 0) return;
    __shared__ uint32_t lh[32768];
    const int n = cnt[0];
    const int B = state[0];
    for (int j = threadIdx.x; j < 32768; j += 256) lh[j] = 0u;
    __syncthreads();
    const int stride = gridDim.x * 256;
    for (int i = blockIdx.x * 256 + threadIdx.x; i < n; i += stride) {
        uint32_t key = keyl[i];
        if ((int)(key >> 16) == B) {
            uint32_t bin = key & 0xFFFFu;
            atomicAdd(&lh[bin >> 1], 1u << ((bin & 1u) << 4));
        }
    }
    __syncthreads();
    for (int j = threadIdx.x; j < 32768; j += 256) {
        uint32_t p = lh[j];
        if (p) {
            uint32_t lo = p & 0xFFFFu, hi = p >> 16;
            if (lo) atomicAdd(&hist2[2 * j], lo);
            if (hi) atomicAdd(&hist2[2 * j + 1], hi);
        }
    }
}
__global__ void k_scan2(const uint32_t* hist2, int* state) {
    __shared__ uint32_t part[256];
    int t = threadIdx.x;
    if (state[0] < 0) return;
    uint32_t s = 0;
    for (int j = 0; j < 256; j++) s += hist2[t * 256 + j];
    part[t] = s;
    __syncthreads();
    if (t == 0) {
        uint32_t krem = (uint32_t)state[2];
        uint32_t cum = 0, cl = 0;
        int L = 0;
        for (int c = 255; c >= 0; c--) {
            if (cum + part[c] >= krem) {
                uint32_t cc = cum;
                for (int b = c * 256 + 255; b >= c * 256; b--) {
                    uint32_t h = hist2[b];
                    if (cc + h >= krem) { L = b; cl = cc; break; }
                    cc += h;
                }
                break;
            }
            cum += part[c];
        }
        uint32_t K = ((uint32_t)state[0] << 16) | (uint32_t)L;
        state[3] = (int)K;
        state[4] = (int)(krem - cl);
        state[5] = 0;
    }
}
// tie collection wave-aggregated: one atomicAdd-with-return per wave
__global__ void k_mark(const uint32_t* __restrict__ keyl, const int* __restrict__ list,
                       const int* cnt, int* state, uint8_t* __restrict__ sel, int* tiel) {
    int n = cnt[0];
    int i = blockIdx.x * 256 + threadIdx.x;
    uint32_t K = (uint32_t)state[3];
    int v = 0, isTie = 0;
    if (i < n) {
        uint32_t key = keyl[i];
        v = list[i];
        sel[v] = (key > K) ? (uint8_t)1 : (uint8_t)0;
        isTie = (key == K && K != 0u);
    }
    unsigned long long m = __ballot(isTie != 0);
    if (m) {
        int lane = threadIdx.x & 63;
        int leader = __ffsll((unsigned long long)m) - 1;
        int base = 0;
        if (lane == leader) base = atomicAdd(&state[5], (int)__popcll(m));
        base = __shfl(base, leader, 64);
        if (isTie) {
            int pos = base + (int)__popcll(m & ((1ull << lane) - 1ull));
            if (pos < TIE_CAP) tiel[pos] = v;
        }
    }
}
// ties at the threshold key: jax.lax.top_k keeps LOWEST voxel indices first
__global__ void k_ties(const int* state, const int* tiel, uint8_t* sel) {
    __shared__ int lst[TIE_CAP];
    int T = state[5];
    if (T > TIE_CAP) T = TIE_CAP;
    int need = state[4];
    if (need <= 0 || T == 0) return;
    for (int i = threadIdx.x; i < T; i += blockDim.x) lst[i] = tiel[i];
    __syncthreads();
    for (int e = threadIdx.x; e < T; e += blockDim.x) {
        int idx = lst[e], r = 0;
        for (int j = 0; j < T; j++) r += (lst[j] < idx) ? 1 : 0;
        if (r < need) sel[idx] = 1;
    }
}
// prune for levels 0/1: write dense mask (pre-zeroed by k_cnt) at actives.
__global__ void k_sapply(const uint8_t* __restrict__ sel, const int* __restrict__ list,
                         const int* cnt, const void* gt, uint8_t* __restrict__ mask,
                         const int* flags) {
    int n = cnt[0];
    int i = blockIdx.x * 256 + threadIdx.x;
    if (i >= n) return;
    int v = list[i];
    mask[v] = (uint8_t)(sel[v] || ldb(gt, v, flags[1]));
}
// final level: scatter masked features straight into pre-zeroed d_out
__global__ void k_sapply_out(const uint8_t* __restrict__ sel, const int* __restrict__ list,
                             const int* cnt, const void* gt, const float* __restrict__ feat,
                             void* dout, const int* flags) {
    int n = cnt[0];
    int i = blockIdx.x * 256 + threadIdx.x;
    if (i >= n) return;
    int v = list[i];
    if (!(sel[v] || ldb(gt, v, flags[1]))) return;
    const int bf = flags[0];
    long base = OFF_OUT + (long)v * 16;
    const float* fp = feat + (long)v * 16;
#pragma unroll
    for (int co = 0; co < 16; co++) stf(dout, base + co, fp[co], bf);
}

// ---------------- launcher ----------------
extern "C" void kernel_launch(void* const* d_in, const int* in_sizes, int n_in,
                              void* d_out, int out_size, void* d_ws, size_t ws_size,
                              hipStream_t stream) {
    char* ws = (char*)d_ws;
    int* flags = (int*)(ws + O_FLAGS);
    int* cnt = flags + 32;
    int* state = (int*)(ws + O_STATE);
    int* tiel = (int*)(ws + O_TIE);
    uint32_t* h1 = (uint32_t*)(ws + O_HIST1);
    uint32_t* h2 = (uint32_t*)(ws + O_HIST2);
    uint8_t* occ0 = (uint8_t*)(ws + O_OCC0);
    uint8_t* occ1 = (uint8_t*)(ws + O_OCC1);
    uint8_t* occ2 = (uint8_t*)(ws + O_OCC2);
    uint8_t* mask0 = (uint8_t*)(ws + O_MASK0);
    uint8_t* mask1 = (uint8_t*)(ws + O_MASK1);
    int* bcnt = (int*)(ws + O_BCNT);
    uint8_t* sel = (uint8_t*)(ws + O_SEL);
    uint32_t* keyl = (uint32_t*)(ws + O_KEYS);
    float* feat0 = (float*)(ws + O_FEAT0);
    float* hr1 = (float*)(ws + O_HR1);
    float* feat1 = (float*)(ws + O_FEAT1);
    float* hr2 = (float*)(ws + O_HR2);
    float* feat2 = (float*)(ws + O_FEAT2);
    // aliased scratch (lifetimes verified disjoint):
    int* list0 = (int*)(ws + O_HR1);                      // lvl0; hr1 written at lvl1
    int* list1 = (int*)(ws + O_HR2);                      // lvl1; hr2 written at lvl2
    int* list2 = (int*)(ws + O_HR1);                      // lvl2; hr1 dead after lvl1 conv
    float* xf = (float*)(ws + O_HR2 + (4UL << 20));       // lvl0 only; 4 MB

    // inputs: 0:x 1:occ0 2:gt0 3:gt1 4:gt2 5:w_conv0 6:b_conv0 7:w_cls0 8:b_cls0
    // 9:w_up1 10:b_up1 11:w_conv1 12:b_conv1 13:w_cls1 14:b_cls1
    // 15:w_up2 16:b_up2 17:w_conv2 18:b_conv2 19:w_cls2 20:b_cls2 21-23:nums
    k_fzero<<<1, 64, 0, stream>>>(flags);
    k_fscan<<<512, 256, 0, stream>>>(d_in[0], d_in[4], flags);
    k_ffinal<<<1, 64, 0, stream>>>(flags);
    k_zout<<<2048, 256, 0, stream>>>(d_out, (long)out_size, flags);
    k_occ0<<<N0 / 256, 256, 0, stream>>>(d_in[1], occ0, flags);
    k_xcast<<<(N0 * 32) / 256, 256, 0, stream>>>(d_in[0], xf, flags);

    // ---- level 0
    k_cnt<<<N0 / 256, 256, 0, stream>>>(occ0, N0, bcnt, mask0);
    k_scanb<<<1, 256, 0, stream>>>(bcnt, N0 / 256, cnt);
    k_fill<<<N0 / 256, 256, 0, stream>>>(occ0, N0, bcnt, list0);
    k_sconv16<32, 32><<<N0 / 256, 256, 0, stream>>>(xf, d_in[5], d_in[6], occ0,
                                                    list0, cnt, feat0, flags);
    k_scls<32><<<N0 / 256, 256, 0, stream>>>(feat0, d_in[7], d_in[8], occ0, list0,
                                             cnt, d_out, OFF_CLS0, keyl, flags);
    k_hzero<<<256, 256, 0, stream>>>(h1, state);
    k_hist1<<<256, 256, 0, stream>>>(keyl, cnt, h1);
    k_scan1<<<1, 256, 0, stream>>>(h1, d_in[21], cnt, state, h2);
    k_hist2<<<256, 256, 0, stream>>>(keyl, cnt, state, h2);
    k_scan2<<<1, 256, 0, stream>>>(h2, state);
    k_mark<<<N0 / 256, 256, 0, stream>>>(keyl, list0, cnt, state, sel, tiel);
    k_ties<<<1, 1024, 0, stream>>>(state, tiel, sel);
    k_sapply<<<N0 / 256, 256, 0, stream>>>(sel, list0, cnt, d_in[2], mask0, flags);

    // ---- level 1
    k_expand<32><<<N1 / 256, 256, 0, stream>>>(mask0, occ1);
    k_cnt<<<N1 / 256, 256, 0, stream>>>(occ1, N1, bcnt, mask1);
    k_scanb<<<1, 256, 0, stream>>>(bcnt, N1 / 256, cnt);
    k_fill<<<N1 / 256, 256, 0, stream>>>(occ1, N1, bcnt, list1);
    k_sup<32><<<N1 / 256, 256, 0, stream>>>(feat0, d_in[9], d_in[10], list1, cnt,
                                            hr1, flags);
    k_sconv16<16, 64><<<N1 / 256, 256, 0, stream>>>(hr1, d_in[11], d_in[12], occ1,
                                                    list1, cnt, feat1, flags);
    k_scls<64><<<N1 / 256, 256, 0, stream>>>(feat1, d_in[13], d_in[14], occ1, list1,
                                             cnt, d_out, OFF_CLS1, keyl, flags);
    k_hzero<<<256, 256, 0, stream>>>(h1, state);
    k_hist1<<<256, 256, 0, stream>>>(keyl, cnt, h1);
    k_scan1<<<1, 256, 0, stream>>>(h1, d_in[22], cnt, state, h2);
    k_hist2<<<256, 256, 0, stream>>>(keyl, cnt, state, h2);
    k_scan2<<<1, 256, 0, stream>>>(h2, state);
    k_mark<<<N1 / 256, 256, 0, stream>>>(keyl, list1, cnt, state, sel, tiel);
    k_ties<<<1, 1024, 0, stream>>>(state, tiel, sel);
    k_sapply<<<N1 / 256, 256, 0, stream>>>(sel, list1, cnt, d_in[3], mask1, flags);

    // ---- level 2
    k_expand<64><<<N2 / 256, 256, 0, stream>>>(mask1, occ2);
    k_cnt<<<N2 / 256, 256, 0, stream>>>(occ2, N2, bcnt, (uint8_t*)0);
    k_scanb<<<1, 256, 0, stream>>>(bcnt, N2 / 256, cnt);
    k_fill<<<N2 / 256, 256, 0, stream>>>(occ2, N2, bcnt, list2);
    k_sup<64><<<N2 / 256, 256, 0, stream>>>(feat1, d_in[15], d_in[16], list2, cnt,
                                            hr2, flags);
    k_sconv16<16, 128><<<N2 / 256, 256, 0, stream>>>(hr2, d_in[17], d_in[18], occ2,
                                                     list2, cnt, feat2, flags);
    k_scls<128><<<N2 / 256, 256, 0, stream>>>(feat2, d_in[19], d_in[20], occ2, list2,
                                              cnt, d_out, OFF_CLS2, keyl, flags);
    k_hzero<<<256, 256, 0, stream>>>(h1, state);
    k_hist1<<<256, 256, 0, stream>>>(keyl, cnt, h1);
    k_scan1<<<1, 256, 0, stream>>>(h1, d_in[23], cnt, state, h2);
    k_hist2<<<256, 256, 0, stream>>>(keyl, cnt, state, h2);
    k_scan2<<<1, 256, 0, stream>>>(h2, state);
    k_mark<<<N2 / 256, 256, 0, stream>>>(keyl, list2, cnt, state, sel, tiel);
    k_ties<<<1, 1024, 0, stream>>>(state, tiel, sel);
    k_sapply_out<<<N2 / 256, 256, 0, stream>>>(sel, list2, cnt, d_in[4], feat2,
                                               d_out, flags);
}

// Round 13
// 886.378 us; speedup vs baseline: 1.4339x; 1.0428x over previous
//
#include <hip/hip_runtime.h>
#include <stdint.h>

// R13 = R12 (924us) + (a) k_sconv16 split 2 threads/voxel (8 co each) to
// double latency-hiding TLP — paired lanes share tap cache lines, weight-LDS
// reads are a 2-address broadcast (free); (b) R12's occ-prefetch bitmask
// ported to k_scls (removes its serial occ-load chain).

// ---------------- problem constants ----------------
#define N0 32768      // 32^3
#define N1 262144     // 64^3
#define N2 2097152    // 128^3

// d_out element offsets (cls0, cls1, cls2, out)
#define OFF_CLS0 0L
#define OFF_CLS1 32768L
#define OFF_CLS2 294912L
#define OFF_OUT  2392064L

// ---------------- ws layout (byte offsets, within proven ~320MB footprint) --
#define O_FLAGS 0UL            // int[64]: [0]=bf16 [1]=boolmode [8..]=counters [32]=list cnt
#define O_STATE 256UL
#define O_TIE   512UL          // 16000 ints (tie voxel-index list)
#define O_HIST1 66048UL        // 65536 u32
#define O_HIST2 328192UL       // 65536 u32
#define O_OCC0  590336UL       // N0 u8
#define O_OCC1  623104UL       // N1 u8
#define O_OCC2  885248UL       // N2 u8
#define O_MASK0 2982400UL
#define O_MASK1 3015168UL
#define O_BCNT  3277312UL      // 8192 ints (block counts / exclusive prefix)
#define O_SEL   5374464UL      // N2 u8 (dense by voxel, only active entries used)
#define O_KEYS  7471616UL      // N2 u32 keyl[] by LIST POSITION
#define O_FEAT0 15860224UL     // N0*16 f32
#define O_HR1   17957376UL     // N1*16 f32 ; ALIASED: list0 (lvl0), list2 (lvl2, hr1 dead)
#define O_FEAT1 34734592UL     // N1*16 f32
#define O_HR2   51511808UL     // N2*16 f32 ; ALIASED: list1 @+0 (lvl1), xf @+4MB (lvl0)
#define O_FEAT2 185729536UL    // N2*16 f32  (ends ~320 MB)

#define TIE_CAP 16000

// ---------------- dtype-flexible helpers ----------------
// flags[0] = floats-are-bf16; flags[1] = bool mode (0 i32,1 u8,2 bf16,3 f32,4 i64)
__device__ __forceinline__ float ldf(const void* p, long i, int bf) {
    if (bf) {
        uint16_t h = ((const uint16_t*)p)[i];
        return __uint_as_float(((uint32_t)h) << 16);
    }
    return ((const float*)p)[i];
}
__device__ __forceinline__ int ldb(const void* p, long i, int m) {
    switch (m) {
        case 0: return ((const int*)p)[i] != 0;
        case 1: return ((const uint8_t*)p)[i] != 0;
        case 2: { uint16_t h = ((const uint16_t*)p)[i]; return (h & 0x7FFF) != 0; }
        case 4: return ((const long long*)p)[i] != 0;
        default: { float f = ((const float*)p)[i]; return f != 0.0f; }
    }
}
__device__ __forceinline__ float rndb(float f, int en) {
    if (!en) return f;
    uint32_t u = __float_as_uint(f);
    u += 0x7FFFu + ((u >> 16) & 1u);
    u &= 0xFFFF0000u;
    return __uint_as_float(u);
}
__device__ __forceinline__ void stf(void* p, long i, float v, int bf) {
    if (bf) {
        uint32_t u = __float_as_uint(v);
        u += 0x7FFFu + ((u >> 16) & 1u);
        ((uint16_t*)p)[i] = (uint16_t)(u >> 16);
    } else {
        ((float*)p)[i] = v;
    }
}
// order-preserving float->u32 key; all finite keys are > 0
__device__ __forceinline__ uint32_t fkey(float f) {
    f = f + 0.0f;
    uint32_t u = __float_as_uint(f);
    return (u & 0x80000000u) ? ~u : (u | 0x80000000u);
}

// ---------------- runtime dtype detection (parallel) ----------------------
__global__ void k_fzero(int* flags) {
    int t = threadIdx.x;
    if (t < 16) flags[8 + t] = 0;
}
__global__ void k_fscan(const void* x, const void* gt2, int* flags) {
    int* cnt = flags + 8;
    __shared__ int lc[8];
    int t = threadIdx.x;
    if (t < 8) lc[t] = 0;
    __syncthreads();
    long gid = (long)blockIdx.x * blockDim.x + threadIdx.x;
    long gstride = (long)gridDim.x * blockDim.x;
    int ltiny = 0;
    const uint32_t* xu = (const uint32_t*)x;
    for (long i = gid; i < 524288; i += gstride) {
        uint32_t u = xu[i];
        uint32_t e = (u >> 23) & 0xFFu;
        if (e == 0u && (u & 0x7FFFFFu) != 0u) ltiny++;
    }
    int l1off = 0, l1any = 0, l3f = 0, l84 = 0;
    const uint8_t* g = (const uint8_t*)gt2;
    for (long i = gid; i < 2097152; i += gstride) {
        uint8_t b = g[i];
        if (b == 1u) {
            l1any++;
            if ((i & 3) != 0) l1off++;
            if ((i & 7) == 4) l84++;
        }
        if (b == 0x3Fu && (i & 3) == 1) l3f++;
    }
    if (ltiny) atomicAdd(&lc[0], ltiny);
    if (l1off) atomicAdd(&lc[1], l1off);
    if (l1any) atomicAdd(&lc[2], l1any);
    if (l3f)   atomicAdd(&lc[3], l3f);
    if (l84)   atomicAdd(&lc[4], l84);
    __syncthreads();
    if (t < 5 && lc[t]) atomicAdd(&cnt[t], lc[t]);
}
__global__ void k_ffinal(int* flags) {
    if (threadIdx.x != 0 || blockIdx.x != 0) return;
    const int* cnt = flags + 8;
    flags[0] = (cnt[0] > 8) ? 1 : 0;
    int bm;
    if (cnt[1] > 8)       bm = 1;
    else if (cnt[2] > 8)  bm = (cnt[4] > 8) ? 0 : 4;
    else if (cnt[3] > 8)  bm = 2;
    else                  bm = 3;
    flags[1] = bm;
}

// zero entire d_out (harness re-poisons to 0xAA each launch)
__global__ void k_zout(void* dout, long out_elems, const int* flags) {
    long bytes = out_elems * (flags[0] ? 2 : 4);
    long n16 = bytes >> 4;
    uint4 z = make_uint4(0, 0, 0, 0);
    uint4* p = (uint4*)dout;
    long stride = (long)gridDim.x * blockDim.x;
    for (long i = (long)blockIdx.x * blockDim.x + threadIdx.x; i < n16; i += stride)
        p[i] = z;
}

__global__ void k_occ0(const void* occraw, uint8_t* occ, const int* flags) {
    long v = (long)blockIdx.x * blockDim.x + threadIdx.x;
    if (v >= N0) return;
    occ[v] = (uint8_t)ldb(occraw, v, flags[1]);
}

__global__ void k_xcast(const void* x, float* xf, const int* flags) {
    long i = (long)blockIdx.x * blockDim.x + threadIdx.x;
    if (i >= (long)N0 * 32) return;
    xf[i] = ldf(x, i, flags[0]);
}

// ---------------- 3-phase scan compaction (zero contended atomics) ---------
__global__ void k_cnt(const uint8_t* __restrict__ occ, long N,
                      int* __restrict__ bcnt, uint8_t* maskz) {
    long v = (long)blockIdx.x * 256 + threadIdx.x;
    int a = (v < N) && occ[v];
    if (maskz && v < N) maskz[v] = 0;
    unsigned long long m = __ballot(a != 0);
    __shared__ int wsum[4];
    int lane = threadIdx.x & 63, wid = threadIdx.x >> 6;
    if (lane == 0) wsum[wid] = (int)__popcll(m);
    __syncthreads();
    if (threadIdx.x == 0)
        bcnt[blockIdx.x] = wsum[0] + wsum[1] + wsum[2] + wsum[3];
}
__global__ void k_scanb(int* __restrict__ bcnt, int nb, int* cnt) {
    __shared__ int tsum[256];
    __shared__ int tpre[257];
    int t = threadIdx.x;
    int ch = (nb + 255) / 256;
    int lo = t * ch, hi = min(lo + ch, nb);
    int s = 0;
    for (int i = lo; i < hi; i++) s += bcnt[i];
    tsum[t] = s;
    __syncthreads();
    if (t == 0) {
        int run = 0;
        for (int j = 0; j < 256; j++) { tpre[j] = run; run += tsum[j]; }
        tpre[256] = run;
        cnt[0] = run;  // total actives
    }
    __syncthreads();
    int run = tpre[t];
    for (int i = lo; i < hi; i++) { int x = bcnt[i]; bcnt[i] = run; run += x; }
}
__global__ void k_fill(const uint8_t* __restrict__ occ, long N,
                       const int* __restrict__ bcnt, int* __restrict__ list) {
    long v = (long)blockIdx.x * 256 + threadIdx.x;
    int a = (v < N) && occ[v];
    unsigned long long m = __ballot(a != 0);
    __shared__ int wsum[4];
    int lane = threadIdx.x & 63, wid = threadIdx.x >> 6;
    if (lane == 0) wsum[wid] = (int)__popcll(m);
    __syncthreads();
    int base = bcnt[blockIdx.x];
    for (int w = 0; w < wid; w++) base += wsum[w];
    if (a) list[base + (int)__popcll(m & ((1ull << lane) - 1ull))] = (int)v;
}

// ---------------- sparse 3^3 conv, CIN->16, relu ---------------------------
// 2 threads per voxel: thread half h computes co in [h*8, h*8+8). Occ-byte
// prefetch bitmask (R12), wave-uniform taps (weight reads = 2-addr broadcast).
template <int CIN, int D>
__global__ void k_sconv16(const float* __restrict__ xin, const void* w, const void* bias,
                          const uint8_t* __restrict__ occ, const int* __restrict__ list,
                          const int* __restrict__ cnt, float* __restrict__ out,
                          const int* __restrict__ flags) {
    __shared__ float wl[27 * CIN * 16 + 16];
    const int n = cnt[0];
    if (blockIdx.x * 128 >= n) return;  // 128 voxels per 256-thread block
    const int bf = flags[0];
    for (int i = threadIdx.x; i < 27 * CIN * 16; i += 256) wl[i] = ldf(w, i, bf);
    if (threadIdx.x < 16) wl[27 * CIN * 16 + threadIdx.x] = ldf(bias, threadIdx.x, bf);
    __syncthreads();
    int gid = blockIdx.x * 256 + threadIdx.x;
    int i = gid >> 1;
    if (i >= n) return;
    const int half = gid & 1;
    int v = list[i];
    int wd = v % D, hh = (v / D) % D, dd = v / (D * D);
    // prefetch 27 neighbor-occupancy bytes (independent loads, single wait)
    uint32_t nbm = 0u;
    {
        int t = 0;
#pragma unroll
        for (int kd = 0; kd < 3; kd++)
#pragma unroll
            for (int kh = 0; kh < 3; kh++)
#pragma unroll
                for (int kw = 0; kw < 3; kw++, t++) {
                    int d2 = dd + kd - 1, h2 = hh + kh - 1, w2 = wd + kw - 1;
                    int ok = (int)((unsigned)d2 < (unsigned)D) &
                             (int)((unsigned)h2 < (unsigned)D) &
                             (int)((unsigned)w2 < (unsigned)D);
                    int nv = v + (kd - 1) * D * D + (kh - 1) * D + (kw - 1);
                    int nvc = ok ? nv : v;  // clamped: load always in-bounds
                    nbm |= ((uint32_t)((int)occ[nvc] & ok)) << t;
                }
    }
    float acc[8];
#pragma unroll
    for (int co = 0; co < 8; co++) acc[co] = 0.0f;
    int t = 0;
    for (int kd = 0; kd < 3; kd++) {
        for (int kh = 0; kh < 3; kh++) {
            for (int kw = 0; kw < 3; kw++, t++) {
                if (!((nbm >> t) & 1u)) continue;
                long nv = (long)v + (kd - 1) * (D * D) + (kh - 1) * D + (kw - 1);
                const float4* xp = (const float4*)(xin + nv * CIN);
                const float* wp = &wl[((kd * 3 + kh) * 3 + kw) * CIN * 16 + half * 8];
#pragma unroll
                for (int c4 = 0; c4 < CIN / 4; c4++) {
                    float4 x4 = xp[c4];
                    const float* wq = wp + c4 * 64;
#pragma unroll
                    for (int co = 0; co < 8; co++) acc[co] += x4.x * wq[co];
#pragma unroll
                    for (int co = 0; co < 8; co++) acc[co] += x4.y * wq[16 + co];
#pragma unroll
                    for (int co = 0; co < 8; co++) acc[co] += x4.z * wq[32 + co];
#pragma unroll
                    for (int co = 0; co < 8; co++) acc[co] += x4.w * wq[48 + co];
                }
            }
        }
    }
    float* op = out + (long)v * 16 + half * 8;
    const float* bp = &wl[27 * CIN * 16 + half * 8];
#pragma unroll
    for (int co = 0; co < 8; co++) {
        float val = rndb(acc[co], bf);
        val = rndb(val + bp[co], bf);
        op[co] = fmaxf(val, 0.0f);
    }
}

// ---------------- sparse cls conv (16->1): d_out slice + position keys -----
// R13: occ-prefetch bitmask (R12 pattern) replaces the serial occ-load chain.
template <int D>
__global__ void k_scls(const float* __restrict__ feat, const void* w, const void* bias,
                       const uint8_t* __restrict__ occ, const int* __restrict__ list,
                       const int* __restrict__ cnt, void* dout, long ooff,
                       uint32_t* __restrict__ keyl, const int* __restrict__ flags) {
    __shared__ float wl[27 * 16 + 1];
    const int n = cnt[0];
    if (blockIdx.x * 256 >= n) return;
    const int bf = flags[0];
    for (int i = threadIdx.x; i < 27 * 16; i += 256) wl[i] = ldf(w, i, bf);
    if (threadIdx.x == 0) wl[432] = ldf(bias, 0, bf);
    __syncthreads();
    int i = blockIdx.x * 256 + threadIdx.x;
    if (i >= n) return;
    int v = list[i];
    int wd = v % D, hh = (v / D) % D, dd = v / (D * D);
    // prefetch 27 neighbor-occupancy bytes (independent loads, single wait)
    uint32_t nbm = 0u;
    {
        int t = 0;
#pragma unroll
        for (int kd = 0; kd < 3; kd++)
#pragma unroll
            for (int kh = 0; kh < 3; kh++)
#pragma unroll
                for (int kw = 0; kw < 3; kw++, t++) {
                    int d2 = dd + kd - 1, h2 = hh + kh - 1, w2 = wd + kw - 1;
                    int ok = (int)((unsigned)d2 < (unsigned)D) &
                             (int)((unsigned)h2 < (unsigned)D) &
                             (int)((unsigned)w2 < (unsigned)D);
                    int nv = v + (kd - 1) * D * D + (kh - 1) * D + (kw - 1);
                    int nvc = ok ? nv : v;
                    nbm |= ((uint32_t)((int)occ[nvc] & ok)) << t;
                }
    }
    float acc = 0.0f;
    int t = 0;
    for (int kd = 0; kd < 3; kd++) {
        for (int kh = 0; kh < 3; kh++) {
            for (int kw = 0; kw < 3; kw++, t++) {
                if (!((nbm >> t) & 1u)) continue;
                long nv = (long)v + (kd - 1) * (D * D) + (kh - 1) * D + (kw - 1);
                const float4* xp = (const float4*)(feat + nv * 16);
                const float* wp = &wl[((kd * 3 + kh) * 3 + kw) * 16];
                float4 a0 = xp[0], a1 = xp[1], a2 = xp[2], a3 = xp[3];
                acc += a0.x * wp[0] + a0.y * wp[1] + a0.z * wp[2] + a0.w * wp[3];
                acc += a1.x * wp[4] + a1.y * wp[5] + a1.z * wp[6] + a1.w * wp[7];
                acc += a2.x * wp[8] + a2.y * wp[9] + a2.z * wp[10] + a2.w * wp[11];
                acc += a3.x * wp[12] + a3.y * wp[13] + a3.z * wp[14] + a3.w * wp[15];
            }
        }
    }
    float val = rndb(acc, bf);
    val = rndb(val + wl[432], bf);
    stf(dout, ooff + v, val, bf);
    keyl[i] = fkey(val);
}

// ---------------- sparse 2x up-sample (transpose conv, kernel-flipped) -----
template <int Dp>
__global__ void k_sup(const float* __restrict__ featp, const void* w, const void* bias,
                      const int* __restrict__ list, const int* __restrict__ cnt,
                      float* __restrict__ hrelu, const int* __restrict__ flags) {
    __shared__ float wl[2048 + 16];
    const int n = cnt[0];
    if (blockIdx.x * 256 >= n) return;
    const int bf = flags[0];
    for (int i = threadIdx.x; i < 2048; i += 256) wl[i] = ldf(w, i, bf);
    if (threadIdx.x < 16) wl[2048 + threadIdx.x] = ldf(bias, threadIdx.x, bf);
    __syncthreads();
    int i = blockIdx.x * 256 + threadIdx.x;
    if (i >= n) return;
    int v = list[i];
    const int D = Dp * 2;
    int wd = v % D, hh = (v / D) % D, dd = v / (D * D);
    const float4* xp = (const float4*)(featp +
        ((long)((dd >> 1) * Dp + (hh >> 1)) * Dp + (wd >> 1)) * 16);
    // y[o] = x[o>>1] * w[1-(o&1)] per axis (jax conv_transpose, k=2,s=2,'VALID')
    int a = 1 - (dd & 1), b2 = 1 - (hh & 1), c = 1 - (wd & 1);
    const float* wp = &wl[((a * 2 + b2) * 2 + c) * 256];
    float acc[16];
#pragma unroll
    for (int co = 0; co < 16; co++) acc[co] = 0.0f;
#pragma unroll
    for (int c4 = 0; c4 < 4; c4++) {
        float4 x4 = xp[c4];
        const float* wq = wp + c4 * 64;
#pragma unroll
        for (int co = 0; co < 16; co++) acc[co] += x4.x * wq[co];
#pragma unroll
        for (int co = 0; co < 16; co++) acc[co] += x4.y * wq[16 + co];
#pragma unroll
        for (int co = 0; co < 16; co++) acc[co] += x4.z * wq[32 + co];
#pragma unroll
        for (int co = 0; co < 16; co++) acc[co] += x4.w * wq[48 + co];
    }
    float* op = hrelu + (long)v * 16;
#pragma unroll
    for (int co = 0; co < 16; co++) {
        float val = rndb(acc[co], bf);
        val = rndb(val + wl[2048 + co], bf);
        op[co] = fmaxf(val, 0.0f);  // relu(h) feeding next conv
    }
}

template <int Dp>
__global__ void k_expand(const uint8_t* __restrict__ maskp, uint8_t* __restrict__ occc) {
    const int D = Dp * 2;
    long v = (long)blockIdx.x * blockDim.x + threadIdx.x;
    if (v >= (long)D * D * D) return;
    int wd = (int)(v % D), hh = (int)((v / D) % D), dd = (int)(v / ((long)D * D));
    occc[v] = maskp[((long)(dd >> 1) * Dp + (hh >> 1)) * Dp + (wd >> 1)];
}

// ---------------- exact top-k over position keys (radix-16/16) -------------
// Per-block LDS histogram (R7 win): 65536 bins as packed u16 pairs in 128KB
// LDS; per-block entries <= 8192 so u16 never overflows.
// state: [0]=B(-1 => select-all) [1]=count_above [2]=krem [3]=K [4]=ties_needed [5]=tie_count
__global__ void k_hzero(uint32_t* hist1, int* state) {
    int i = blockIdx.x * blockDim.x + threadIdx.x;
    if (i < 65536) hist1[i] = 0u;
    if (i < 16) state[i] = 0;
}
__global__ void k_hist1(const uint32_t* __restrict__ keyl, const int* cnt,
                        uint32_t* __restrict__ hist) {
    __shared__ uint32_t lh[32768];
    const int n = cnt[0];
    for (int j = threadIdx.x; j < 32768; j += 256) lh[j] = 0u;
    __syncthreads();
    const int stride = gridDim.x * 256;
    for (int i = blockIdx.x * 256 + threadIdx.x; i < n; i += stride) {
        uint32_t bin = keyl[i] >> 16;
        atomicAdd(&lh[bin >> 1], 1u << ((bin & 1u) << 4));
    }
    __syncthreads();
    for (int j = threadIdx.x; j < 32768; j += 256) {
        uint32_t p = lh[j];
        if (p) {
            uint32_t lo = p & 0xFFFFu, hi = p >> 16;
            if (lo) atomicAdd(&hist[2 * j], lo);
            if (hi) atomicAdd(&hist[2 * j + 1], hi);
        }
    }
}
__global__ void k_scan1(const uint32_t* hist, const void* kptr, const int* cnt,
                        int* state, uint32_t* hist2) {
    __shared__ uint32_t part[256];
    int t = threadIdx.x;
    uint32_t s = 0;
    for (int j = 0; j < 256; j++) s += hist[t * 256 + j];
    part[t] = s;
    for (int i = t; i < 65536; i += 256) hist2[i] = 0u;
    __syncthreads();
    if (t == 0) {
        uint32_t k = (uint32_t)((const int*)kptr)[0];
        uint32_t total = (uint32_t)cnt[0];
        if (k >= total) {
            state[0] = -1;
            state[3] = 0;   // K=0 -> sel = (key > 0), true for all finite keys
            state[4] = 0;
            state[5] = 0;
            return;
        }
        uint32_t cum = 0, cab = 0;
        int B = 0;
        for (int c = 255; c >= 0; c--) {
            if (cum + part[c] >= k) {
                uint32_t cc = cum;
                for (int b = c * 256 + 255; b >= c * 256; b--) {
                    uint32_t h = hist[b];
                    if (cc + h >= k) { B = b; cab = cc; break; }
                    cc += h;
                }
                break;
            }
            cum += part[c];
        }
        state[0] = B;
        state[1] = (int)cab;
        state[2] = (int)(k - cab);
    }
}
__global__ void k_hist2(const uint32_t* __restrict__ keyl, const int* cnt,
                        const int* state, uint32_t* __restrict__ hist2) {
    if (state[0] < 0) return;
    __shared__ uint32_t lh[32768];
    const int n = cnt[0];
    const int B = state[0];
    for (int j = threadIdx.x; j < 32768; j += 256) lh[j] = 0u;
    __syncthreads();
    const int stride = gridDim.x * 256;
    for (int i = blockIdx.x * 256 + threadIdx.x; i < n; i += stride) {
        uint32_t key = keyl[i];
        if ((int)(key >> 16) == B) {
            uint32_t bin = key & 0xFFFFu;
            atomicAdd(&lh[bin >> 1], 1u << ((bin & 1u) << 4));
        }
    }
    __syncthreads();
    for (int j = threadIdx.x; j < 32768; j += 256) {
        uint32_t p = lh[j];
        if (p) {
            uint32_t lo = p & 0xFFFFu, hi = p >> 16;
            if (lo) atomicAdd(&hist2[2 * j], lo);
            if (hi) atomicAdd(&hist2[2 * j + 1], hi);
        }
    }
}
__global__ void k_scan2(const uint32_t* hist2, int* state) {
    __shared__ uint32_t part[256];
    int t = threadIdx.x;
    if (state[0] < 0) return;
    uint32_t s = 0;
    for (int j = 0; j < 256; j++) s += hist2[t * 256 + j];
    part[t] = s;
    __syncthreads();
    if (t == 0) {
        uint32_t krem = (uint32_t)state[2];
        uint32_t cum = 0, cl = 0;
        int L = 0;
        for (int c = 255; c >= 0; c--) {
            if (cum + part[c] >= krem) {
                uint32_t cc = cum;
                for (int b = c * 256 + 255; b >= c * 256; b--) {
                    uint32_t h = hist2[b];
                    if (cc + h >= krem) { L = b; cl = cc; break; }
                    cc += h;
                }
                break;
            }
            cum += part[c];
        }
        uint32_t K = ((uint32_t)state[0] << 16) | (uint32_t)L;
        state[3] = (int)K;
        state[4] = (int)(krem - cl);
        state[5] = 0;
    }
}
// tie collection wave-aggregated: one atomicAdd-with-return per wave
__global__ void k_mark(const uint32_t* __restrict__ keyl, const int* __restrict__ list,
                       const int* cnt, int* state, uint8_t* __restrict__ sel, int* tiel) {
    int n = cnt[0];
    int i = blockIdx.x * 256 + threadIdx.x;
    uint32_t K = (uint32_t)state[3];
    int v = 0, isTie = 0;
    if (i < n) {
        uint32_t key = keyl[i];
        v = list[i];
        sel[v] = (key > K) ? (uint8_t)1 : (uint8_t)0;
        isTie = (key == K && K != 0u);
    }
    unsigned long long m = __ballot(isTie != 0);
    if (m) {
        int lane = threadIdx.x & 63;
        int leader = __ffsll((unsigned long long)m) - 1;
        int base = 0;
        if (lane == leader) base = atomicAdd(&state[5], (int)__popcll(m));
        base = __shfl(base, leader, 64);
        if (isTie) {
            int pos = base + (int)__popcll(m & ((1ull << lane) - 1ull));
            if (pos < TIE_CAP) tiel[pos] = v;
        }
    }
}
// ties at the threshold key: jax.lax.top_k keeps LOWEST voxel indices first
__global__ void k_ties(const int* state, const int* tiel, uint8_t* sel) {
    __shared__ int lst[TIE_CAP];
    int T = state[5];
    if (T > TIE_CAP) T = TIE_CAP;
    int need = state[4];
    if (need <= 0 || T == 0) return;
    for (int i = threadIdx.x; i < T; i += blockDim.x) lst[i] = tiel[i];
    __syncthreads();
    for (int e = threadIdx.x; e < T; e += blockDim.x) {
        int idx = lst[e], r = 0;
        for (int j = 0; j < T; j++) r += (lst[j] < idx) ? 1 : 0;
        if (r < need) sel[idx] = 1;
    }
}
// prune for levels 0/1: write dense mask (pre-zeroed by k_cnt) at actives.
__global__ void k_sapply(const uint8_t* __restrict__ sel, const int* __restrict__ list,
                         const int* cnt, const void* gt, uint8_t* __restrict__ mask,
                         const int* flags) {
    int n = cnt[0];
    int i = blockIdx.x * 256 + threadIdx.x;
    if (i >= n) return;
    int v = list[i];
    mask[v] = (uint8_t)(sel[v] || ldb(gt, v, flags[1]));
}
// final level: scatter masked features straight into pre-zeroed d_out
__global__ void k_sapply_out(const uint8_t* __restrict__ sel, const int* __restrict__ list,
                             const int* cnt, const void* gt, const float* __restrict__ feat,
                             void* dout, const int* flags) {
    int n = cnt[0];
    int i = blockIdx.x * 256 + threadIdx.x;
    if (i >= n) return;
    int v = list[i];
    if (!(sel[v] || ldb(gt, v, flags[1]))) return;
    const int bf = flags[0];
    long base = OFF_OUT + (long)v * 16;
    const float* fp = feat + (long)v * 16;
#pragma unroll
    for (int co = 0; co < 16; co++) stf(dout, base + co, fp[co], bf);
}

// ---------------- launcher ----------------
extern "C" void kernel_launch(void* const* d_in, const int* in_sizes, int n_in,
                              void* d_out, int out_size, void* d_ws, size_t ws_size,
                              hipStream_t stream) {
    char* ws = (char*)d_ws;
    int* flags = (int*)(ws + O_FLAGS);
    int* cnt = flags + 32;
    int* state = (int*)(ws + O_STATE);
    int* tiel = (int*)(ws + O_TIE);
    uint32_t* h1 = (uint32_t*)(ws + O_HIST1);
    uint32_t* h2 = (uint32_t*)(ws + O_HIST2);
    uint8_t* occ0 = (uint8_t*)(ws + O_OCC0);
    uint8_t* occ1 = (uint8_t*)(ws + O_OCC1);
    uint8_t* occ2 = (uint8_t*)(ws + O_OCC2);
    uint8_t* mask0 = (uint8_t*)(ws + O_MASK0);
    uint8_t* mask1 = (uint8_t*)(ws + O_MASK1);
    int* bcnt = (int*)(ws + O_BCNT);
    uint8_t* sel = (uint8_t*)(ws + O_SEL);
    uint32_t* keyl = (uint32_t*)(ws + O_KEYS);
    float* feat0 = (float*)(ws + O_FEAT0);
    float* hr1 = (float*)(ws + O_HR1);
    float* feat1 = (float*)(ws + O_FEAT1);
    float* hr2 = (float*)(ws + O_HR2);
    float* feat2 = (float*)(ws + O_FEAT2);
    // aliased scratch (lifetimes verified disjoint):
    int* list0 = (int*)(ws + O_HR1);                      // lvl0; hr1 written at lvl1
    int* list1 = (int*)(ws + O_HR2);                      // lvl1; hr2 written at lvl2
    int* list2 = (int*)(ws + O_HR1);                      // lvl2; hr1 dead after lvl1 conv
    float* xf = (float*)(ws + O_HR2 + (4UL << 20));       // lvl0 only; 4 MB

    // inputs: 0:x 1:occ0 2:gt0 3:gt1 4:gt2 5:w_conv0 6:b_conv0 7:w_cls0 8:b_cls0
    // 9:w_up1 10:b_up1 11:w_conv1 12:b_conv1 13:w_cls1 14:b_cls1
    // 15:w_up2 16:b_up2 17:w_conv2 18:b_conv2 19:w_cls2 20:b_cls2 21-23:nums
    k_fzero<<<1, 64, 0, stream>>>(flags);
    k_fscan<<<512, 256, 0, stream>>>(d_in[0], d_in[4], flags);
    k_ffinal<<<1, 64, 0, stream>>>(flags);
    k_zout<<<2048, 256, 0, stream>>>(d_out, (long)out_size, flags);
    k_occ0<<<N0 / 256, 256, 0, stream>>>(d_in[1], occ0, flags);
    k_xcast<<<(N0 * 32) / 256, 256, 0, stream>>>(d_in[0], xf, flags);

    // ---- level 0
    k_cnt<<<N0 / 256, 256, 0, stream>>>(occ0, N0, bcnt, mask0);
    k_scanb<<<1, 256, 0, stream>>>(bcnt, N0 / 256, cnt);
    k_fill<<<N0 / 256, 256, 0, stream>>>(occ0, N0, bcnt, list0);
    k_sconv16<32, 32><<<(2 * N0) / 256, 256, 0, stream>>>(xf, d_in[5], d_in[6], occ0,
                                                          list0, cnt, feat0, flags);
    k_scls<32><<<N0 / 256, 256, 0, stream>>>(feat0, d_in[7], d_in[8], occ0, list0,
                                             cnt, d_out, OFF_CLS0, keyl, flags);
    k_hzero<<<256, 256, 0, stream>>>(h1, state);
    k_hist1<<<256, 256, 0, stream>>>(keyl, cnt, h1);
    k_scan1<<<1, 256, 0, stream>>>(h1, d_in[21], cnt, state, h2);
    k_hist2<<<256, 256, 0, stream>>>(keyl, cnt, state, h2);
    k_scan2<<<1, 256, 0, stream>>>(h2, state);
    k_mark<<<N0 / 256, 256, 0, stream>>>(keyl, list0, cnt, state, sel, tiel);
    k_ties<<<1, 1024, 0, stream>>>(state, tiel, sel);
    k_sapply<<<N0 / 256, 256, 0, stream>>>(sel, list0, cnt, d_in[2], mask0, flags);

    // ---- level 1
    k_expand<32><<<N1 / 256, 256, 0, stream>>>(mask0, occ1);
    k_cnt<<<N1 / 256, 256, 0, stream>>>(occ1, N1, bcnt, mask1);
    k_scanb<<<1, 256, 0, stream>>>(bcnt, N1 / 256, cnt);
    k_fill<<<N1 / 256, 256, 0, stream>>>(occ1, N1, bcnt, list1);
    k_sup<32><<<N1 / 256, 256, 0, stream>>>(feat0, d_in[9], d_in[10], list1, cnt,
                                            hr1, flags);
    k_sconv16<16, 64><<<(2 * N1) / 256, 256, 0, stream>>>(hr1, d_in[11], d_in[12], occ1,
                                                          list1, cnt, feat1, flags);
    k_scls<64><<<N1 / 256, 256, 0, stream>>>(feat1, d_in[13], d_in[14], occ1, list1,
                                             cnt, d_out, OFF_CLS1, keyl, flags);
    k_hzero<<<256, 256, 0, stream>>>(h1, state);
    k_hist1<<<256, 256, 0, stream>>>(keyl, cnt, h1);
    k_scan1<<<1, 256, 0, stream>>>(h1, d_in[22], cnt, state, h2);
    k_hist2<<<256, 256, 0, stream>>>(keyl, cnt, state, h2);
    k_scan2<<<1, 256, 0, stream>>>(h2, state);
    k_mark<<<N1 / 256, 256, 0, stream>>>(keyl, list1, cnt, state, sel, tiel);
    k_ties<<<1, 1024, 0, stream>>>(state, tiel, sel);
    k_sapply<<<N1 / 256, 256, 0, stream>>>(sel, list1, cnt, d_in[3], mask1, flags);

    // ---- level 2
    k_expand<64><<<N2 / 256, 256, 0, stream>>>(mask1, occ2);
    k_cnt<<<N2 / 256, 256, 0, stream>>>(occ2, N2, bcnt, (uint8_t*)0);
    k_scanb<<<1, 256, 0, stream>>>(bcnt, N2 / 256, cnt);
    k_fill<<<N2 / 256, 256, 0, stream>>>(occ2, N2, bcnt, list2);
    k_sup<64><<<N2 / 256, 256, 0, stream>>>(feat1, d_in[15], d_in[16], list2, cnt,
                                            hr2, flags);
    k_sconv16<16, 128><<<(2 * N2) / 256, 256, 0, stream>>>(hr2, d_in[17], d_in[18], occ2,
                                                           list2, cnt, feat2, flags);
    k_scls<128><<<N2 / 256, 256, 0, stream>>>(feat2, d_in[19], d_in[20], occ2, list2,
                                              cnt, d_out, OFF_CLS2, keyl, flags);
    k_hzero<<<256, 256, 0, stream>>>(h1, state);
    k_hist1<<<256, 256, 0, stream>>>(keyl, cnt, h1);
    k_scan1<<<1, 256, 0, stream>>>(h1, d_in[23], cnt, state, h2);
    k_hist2<<<256, 256, 0, stream>>>(keyl, cnt, state, h2);
    k_scan2<<<1, 256, 0, stream>>>(h2, state);
    k_mark<<<N2 / 256, 256, 0, stream>>>(keyl, list2, cnt, state, sel, tiel);
    k_ties<<<1, 1024, 0, stream>>>(state, tiel, sel);
    k_sapply_out<<<N2 / 256, 256, 0, stream>>>(sel, list2, cnt, d_in[4], feat2,
                                               d_out, flags);
}

// Round 14
// 866.998 us; speedup vs baseline: 1.4659x; 1.0224x over previous
//
#include <hip/hip_runtime.h>
#include <stdint.h>

// R14 = R13 (886us) + (a) k_scls split 2 threads/voxel by tap parity
// (shfl_xor combine) — halves its serial load chain like conv's R13 split;
// (b) 9 fewer dispatches: k_hzero deleted (h1 zeroed in k_fill; state-zero
// provably redundant), k_cnt fused into k_occ0/k_expand, k_sapply(_out)
// fused into k_mark/k_ties (sel array eliminated; mask/out written direct).

// ---------------- problem constants ----------------
#define N0 32768      // 32^3
#define N1 262144     // 64^3
#define N2 2097152    // 128^3

// d_out element offsets (cls0, cls1, cls2, out)
#define OFF_CLS0 0L
#define OFF_CLS1 32768L
#define OFF_CLS2 294912L
#define OFF_OUT  2392064L

// ---------------- ws layout (byte offsets, within proven ~320MB footprint) --
#define O_FLAGS 0UL            // int[64]: [0]=bf16 [1]=boolmode [8..]=counters
#define O_STATE 256UL
#define O_TIE   512UL          // 16000 ints (tie voxel-index list)
#define O_HIST1 66048UL        // 65536 u32
#define O_HIST2 328192UL       // 65536 u32
#define O_OCC0  590336UL       // N0 u8
#define O_OCC1  623104UL       // N1 u8
#define O_OCC2  885248UL       // N2 u8
#define O_MASK0 2982400UL
#define O_MASK1 3015168UL
#define O_BCNT  3277312UL      // 8192 ints (block counts / exclusive prefix)
#define O_SEL   5374464UL      // (unused since R14)
#define O_KEYS  7471616UL      // N2 u32 keyl[] by LIST POSITION
#define O_FEAT0 15860224UL     // N0*16 f32
#define O_HR1   17957376UL     // N1*16 f32 ; ALIASED: list0 (lvl0), list2 (lvl2, hr1 dead)
#define O_FEAT1 34734592UL     // N1*16 f32
#define O_HR2   51511808UL     // N2*16 f32 ; ALIASED: list1 @+0 (lvl1), xf @+4MB (lvl0)
#define O_FEAT2 185729536UL    // N2*16 f32  (ends ~320 MB)

#define TIE_CAP 16000

// ---------------- dtype-flexible helpers ----------------
// flags[0] = floats-are-bf16; flags[1] = bool mode (0 i32,1 u8,2 bf16,3 f32,4 i64)
__device__ __forceinline__ float ldf(const void* p, long i, int bf) {
    if (bf) {
        uint16_t h = ((const uint16_t*)p)[i];
        return __uint_as_float(((uint32_t)h) << 16);
    }
    return ((const float*)p)[i];
}
__device__ __forceinline__ int ldb(const void* p, long i, int m) {
    switch (m) {
        case 0: return ((const int*)p)[i] != 0;
        case 1: return ((const uint8_t*)p)[i] != 0;
        case 2: { uint16_t h = ((const uint16_t*)p)[i]; return (h & 0x7FFF) != 0; }
        case 4: return ((const long long*)p)[i] != 0;
        default: { float f = ((const float*)p)[i]; return f != 0.0f; }
    }
}
__device__ __forceinline__ float rndb(float f, int en) {
    if (!en) return f;
    uint32_t u = __float_as_uint(f);
    u += 0x7FFFu + ((u >> 16) & 1u);
    u &= 0xFFFF0000u;
    return __uint_as_float(u);
}
__device__ __forceinline__ void stf(void* p, long i, float v, int bf) {
    if (bf) {
        uint32_t u = __float_as_uint(v);
        u += 0x7FFFu + ((u >> 16) & 1u);
        ((uint16_t*)p)[i] = (uint16_t)(u >> 16);
    } else {
        ((float*)p)[i] = v;
    }
}
// order-preserving float->u32 key; all finite keys are > 0
__device__ __forceinline__ uint32_t fkey(float f) {
    f = f + 0.0f;
    uint32_t u = __float_as_uint(f);
    return (u & 0x80000000u) ? ~u : (u | 0x80000000u);
}

// ---------------- runtime dtype detection (parallel) ----------------------
__global__ void k_fzero(int* flags) {
    int t = threadIdx.x;
    if (t < 16) flags[8 + t] = 0;
}
__global__ void k_fscan(const void* x, const void* gt2, int* flags) {
    int* cnt = flags + 8;
    __shared__ int lc[8];
    int t = threadIdx.x;
    if (t < 8) lc[t] = 0;
    __syncthreads();
    long gid = (long)blockIdx.x * blockDim.x + threadIdx.x;
    long gstride = (long)gridDim.x * blockDim.x;
    int ltiny = 0;
    const uint32_t* xu = (const uint32_t*)x;
    for (long i = gid; i < 524288; i += gstride) {
        uint32_t u = xu[i];
        uint32_t e = (u >> 23) & 0xFFu;
        if (e == 0u && (u & 0x7FFFFFu) != 0u) ltiny++;
    }
    int l1off = 0, l1any = 0, l3f = 0, l84 = 0;
    const uint8_t* g = (const uint8_t*)gt2;
    for (long i = gid; i < 2097152; i += gstride) {
        uint8_t b = g[i];
        if (b == 1u) {
            l1any++;
            if ((i & 3) != 0) l1off++;
            if ((i & 7) == 4) l84++;
        }
        if (b == 0x3Fu && (i & 3) == 1) l3f++;
    }
    if (ltiny) atomicAdd(&lc[0], ltiny);
    if (l1off) atomicAdd(&lc[1], l1off);
    if (l1any) atomicAdd(&lc[2], l1any);
    if (l3f)   atomicAdd(&lc[3], l3f);
    if (l84)   atomicAdd(&lc[4], l84);
    __syncthreads();
    if (t < 5 && lc[t]) atomicAdd(&cnt[t], lc[t]);
}
__global__ void k_ffinal(int* flags) {
    if (threadIdx.x != 0 || blockIdx.x != 0) return;
    const int* cnt = flags + 8;
    flags[0] = (cnt[0] > 8) ? 1 : 0;
    int bm;
    if (cnt[1] > 8)       bm = 1;
    else if (cnt[2] > 8)  bm = (cnt[4] > 8) ? 0 : 4;
    else if (cnt[3] > 8)  bm = 2;
    else                  bm = 3;
    flags[1] = bm;
}

// zero entire d_out (harness re-poisons to 0xAA each launch)
__global__ void k_zout(void* dout, long out_elems, const int* flags) {
    long bytes = out_elems * (flags[0] ? 2 : 4);
    long n16 = bytes >> 4;
    uint4 z = make_uint4(0, 0, 0, 0);
    uint4* p = (uint4*)dout;
    long stride = (long)gridDim.x * blockDim.x;
    for (long i = (long)blockIdx.x * blockDim.x + threadIdx.x; i < n16; i += stride)
        p[i] = z;
}

__global__ void k_xcast(const void* x, float* xf, const int* flags) {
    long i = (long)blockIdx.x * blockDim.x + threadIdx.x;
    if (i >= (long)N0 * 32) return;
    xf[i] = ldf(x, i, flags[0]);
}

// ---------------- occupancy build + per-block count (fused) ----------------
// occ0 from raw bool input; also ballot-count into bcnt and zero mask.
__global__ void k_occ0cnt(const void* occraw, uint8_t* occ, const int* flags,
                          int* __restrict__ bcnt, uint8_t* maskz) {
    long v = (long)blockIdx.x * 256 + threadIdx.x;
    int a = (v < N0) ? ldb(occraw, v, flags[1]) : 0;
    if (v < N0) { occ[v] = (uint8_t)a; maskz[v] = 0; }
    unsigned long long m = __ballot(a != 0);
    __shared__ int wsum[4];
    int lane = threadIdx.x & 63, wid = threadIdx.x >> 6;
    if (lane == 0) wsum[wid] = (int)__popcll(m);
    __syncthreads();
    if (threadIdx.x == 0)
        bcnt[blockIdx.x] = wsum[0] + wsum[1] + wsum[2] + wsum[3];
}
// child occ from parent mask; ballot-count; optional mask zero.
template <int Dp>
__global__ void k_expcnt(const uint8_t* __restrict__ maskp, uint8_t* __restrict__ occc,
                         int* __restrict__ bcnt, uint8_t* maskz) {
    const int D = Dp * 2;
    long v = (long)blockIdx.x * 256 + threadIdx.x;
    const long N = (long)D * D * D;
    int a = 0;
    if (v < N) {
        int wd = (int)(v % D), hh = (int)((v / D) % D), dd = (int)(v / ((long)D * D));
        a = maskp[((long)(dd >> 1) * Dp + (hh >> 1)) * Dp + (wd >> 1)];
        occc[v] = (uint8_t)a;
        if (maskz) maskz[v] = 0;
    }
    unsigned long long m = __ballot(a != 0);
    __shared__ int wsum[4];
    int lane = threadIdx.x & 63, wid = threadIdx.x >> 6;
    if (lane == 0) wsum[wid] = (int)__popcll(m);
    __syncthreads();
    if (threadIdx.x == 0)
        bcnt[blockIdx.x] = wsum[0] + wsum[1] + wsum[2] + wsum[3];
}
__global__ void k_scanb(int* __restrict__ bcnt, int nb, int* cnt) {
    __shared__ int tsum[256];
    __shared__ int tpre[257];
    int t = threadIdx.x;
    int ch = (nb + 255) / 256;
    int lo = t * ch, hi = min(lo + ch, nb);
    int s = 0;
    for (int i = lo; i < hi; i++) s += bcnt[i];
    tsum[t] = s;
    __syncthreads();
    if (t == 0) {
        int run = 0;
        for (int j = 0; j < 256; j++) { tpre[j] = run; run += tsum[j]; }
        tpre[256] = run;
        cnt[0] = run;  // total actives
    }
    __syncthreads();
    int run = tpre[t];
    for (int i = lo; i < hi; i++) { int x = bcnt[i]; bcnt[i] = run; run += x; }
}
// fill list; ALSO grid-stride zero h1 (replaces k_hzero; state-zero is
// redundant: scan1/scan2 write every state field mark/ties read, in-stream).
__global__ void k_fill(const uint8_t* __restrict__ occ, long N,
                       const int* __restrict__ bcnt, int* __restrict__ list,
                       uint32_t* __restrict__ h1z) {
    long v = (long)blockIdx.x * 256 + threadIdx.x;
    for (long j = v; j < 65536; j += (long)gridDim.x * 256) h1z[j] = 0u;
    int a = (v < N) && occ[v];
    unsigned long long m = __ballot(a != 0);
    __shared__ int wsum[4];
    int lane = threadIdx.x & 63, wid = threadIdx.x >> 6;
    if (lane == 0) wsum[wid] = (int)__popcll(m);
    __syncthreads();
    int base = bcnt[blockIdx.x];
    for (int w = 0; w < wid; w++) base += wsum[w];
    if (a) list[base + (int)__popcll(m & ((1ull << lane) - 1ull))] = (int)v;
}

// ---------------- sparse 3^3 conv, CIN->16, relu ---------------------------
// 2 threads per voxel (half computes 8 co). Occ-byte prefetch bitmask,
// wave-uniform taps (weight reads = 2-addr broadcast, free).
template <int CIN, int D>
__global__ void k_sconv16(const float* __restrict__ xin, const void* w, const void* bias,
                          const uint8_t* __restrict__ occ, const int* __restrict__ list,
                          const int* __restrict__ cnt, float* __restrict__ out,
                          const int* __restrict__ flags) {
    __shared__ float wl[27 * CIN * 16 + 16];
    const int n = cnt[0];
    if (blockIdx.x * 128 >= n) return;  // 128 voxels per 256-thread block
    const int bf = flags[0];
    for (int i = threadIdx.x; i < 27 * CIN * 16; i += 256) wl[i] = ldf(w, i, bf);
    if (threadIdx.x < 16) wl[27 * CIN * 16 + threadIdx.x] = ldf(bias, threadIdx.x, bf);
    __syncthreads();
    int gid = blockIdx.x * 256 + threadIdx.x;
    int i = gid >> 1;
    if (i >= n) return;
    const int half = gid & 1;
    int v = list[i];
    int wd = v % D, hh = (v / D) % D, dd = v / (D * D);
    uint32_t nbm = 0u;
    {
        int t = 0;
#pragma unroll
        for (int kd = 0; kd < 3; kd++)
#pragma unroll
            for (int kh = 0; kh < 3; kh++)
#pragma unroll
                for (int kw = 0; kw < 3; kw++, t++) {
                    int d2 = dd + kd - 1, h2 = hh + kh - 1, w2 = wd + kw - 1;
                    int ok = (int)((unsigned)d2 < (unsigned)D) &
                             (int)((unsigned)h2 < (unsigned)D) &
                             (int)((unsigned)w2 < (unsigned)D);
                    int nv = v + (kd - 1) * D * D + (kh - 1) * D + (kw - 1);
                    int nvc = ok ? nv : v;  // clamped: load always in-bounds
                    nbm |= ((uint32_t)((int)occ[nvc] & ok)) << t;
                }
    }
    float acc[8];
#pragma unroll
    for (int co = 0; co < 8; co++) acc[co] = 0.0f;
    int t = 0;
    for (int kd = 0; kd < 3; kd++) {
        for (int kh = 0; kh < 3; kh++) {
            for (int kw = 0; kw < 3; kw++, t++) {
                if (!((nbm >> t) & 1u)) continue;
                long nv = (long)v + (kd - 1) * (D * D) + (kh - 1) * D + (kw - 1);
                const float4* xp = (const float4*)(xin + nv * CIN);
                const float* wp = &wl[((kd * 3 + kh) * 3 + kw) * CIN * 16 + half * 8];
#pragma unroll
                for (int c4 = 0; c4 < CIN / 4; c4++) {
                    float4 x4 = xp[c4];
                    const float* wq = wp + c4 * 64;
#pragma unroll
                    for (int co = 0; co < 8; co++) acc[co] += x4.x * wq[co];
#pragma unroll
                    for (int co = 0; co < 8; co++) acc[co] += x4.y * wq[16 + co];
#pragma unroll
                    for (int co = 0; co < 8; co++) acc[co] += x4.z * wq[32 + co];
#pragma unroll
                    for (int co = 0; co < 8; co++) acc[co] += x4.w * wq[48 + co];
                }
            }
        }
    }
    float* op = out + (long)v * 16 + half * 8;
    const float* bp = &wl[27 * CIN * 16 + half * 8];
#pragma unroll
    for (int co = 0; co < 8; co++) {
        float val = rndb(acc[co], bf);
        val = rndb(val + bp[co], bf);
        op[co] = fmaxf(val, 0.0f);
    }
}

// ---------------- sparse cls conv (16->1): d_out slice + position keys -----
// R14: 2 threads/voxel split by tap PARITY (shfl_xor combine) — halves the
// serial load chain. f32 reassociation only; well within bf16 tolerance.
template <int D>
__global__ void k_scls(const float* __restrict__ feat, const void* w, const void* bias,
                       const uint8_t* __restrict__ occ, const int* __restrict__ list,
                       const int* __restrict__ cnt, void* dout, long ooff,
                       uint32_t* __restrict__ keyl, const int* __restrict__ flags) {
    __shared__ float wl[27 * 16 + 1];
    const int n = cnt[0];
    if (blockIdx.x * 128 >= n) return;  // 128 voxels per 256-thread block
    const int bf = flags[0];
    for (int i = threadIdx.x; i < 27 * 16; i += 256) wl[i] = ldf(w, i, bf);
    if (threadIdx.x == 0) wl[432] = ldf(bias, 0, bf);
    __syncthreads();
    int gid = blockIdx.x * 256 + threadIdx.x;
    int i = gid >> 1;
    if (i >= n) return;
    const int half = gid & 1;
    int v = list[i];
    int wd = v % D, hh = (v / D) % D, dd = v / (D * D);
    uint32_t nbm = 0u;
    {
        int t = 0;
#pragma unroll
        for (int kd = 0; kd < 3; kd++)
#pragma unroll
            for (int kh = 0; kh < 3; kh++)
#pragma unroll
                for (int kw = 0; kw < 3; kw++, t++) {
                    int d2 = dd + kd - 1, h2 = hh + kh - 1, w2 = wd + kw - 1;
                    int ok = (int)((unsigned)d2 < (unsigned)D) &
                             (int)((unsigned)h2 < (unsigned)D) &
                             (int)((unsigned)w2 < (unsigned)D);
                    int nv = v + (kd - 1) * D * D + (kh - 1) * D + (kw - 1);
                    int nvc = ok ? nv : v;
                    nbm |= ((uint32_t)((int)occ[nvc] & ok)) << t;
                }
    }
    float acc = 0.0f;
    int t = 0;
    for (int kd = 0; kd < 3; kd++) {
        for (int kh = 0; kh < 3; kh++) {
            for (int kw = 0; kw < 3; kw++, t++) {
                if ((t & 1) != half) continue;       // tap-parity split
                if (!((nbm >> t) & 1u)) continue;
                long nv = (long)v + (kd - 1) * (D * D) + (kh - 1) * D + (kw - 1);
                const float4* xp = (const float4*)(feat + nv * 16);
                const float* wp = &wl[((kd * 3 + kh) * 3 + kw) * 16];
                float4 a0 = xp[0], a1 = xp[1], a2 = xp[2], a3 = xp[3];
                acc += a0.x * wp[0] + a0.y * wp[1] + a0.z * wp[2] + a0.w * wp[3];
                acc += a1.x * wp[4] + a1.y * wp[5] + a1.z * wp[6] + a1.w * wp[7];
                acc += a2.x * wp[8] + a2.y * wp[9] + a2.z * wp[10] + a2.w * wp[11];
                acc += a3.x * wp[12] + a3.y * wp[13] + a3.z * wp[14] + a3.w * wp[15];
            }
        }
    }
    acc += __shfl_xor(acc, 1, 64);  // combine tap halves (adjacent lanes)
    if (half == 0) {
        float val = rndb(acc, bf);
        val = rndb(val + wl[432], bf);
        stf(dout, ooff + v, val, bf);
        keyl[i] = fkey(val);
    }
}

// ---------------- sparse 2x up-sample (transpose conv, kernel-flipped) -----
template <int Dp>
__global__ void k_sup(const float* __restrict__ featp, const void* w, const void* bias,
                      const int* __restrict__ list, const int* __restrict__ cnt,
                      float* __restrict__ hrelu, const int* __restrict__ flags) {
    __shared__ float wl[2048 + 16];
    const int n = cnt[0];
    if (blockIdx.x * 256 >= n) return;
    const int bf = flags[0];
    for (int i = threadIdx.x; i < 2048; i += 256) wl[i] = ldf(w, i, bf);
    if (threadIdx.x < 16) wl[2048 + threadIdx.x] = ldf(bias, threadIdx.x, bf);
    __syncthreads();
    int i = blockIdx.x * 256 + threadIdx.x;
    if (i >= n) return;
    int v = list[i];
    const int D = Dp * 2;
    int wd = v % D, hh = (v / D) % D, dd = v / (D * D);
    const float4* xp = (const float4*)(featp +
        ((long)((dd >> 1) * Dp + (hh >> 1)) * Dp + (wd >> 1)) * 16);
    // y[o] = x[o>>1] * w[1-(o&1)] per axis (jax conv_transpose, k=2,s=2,'VALID')
    int a = 1 - (dd & 1), b2 = 1 - (hh & 1), c = 1 - (wd & 1);
    const float* wp = &wl[((a * 2 + b2) * 2 + c) * 256];
    float acc[16];
#pragma unroll
    for (int co = 0; co < 16; co++) acc[co] = 0.0f;
#pragma unroll
    for (int c4 = 0; c4 < 4; c4++) {
        float4 x4 = xp[c4];
        const float* wq = wp + c4 * 64;
#pragma unroll
        for (int co = 0; co < 16; co++) acc[co] += x4.x * wq[co];
#pragma unroll
        for (int co = 0; co < 16; co++) acc[co] += x4.y * wq[16 + co];
#pragma unroll
        for (int co = 0; co < 16; co++) acc[co] += x4.z * wq[32 + co];
#pragma unroll
        for (int co = 0; co < 16; co++) acc[co] += x4.w * wq[48 + co];
    }
    float* op = hrelu + (long)v * 16;
#pragma unroll
    for (int co = 0; co < 16; co++) {
        float val = rndb(acc[co], bf);
        val = rndb(val + wl[2048 + co], bf);
        op[co] = fmaxf(val, 0.0f);  // relu(h) feeding next conv
    }
}

// ---------------- exact top-k over position keys (radix-16/16) -------------
// Per-block LDS histogram: 65536 bins as packed u16 pairs in 128KB LDS.
// state: [0]=B(-1 => select-all) [1]=count_above [2]=krem [3]=K [4]=ties_needed [5]=tie_count
__global__ void k_hist1(const uint32_t* __restrict__ keyl, const int* cnt,
                        uint32_t* __restrict__ hist) {
    __shared__ uint32_t lh[32768];
    const int n = cnt[0];
    for (int j = threadIdx.x; j < 32768; j += 256) lh[j] = 0u;
    __syncthreads();
    const int stride = gridDim.x * 256;
    for (int i = blockIdx.x * 256 + threadIdx.x; i < n; i += stride) {
        uint32_t bin = keyl[i] >> 16;
        atomicAdd(&lh[bin >> 1], 1u << ((bin & 1u) << 4));
    }
    __syncthreads();
    for (int j = threadIdx.x; j < 32768; j += 256) {
        uint32_t p = lh[j];
        if (p) {
            uint32_t lo = p & 0xFFFFu, hi = p >> 16;
            if (lo) atomicAdd(&hist[2 * j], lo);
            if (hi) atomicAdd(&hist[2 * j + 1], hi);
        }
    }
}
__global__ void k_scan1(const uint32_t* hist, const void* kptr, const int* cnt,
                        int* state, uint32_t* hist2) {
    __shared__ uint32_t part[256];
    int t = threadIdx.x;
    uint32_t s = 0;
    for (int j = 0; j < 256; j++) s += hist[t * 256 + j];
    part[t] = s;
    for (int i = t; i < 65536; i += 256) hist2[i] = 0u;
    __syncthreads();
    if (t == 0) {
        uint32_t k = (uint32_t)((const int*)kptr)[0];
        uint32_t total = (uint32_t)cnt[0];
        if (k >= total) {
            state[0] = -1;
            state[3] = 0;   // K=0 -> selected = (key > 0), true for all finite keys
            state[4] = 0;
            state[5] = 0;
            return;
        }
        uint32_t cum = 0, cab = 0;
        int B = 0;
        for (int c = 255; c >= 0; c--) {
            if (cum + part[c] >= k) {
                uint32_t cc = cum;
                for (int b = c * 256 + 255; b >= c * 256; b--) {
                    uint32_t h = hist[b];
                    if (cc + h >= k) { B = b; cab = cc; break; }
                    cc += h;
                }
                break;
            }
            cum += part[c];
        }
        state[0] = B;
        state[1] = (int)cab;
        state[2] = (int)(k - cab);
    }
}
__global__ void k_hist2(const uint32_t* __restrict__ keyl, const int* cnt,
                        const int* state, uint32_t* __restrict__ hist2) {
    if (state[0] < 0) return;
    __shared__ uint32_t lh[32768];
    const int n = cnt[0];
    const int B = state[0];
    for (int j = threadIdx.x; j < 32768; j += 256) lh[j] = 0u;
    __syncthreads();
    const int stride = gridDim.x * 256;
    for (int i = blockIdx.x * 256 + threadIdx.x; i < n; i += stride) {
        uint32_t key = keyl[i];
        if ((int)(key >> 16) == B) {
            uint32_t bin = key & 0xFFFFu;
            atomicAdd(&lh[bin >> 1], 1u << ((bin & 1u) << 4));
        }
    }
    __syncthreads();
    for (int j = threadIdx.x; j < 32768; j += 256) {
        uint32_t p = lh[j];
        if (p) {
            uint32_t lo = p & 0xFFFFu, hi = p >> 16;
            if (lo) atomicAdd(&hist2[2 * j], lo);
            if (hi) atomicAdd(&hist2[2 * j + 1], hi);
        }
    }
}
__global__ void k_scan2(const uint32_t* hist2, int* state) {
    __shared__ uint32_t part[256];
    int t = threadIdx.x;
    if (state[0] < 0) return;
    uint32_t s = 0;
    for (int j = 0; j < 256; j++) s += hist2[t * 256 + j];
    part[t] = s;
    __syncthreads();
    if (t == 0) {
        uint32_t krem = (uint32_t)state[2];
        uint32_t cum = 0, cl = 0;
        int L = 0;
        for (int c = 255; c >= 0; c--) {
            if (cum + part[c] >= krem) {
                uint32_t cc = cum;
                for (int b = c * 256 + 255; b >= c * 256; b--) {
                    uint32_t h = hist2[b];
                    if (cc + h >= krem) { L = b; cl = cc; break; }
                    cc += h;
                }
                break;
            }
            cum += part[c];
        }
        uint32_t K = ((uint32_t)state[0] << 16) | (uint32_t)L;
        state[3] = (int)K;
        state[4] = (int)(krem - cl);
        state[5] = 0;
    }
}
// ---- mark + prune fused (levels 0/1): mask[v] = (key>K) || gt; tie collect.
// k_ties upgrades tie winners to mask=1 afterwards (in-stream order).
__global__ void k_markm(const uint32_t* __restrict__ keyl, const int* __restrict__ list,
                        const int* cnt, int* state, const void* gt,
                        uint8_t* __restrict__ mask, int* tiel, const int* flags) {
    int n = cnt[0];
    int i = blockIdx.x * 256 + threadIdx.x;
    uint32_t K = (uint32_t)state[3];
    int v = 0, isTie = 0;
    if (i < n) {
        uint32_t key = keyl[i];
        v = list[i];
        mask[v] = (uint8_t)((key > K) || ldb(gt, v, flags[1]));
        isTie = (key == K && K != 0u);
    }
    unsigned long long m = __ballot(isTie != 0);
    if (m) {
        int lane = threadIdx.x & 63;
        int leader = __ffsll((unsigned long long)m) - 1;
        int base = 0;
        if (lane == leader) base = atomicAdd(&state[5], (int)__popcll(m));
        base = __shfl(base, leader, 64);
        if (isTie) {
            int pos = base + (int)__popcll(m & ((1ull << lane) - 1ull));
            if (pos < TIE_CAP) tiel[pos] = v;
        }
    }
}
__global__ void k_tiesm(const int* state, const int* tiel, uint8_t* mask) {
    __shared__ int lst[TIE_CAP];
    int T = state[5];
    if (T > TIE_CAP) T = TIE_CAP;
    int need = state[4];
    if (need <= 0 || T == 0) return;
    for (int i = threadIdx.x; i < T; i += blockDim.x) lst[i] = tiel[i];
    __syncthreads();
    for (int e = threadIdx.x; e < T; e += blockDim.x) {
        int idx = lst[e], r = 0;
        for (int j = 0; j < T; j++) r += (lst[j] < idx) ? 1 : 0;
        if (r < need) mask[idx] = 1;  // winner: selected -> mask 1
    }
}
// ---- final level: mark + feature scatter fused; ties writes winners' feats.
__global__ void k_marko(const uint32_t* __restrict__ keyl, const int* __restrict__ list,
                        const int* cnt, int* state, const void* gt,
                        const float* __restrict__ feat, void* dout, int* tiel,
                        const int* flags) {
    int n = cnt[0];
    int i = blockIdx.x * 256 + threadIdx.x;
    uint32_t K = (uint32_t)state[3];
    int v = 0, isTie = 0;
    const int bf = flags[0];
    if (i < n) {
        uint32_t key = keyl[i];
        v = list[i];
        if ((key > K) || ldb(gt, v, flags[1])) {
            long base = OFF_OUT + (long)v * 16;
            const float* fp = feat + (long)v * 16;
#pragma unroll
            for (int co = 0; co < 16; co++) stf(dout, base + co, fp[co], bf);
        }
        isTie = (key == K && K != 0u);
    }
    unsigned long long m = __ballot(isTie != 0);
    if (m) {
        int lane = threadIdx.x & 63;
        int leader = __ffsll((unsigned long long)m) - 1;
        int base = 0;
        if (lane == leader) base = atomicAdd(&state[5], (int)__popcll(m));
        base = __shfl(base, leader, 64);
        if (isTie) {
            int pos = base + (int)__popcll(m & ((1ull << lane) - 1ull));
            if (pos < TIE_CAP) tiel[pos] = v;
        }
    }
}
__global__ void k_tieso(const int* state, const int* tiel,
                        const float* __restrict__ feat, void* dout, const int* flags) {
    __shared__ int lst[TIE_CAP];
    int T = state[5];
    if (T > TIE_CAP) T = TIE_CAP;
    int need = state[4];
    if (need <= 0 || T == 0) return;
    const int bf = flags[0];
    for (int i = threadIdx.x; i < T; i += blockDim.x) lst[i] = tiel[i];
    __syncthreads();
    for (int e = threadIdx.x; e < T; e += blockDim.x) {
        int idx = lst[e], r = 0;
        for (int j = 0; j < T; j++) r += (lst[j] < idx) ? 1 : 0;
        if (r < need) {
            long base = OFF_OUT + (long)idx * 16;
            const float* fp = feat + (long)idx * 16;
            for (int co = 0; co < 16; co++) stf(dout, base + co, fp[co], bf);
        }
    }
}

// ---------------- launcher ----------------
extern "C" void kernel_launch(void* const* d_in, const int* in_sizes, int n_in,
                              void* d_out, int out_size, void* d_ws, size_t ws_size,
                              hipStream_t stream) {
    char* ws = (char*)d_ws;
    int* flags = (int*)(ws + O_FLAGS);
    int* cnt = flags + 32;
    int* state = (int*)(ws + O_STATE);
    int* tiel = (int*)(ws + O_TIE);
    uint32_t* h1 = (uint32_t*)(ws + O_HIST1);
    uint32_t* h2 = (uint32_t*)(ws + O_HIST2);
    uint8_t* occ0 = (uint8_t*)(ws + O_OCC0);
    uint8_t* occ1 = (uint8_t*)(ws + O_OCC1);
    uint8_t* occ2 = (uint8_t*)(ws + O_OCC2);
    uint8_t* mask0 = (uint8_t*)(ws + O_MASK0);
    uint8_t* mask1 = (uint8_t*)(ws + O_MASK1);
    int* bcnt = (int*)(ws + O_BCNT);
    uint32_t* keyl = (uint32_t*)(ws + O_KEYS);
    float* feat0 = (float*)(ws + O_FEAT0);
    float* hr1 = (float*)(ws + O_HR1);
    float* feat1 = (float*)(ws + O_FEAT1);
    float* hr2 = (float*)(ws + O_HR2);
    float* feat2 = (float*)(ws + O_FEAT2);
    // aliased scratch (lifetimes verified disjoint):
    int* list0 = (int*)(ws + O_HR1);                      // lvl0; hr1 written at lvl1
    int* list1 = (int*)(ws + O_HR2);                      // lvl1; hr2 written at lvl2
    int* list2 = (int*)(ws + O_HR1);                      // lvl2; hr1 dead after lvl1 conv
    float* xf = (float*)(ws + O_HR2 + (4UL << 20));       // lvl0 only; 4 MB

    // inputs: 0:x 1:occ0 2:gt0 3:gt1 4:gt2 5:w_conv0 6:b_conv0 7:w_cls0 8:b_cls0
    // 9:w_up1 10:b_up1 11:w_conv1 12:b_conv1 13:w_cls1 14:b_cls1
    // 15:w_up2 16:b_up2 17:w_conv2 18:b_conv2 19:w_cls2 20:b_cls2 21-23:nums
    k_fzero<<<1, 64, 0, stream>>>(flags);
    k_fscan<<<512, 256, 0, stream>>>(d_in[0], d_in[4], flags);
    k_ffinal<<<1, 64, 0, stream>>>(flags);
    k_zout<<<2048, 256, 0, stream>>>(d_out, (long)out_size, flags);
    k_xcast<<<(N0 * 32) / 256, 256, 0, stream>>>(d_in[0], xf, flags);

    // ---- level 0
    k_occ0cnt<<<N0 / 256, 256, 0, stream>>>(d_in[1], occ0, flags, bcnt, mask0);
    k_scanb<<<1, 256, 0, stream>>>(bcnt, N0 / 256, cnt);
    k_fill<<<N0 / 256, 256, 0, stream>>>(occ0, N0, bcnt, list0, h1);
    k_sconv16<32, 32><<<(2 * N0) / 256, 256, 0, stream>>>(xf, d_in[5], d_in[6], occ0,
                                                          list0, cnt, feat0, flags);
    k_scls<32><<<(2 * N0) / 256, 256, 0, stream>>>(feat0, d_in[7], d_in[8], occ0, list0,
                                                   cnt, d_out, OFF_CLS0, keyl, flags);
    k_hist1<<<256, 256, 0, stream>>>(keyl, cnt, h1);
    k_scan1<<<1, 256, 0, stream>>>(h1, d_in[21], cnt, state, h2);
    k_hist2<<<256, 256, 0, stream>>>(keyl, cnt, state, h2);
    k_scan2<<<1, 256, 0, stream>>>(h2, state);
    k_markm<<<N0 / 256, 256, 0, stream>>>(keyl, list0, cnt, state, d_in[2], mask0,
                                          tiel, flags);
    k_tiesm<<<1, 1024, 0, stream>>>(state, tiel, mask0);

    // ---- level 1
    k_expcnt<32><<<N1 / 256, 256, 0, stream>>>(mask0, occ1, bcnt, mask1);
    k_scanb<<<1, 256, 0, stream>>>(bcnt, N1 / 256, cnt);
    k_fill<<<N1 / 256, 256, 0, stream>>>(occ1, N1, bcnt, list1, h1);
    k_sup<32><<<N1 / 256, 256, 0, stream>>>(feat0, d_in[9], d_in[10], list1, cnt,
                                            hr1, flags);
    k_sconv16<16, 64><<<(2 * N1) / 256, 256, 0, stream>>>(hr1, d_in[11], d_in[12], occ1,
                                                          list1, cnt, feat1, flags);
    k_scls<64><<<(2 * N1) / 256, 256, 0, stream>>>(feat1, d_in[13], d_in[14], occ1,
                                                   list1, cnt, d_out, OFF_CLS1, keyl,
                                                   flags);
    k_hist1<<<256, 256, 0, stream>>>(keyl, cnt, h1);
    k_scan1<<<1, 256, 0, stream>>>(h1, d_in[22], cnt, state, h2);
    k_hist2<<<256, 256, 0, stream>>>(keyl, cnt, state, h2);
    k_scan2<<<1, 256, 0, stream>>>(h2, state);
    k_markm<<<N1 / 256, 256, 0, stream>>>(keyl, list1, cnt, state, d_in[3], mask1,
                                          tiel, flags);
    k_tiesm<<<1, 1024, 0, stream>>>(state, tiel, mask1);

    // ---- level 2
    k_expcnt<64><<<N2 / 256, 256, 0, stream>>>(mask1, occ2, bcnt, (uint8_t*)0);
    k_scanb<<<1, 256, 0, stream>>>(bcnt, N2 / 256, cnt);
    k_fill<<<N2 / 256, 256, 0, stream>>>(occ2, N2, bcnt, list2, h1);
    k_sup<64><<<N2 / 256, 256, 0, stream>>>(feat1, d_in[15], d_in[16], list2, cnt,
                                            hr2, flags);
    k_sconv16<16, 128><<<(2 * N2) / 256, 256, 0, stream>>>(hr2, d_in[17], d_in[18],
                                                           occ2, list2, cnt, feat2,
                                                           flags);
    k_scls<128><<<(2 * N2) / 256, 256, 0, stream>>>(feat2, d_in[19], d_in[20], occ2,
                                                    list2, cnt, d_out, OFF_CLS2, keyl,
                                                    flags);
    k_hist1<<<256, 256, 0, stream>>>(keyl, cnt, h1);
    k_scan1<<<1, 256, 0, stream>>>(h1, d_in[23], cnt, state, h2);
    k_hist2<<<256, 256, 0, stream>>>(keyl, cnt, state, h2);
    k_scan2<<<1, 256, 0, stream>>>(h2, state);
    k_marko<<<N2 / 256, 256, 0, stream>>>(keyl, list2, cnt, state, d_in[4], feat2,
                                          d_out, tiel, flags);
    k_tieso<<<1, 1024, 0, stream>>>(state, tiel, feat2, d_out, flags);
}